// Round 1
// baseline (4585.815 us; speedup 1.0000x reference)
//
#include <hip/hip_runtime.h>
#include <cstddef>

// ---------------------------------------------------------------------------
// SpiralAutoencoder on MI355X — round 1: correct fp32 baseline.
// Pipeline: 4x [spiral_conv -> downsample] -> fc_enc -> fc_dec ->
//           4x [upsample -> spiral_conv] -> spiral_conv(identity) -> +template
// d_ws arena: bufA (10,289,152 f32) | bufB (5,144,576 f32) ping-pong. 61.7 MB.
// ---------------------------------------------------------------------------

#define BATCH 64
#define SPK 12  // spiral length

// ---------------------------------------------------------------------------
// Spiral conv: y[b,n,o] = act( sum_{k,f} x[b, S[n,k], f] * W[o, k*F+f] + bias[o] )
// Row n == Nv-1 (padding vertex) zeroed. Gather staged in LDS, float4 dot.
// Block: 256 threads, handles NT rows of n for one b.
// ---------------------------------------------------------------------------
__global__ __launch_bounds__(256) void spiral_conv_kernel(
    const float* __restrict__ x, const int* __restrict__ S,
    const float* __restrict__ W, const float* __restrict__ bias,
    float* __restrict__ y, int Nv, int F, int O, int KF, int NT, int elu_flag)
{
    __shared__ float g[8192];  // 32 KB: NT*KF <= 8192 guaranteed by host
    const int b   = blockIdx.y;
    const int n0  = blockIdx.x * NT;
    const int tid = threadIdx.x;

    // stage gathered rows
    const int total = NT * KF;
    for (int j = tid; j < total; j += 256) {
        int r  = j / KF;
        int jj = j - r * KF;
        int n  = n0 + r;
        if (n < Nv) {
            int k = jj / F;
            int f = jj - k * F;
            int src = S[n * SPK + k];
            g[j] = x[((size_t)b * Nv + src) * F + f];
        }
    }
    __syncthreads();

    const int outs = NT * O;
    for (int t = tid; t < outs; t += 256) {
        int r = t / O;
        int o = t - r * O;
        int n = n0 + r;
        if (n >= Nv) continue;
        float res;
        if (n == Nv - 1) {
            res = 0.f;  // padding-vertex mask
        } else {
            const float* wrow = W + (size_t)o * KF;
            const float* grow = g + r * KF;
            float a0 = 0.f, a1 = 0.f, a2 = 0.f, a3 = 0.f;
            for (int j = 0; j < KF; j += 4) {
                float4 wv = *(const float4*)(wrow + j);
                float4 gv = *(const float4*)(grow + j);
                a0 += wv.x * gv.x;
                a1 += wv.y * gv.y;
                a2 += wv.z * gv.z;
                a3 += wv.w * gv.w;
            }
            float acc = (a0 + a1) + (a2 + a3) + bias[o];
            res = (elu_flag && acc <= 0.f) ? expm1f(acc) : acc;
        }
        y[((size_t)b * Nv + n) * O + o] = res;
    }
}

// ---------------------------------------------------------------------------
// Down/up-sample: Y[b,m,f] = sum_n A[m,n] * X[b,n,f]
// Viewed as GEMM C[M, 64*F] = A[M,N] @ Xcols[N, 64*F], c = b*F + f.
// 64x64 tile, TK=16, 256 threads, 4x4 micro-tile per thread.
// ---------------------------------------------------------------------------
__global__ __launch_bounds__(256) void dsamp_kernel(
    const float* __restrict__ A, const float* __restrict__ X,
    float* __restrict__ Y, int M, int N, int F)
{
    __shared__ float As[16][68];  // [k][m], padded stride 68 (16B-aligned rows)
    __shared__ float Xs[16][64];  // [k][c]

    const int m0  = blockIdx.x * 64;
    const int c0  = blockIdx.y * 64;
    const int tid = threadIdx.x;
    const int tx  = tid & 15;
    const int ty  = tid >> 4;

    float acc[4][4];
#pragma unroll
    for (int i = 0; i < 4; ++i)
#pragma unroll
        for (int j = 0; j < 4; ++j) acc[i][j] = 0.f;

    for (int k0 = 0; k0 < N; k0 += 16) {
        // A tile: 64 (m) x 16 (k), coalesced along k
#pragma unroll
        for (int p = 0; p < 4; ++p) {
            int r  = (tid >> 4) + p * 16;
            int kk = tid & 15;
            int m  = m0 + r;
            int n  = k0 + kk;
            float v = 0.f;
            if (m < M && n < N) v = A[(size_t)m * N + n];
            As[kk][r] = v;
        }
        // X tile: 16 (k=n) x 64 (c), float4 per thread (always within one b: F%16==0)
        {
            int kk = tid >> 4;
            int cc = (tid & 15) * 4;
            int n  = k0 + kk;
            float4 v = make_float4(0.f, 0.f, 0.f, 0.f);
            if (n < N) {
                int c  = c0 + cc;
                int bb = c / F;
                int f  = c - bb * F;
                v = *(const float4*)(X + ((size_t)bb * N + n) * F + f);
            }
            *(float4*)&Xs[kk][cc] = v;
        }
        __syncthreads();
#pragma unroll
        for (int kk = 0; kk < 16; ++kk) {
            float4 av = *(const float4*)&As[kk][ty * 4];
            float4 xv = *(const float4*)&Xs[kk][tx * 4];
            acc[0][0] += av.x * xv.x; acc[0][1] += av.x * xv.y; acc[0][2] += av.x * xv.z; acc[0][3] += av.x * xv.w;
            acc[1][0] += av.y * xv.x; acc[1][1] += av.y * xv.y; acc[1][2] += av.y * xv.z; acc[1][3] += av.y * xv.w;
            acc[2][0] += av.z * xv.x; acc[2][1] += av.z * xv.y; acc[2][2] += av.z * xv.z; acc[2][3] += av.z * xv.w;
            acc[3][0] += av.w * xv.x; acc[3][1] += av.w * xv.y; acc[3][2] += av.w * xv.z; acc[3][3] += av.w * xv.w;
        }
        __syncthreads();
    }

    const int cbase = c0 + tx * 4;
    const int bb = cbase / F;
    const int f  = cbase - bb * F;
#pragma unroll
    for (int i = 0; i < 4; ++i) {
        int m = m0 + ty * 4 + i;
        if (m < M) {
            float4 v = make_float4(acc[i][0], acc[i][1], acc[i][2], acc[i][3]);
            *(float4*)(Y + ((size_t)bb * M + m) * F + f) = v;
        }
    }
}

// ---------------------------------------------------------------------------
// Fully-connected: out[b,o] = bias[o] + sum_k in[b,k] * Wrow(o,k)
// dup: W has 2*In cols (concat([z,z]) case): use W[o,k] + W[o,k+In].
// ---------------------------------------------------------------------------
__global__ __launch_bounds__(256) void fc_kernel(
    const float* __restrict__ in, const float* __restrict__ W,
    const float* __restrict__ bias, float* __restrict__ out,
    int In, int O, int dup)
{
    int b = blockIdx.x;
    int o = blockIdx.y * blockDim.x + threadIdx.x;
    if (o >= O) return;
    const float* xr = in + (size_t)b * In;
    const int wstride = dup ? 2 * In : In;
    const float* wr = W + (size_t)o * wstride;
    float acc = bias[o];
    if (dup) {
        for (int k = 0; k < In; ++k) acc += xr[k] * (wr[k] + wr[In + k]);
    } else {
        for (int k = 0; k < In; ++k) acc += xr[k] * wr[k];
    }
    out[(size_t)b * O + o] = acc;
}

// out1 = out0 + template (float4 over 964608 elements)
__global__ __launch_bounds__(256) void add_kernel(
    const float* __restrict__ a, const float* __restrict__ t,
    float* __restrict__ o, int n4)
{
    int i = blockIdx.x * blockDim.x + threadIdx.x;
    if (i < n4) {
        float4 av = ((const float4*)a)[i];
        float4 tv = ((const float4*)t)[i];
        float4 r  = make_float4(av.x + tv.x, av.y + tv.y, av.z + tv.z, av.w + tv.w);
        ((float4*)o)[i] = r;
    }
}

// ---------------------------------------------------------------------------

static inline void conv_launch(const float* x, const int* S, const float* W,
                               const float* b, float* y, int Nv, int F, int O,
                               int elu, hipStream_t s)
{
    int KF = SPK * F;
    int nt_o = 256 / O;           // enough rows so all 256 threads have outputs
    if (nt_o < 1) nt_o = 1;
    int nt_l = 8192 / KF;         // LDS capacity (32 KB)
    int NT = nt_o < nt_l ? nt_o : nt_l;
    if (NT < 1) NT = 1;
    dim3 grid((Nv + NT - 1) / NT, BATCH);
    spiral_conv_kernel<<<grid, 256, 0, s>>>(x, S, W, b, y, Nv, F, O, KF, NT, elu);
}

static inline void dsamp_launch(const float* A, const float* X, float* Y,
                                int M, int N, int F, hipStream_t s)
{
    dim3 grid((M + 63) / 64, F);  // grid.y = 64*F/64
    dsamp_kernel<<<grid, 256, 0, s>>>(A, X, Y, M, N, F);
}

extern "C" void kernel_launch(void* const* d_in, const int* in_sizes, int n_in,
                              void* d_out, int out_size, void* d_ws, size_t ws_size,
                              hipStream_t stream)
{
    // setup_inputs() dict order:
    const float* x_talking = (const float*)d_in[0];
    const float* templ     = (const float*)d_in[1];
    const float* D0 = (const float*)d_in[2];
    const float* U0 = (const float*)d_in[3];
    const float* D1 = (const float*)d_in[4];
    const float* U1 = (const float*)d_in[5];
    const float* D2 = (const float*)d_in[6];
    const float* U2 = (const float*)d_in[7];
    const float* D3 = (const float*)d_in[8];
    const float* U3 = (const float*)d_in[9];
    const float* enc_w0 = (const float*)d_in[10]; const float* enc_b0 = (const float*)d_in[11];
    const float* enc_w1 = (const float*)d_in[12]; const float* enc_b1 = (const float*)d_in[13];
    const float* enc_w2 = (const float*)d_in[14]; const float* enc_b2 = (const float*)d_in[15];
    const float* enc_w3 = (const float*)d_in[16]; const float* enc_b3 = (const float*)d_in[17];
    const float* fc_enc_w = (const float*)d_in[18]; const float* fc_enc_b = (const float*)d_in[19];
    const float* fc_dec_w = (const float*)d_in[20]; const float* fc_dec_b = (const float*)d_in[21];
    const float* dec_w0 = (const float*)d_in[22]; const float* dec_b0 = (const float*)d_in[23];
    const float* dec_w1 = (const float*)d_in[24]; const float* dec_b1 = (const float*)d_in[25];
    const float* dec_w2 = (const float*)d_in[26]; const float* dec_b2 = (const float*)d_in[27];
    const float* dec_w3 = (const float*)d_in[28]; const float* dec_b3 = (const float*)d_in[29];
    const float* dec_w4 = (const float*)d_in[30]; const float* dec_b4 = (const float*)d_in[31];
    const int* S0 = (const int*)d_in[32];
    const int* S1 = (const int*)d_in[33];
    const int* S2 = (const int*)d_in[34];
    const int* S3 = (const int*)d_in[35];

    float* bufA = (float*)d_ws;            // 10,289,152 floats
    float* bufB = bufA + 10289152;         // 5,144,576 floats

    float* out0 = (float*)d_out;           // 964,608 floats
    float* out1 = out0 + 964608;

    // ---- encoder ----
    conv_launch(x_talking, S0, enc_w0, enc_b0, bufA, 5024, 3, 16, 1, stream);   // e0 [64,5024,16]
    dsamp_launch(D0, bufA, bufB, 1257, 5024, 16, stream);                       // d0 [64,1257,16]
    conv_launch(bufB, S1, enc_w1, enc_b1, bufA, 1257, 16, 32, 1, stream);       // e1 [64,1257,32]
    dsamp_launch(D1, bufA, bufB, 315, 1257, 32, stream);                        // d1 [64,315,32]
    conv_launch(bufB, S2, enc_w2, enc_b2, bufA, 315, 32, 64, 1, stream);        // e2 [64,315,64]
    dsamp_launch(D2, bufA, bufB, 80, 315, 64, stream);                          // d2 [64,80,64]
    conv_launch(bufB, S3, enc_w3, enc_b3, bufA, 80, 64, 128, 1, stream);        // e3 [64,80,128]
    dsamp_launch(D3, bufA, bufB, 21, 80, 128, stream);                          // d3 [64,21,128]

    // z = d3.reshape(64,2688) @ fc_enc_w.T + b   -> bufA [64,128]
    fc_kernel<<<dim3(64, 1), 128, 0, stream>>>(bufB, fc_enc_w, fc_enc_b, bufA, 2688, 128, 0);
    // h = cat(z,z) @ fc_dec_w.T + b              -> bufB [64,2688]
    fc_kernel<<<dim3(64, 11), 256, 0, stream>>>(bufA, fc_dec_w, fc_dec_b, bufB, 128, 2688, 1);

    // ---- decoder ----
    dsamp_launch(U3, bufB, bufA, 80, 21, 128, stream);                          // u3 [64,80,128]
    conv_launch(bufA, S3, dec_w0, dec_b0, bufB, 80, 128, 64, 1, stream);        // c0 [64,80,64]
    dsamp_launch(U2, bufB, bufA, 315, 80, 64, stream);                          // u2 [64,315,64]
    conv_launch(bufA, S2, dec_w1, dec_b1, bufB, 315, 64, 32, 1, stream);        // c1 [64,315,32]
    dsamp_launch(U1, bufB, bufA, 1257, 315, 32, stream);                        // u1 [64,1257,32]
    conv_launch(bufA, S1, dec_w2, dec_b2, bufB, 1257, 32, 32, 1, stream);       // c2 [64,1257,32]
    dsamp_launch(U0, bufB, bufA, 5024, 1257, 32, stream);                       // u0 [64,5024,32]
    conv_launch(bufA, S0, dec_w3, dec_b3, bufB, 5024, 32, 16, 1, stream);       // c3 [64,5024,16]
    conv_launch(bufB, S0, dec_w4, dec_b4, out0, 5024, 16, 3, 0, stream);        // c4 -> out0

    // out1 = out0 + template
    int n4 = 964608 / 4;
    add_kernel<<<(n4 + 255) / 256, 256, 0, stream>>>(out0, templ, out1, n4);
}

// Round 3
// 2480.934 us; speedup vs baseline: 1.8484x; 1.8484x over previous
//
#include <hip/hip_runtime.h>
#include <cstddef>

// ---------------------------------------------------------------------------
// SpiralAutoencoder on MI355X — round 3:
//  * hipMemsetAsync(d_ws) at launch start: replay-determinism (post-timing fix)
//  * D0/U0/D1/U1 resampling GEMMs -> bf16 MFMA (16x16x32), fp32 accumulate
// ---------------------------------------------------------------------------

#define BATCH 64
#define SPK 12  // spiral length

typedef __attribute__((ext_vector_type(8))) short bf16x8;
typedef __attribute__((ext_vector_type(4))) float f32x4;

__device__ __forceinline__ unsigned short f2bf(float x) {
    union { float f; unsigned int u; } v; v.f = x;
    unsigned int r = v.u + 0x7FFF + ((v.u >> 16) & 1);  // RNE
    return (unsigned short)(r >> 16);
}

// ---------------------------------------------------------------------------
// MFMA down/up-sample: Y[b,m,f] = sum_k A[m,k] * X[b,k,f]
// GEMM view: Y[M, C] = A[M,K] @ Xcols[K, C], C = 64*F, col c = b*F + f.
// 64x64 block tile, 4 waves (2x2), each wave 32x32 via 2x2 mfma_16x16x32_bf16.
// LDS: As[m][k], Xs[c][k], row stride PAD=40 bf16 (80B, 16B-aligned frags).
// A loaded scalar (rows may be odd-stride); X loaded float4 along f.
// ---------------------------------------------------------------------------
__global__ __launch_bounds__(256) void dsamp_mfma_kernel(
    const float* __restrict__ A, const float* __restrict__ X,
    float* __restrict__ Y, int M, int K, int logF)
{
    constexpr int PAD = 40;
    __shared__ unsigned short As[64 * PAD];
    __shared__ unsigned short Xs[64 * PAD];

    const int F    = 1 << logF;
    const int m0   = blockIdx.x * 64;
    const int c0   = blockIdx.y * 64;
    const int tid  = threadIdx.x;
    const int lane = tid & 63;
    const int wave = tid >> 6;
    const int wm   = (wave >> 1) * 32;
    const int wn   = (wave & 1) * 32;
    const int l15  = lane & 15;
    const int quad = lane >> 4;

    f32x4 acc[2][2] = {{{0.f,0.f,0.f,0.f},{0.f,0.f,0.f,0.f}},
                       {{0.f,0.f,0.f,0.f},{0.f,0.f,0.f,0.f}}};

    for (int k0 = 0; k0 < K; k0 += 32) {
        // ---- A tile: 64 m x 32 k (scalar global loads, coalesced along k) ----
#pragma unroll
        for (int i = 0; i < 8; ++i) {
            int idx = tid + i * 256;
            int r = idx >> 5, kk = idx & 31;
            int m = m0 + r, k = k0 + kk;
            float v = (m < M && k < K) ? A[(size_t)m * K + k] : 0.f;
            As[r * PAD + kk] = f2bf(v);
        }
        // ---- X tile: 64 c x 32 k, stored [c][k]; float4 global read along f ----
#pragma unroll
        for (int i = 0; i < 2; ++i) {
            int idx = tid + i * 256;
            int kk = idx >> 4, cg = idx & 15;
            int k = k0 + kk;
            int c = c0 + cg * 4;
            int bb = c >> logF, f = c & (F - 1);
            float4 v = make_float4(0.f, 0.f, 0.f, 0.f);
            if (k < K) v = *(const float4*)(X + (((size_t)bb * K + k) << logF) + f);
            Xs[(cg * 4 + 0) * PAD + kk] = f2bf(v.x);
            Xs[(cg * 4 + 1) * PAD + kk] = f2bf(v.y);
            Xs[(cg * 4 + 2) * PAD + kk] = f2bf(v.z);
            Xs[(cg * 4 + 3) * PAD + kk] = f2bf(v.w);
        }
        __syncthreads();
        // ---- fragments: A[m=l15][k=quad*8+j], B[k=quad*8+j][n=l15] ----
        bf16x8 a0 = *(const bf16x8*)&As[(wm +      l15) * PAD + quad * 8];
        bf16x8 a1 = *(const bf16x8*)&As[(wm + 16 + l15) * PAD + quad * 8];
        bf16x8 b0 = *(const bf16x8*)&Xs[(wn +      l15) * PAD + quad * 8];
        bf16x8 b1 = *(const bf16x8*)&Xs[(wn + 16 + l15) * PAD + quad * 8];
        acc[0][0] = __builtin_amdgcn_mfma_f32_16x16x32_bf16(a0, b0, acc[0][0], 0, 0, 0);
        acc[0][1] = __builtin_amdgcn_mfma_f32_16x16x32_bf16(a0, b1, acc[0][1], 0, 0, 0);
        acc[1][0] = __builtin_amdgcn_mfma_f32_16x16x32_bf16(a1, b0, acc[1][0], 0, 0, 0);
        acc[1][1] = __builtin_amdgcn_mfma_f32_16x16x32_bf16(a1, b1, acc[1][1], 0, 0, 0);
        __syncthreads();
    }

    // ---- epilogue: C/D layout col=lane&15, row=quad*4+reg ----
#pragma unroll
    for (int tm = 0; tm < 2; ++tm)
#pragma unroll
        for (int tn = 0; tn < 2; ++tn)
#pragma unroll
            for (int reg = 0; reg < 4; ++reg) {
                int m  = m0 + wm + tm * 16 + quad * 4 + reg;
                int cc = c0 + wn + tn * 16 + l15;
                if (m < M) {
                    int bb = cc >> logF, f = cc & (F - 1);
                    Y[(((size_t)bb * M + m) << logF) + f] = acc[tm][tn][reg];
                }
            }
}

// ---------------------------------------------------------------------------
// conv_gemm (unchanged from round 2 — call-1-verified correct)
// ---------------------------------------------------------------------------
template<int MT, int OT>
__global__ __launch_bounds__(256) void conv_gemm_kernel(
    const float* __restrict__ x, const int* __restrict__ S,
    const float* __restrict__ W, const float* __restrict__ bias,
    float* __restrict__ y, int Nv, int logF, int O, int KF, int elu_flag)
{
    constexpr int CT = OT / 4;
    constexpr int RT = 256 / CT;
    static_assert(RT * 4 == MT, "tile shape");
    __shared__ float Gs[32][MT];
    __shared__ float Ws[32][OT];

    const int b   = blockIdx.y;
    const int n0  = blockIdx.x * MT;
    const int tid = threadIdx.x;
    const int cx  = tid % CT;
    const int ry  = tid / CT;
    const int r0  = ry * 4;
    const int o0  = cx * 4;
    const int fmask = (1 << logF) - 1;
    const size_t xb = (size_t)b * Nv;

    float acc[4][4];
#pragma unroll
    for (int i = 0; i < 4; ++i)
#pragma unroll
        for (int j = 0; j < 4; ++j) acc[i][j] = 0.f;

    for (int k0 = 0; k0 < KF; k0 += 32) {
        constexpr int GSLOTS = MT * 8;
#pragma unroll
        for (int i = 0; i < GSLOTS / 256; ++i) {
            int idx = tid + i * 256;
            int r   = idx & (MT - 1);
            int jg  = idx / MT;
            int j0  = jg * 4;
            int n   = n0 + r;
            float4 v = make_float4(0.f, 0.f, 0.f, 0.f);
            if (n < Nv) {
                int kf  = k0 + j0;
                int k   = kf >> logF;
                int f   = kf & fmask;
                int src = S[n * SPK + k];
                v = *(const float4*)(x + ((xb + src) << logF) + f);
            }
            Gs[j0 + 0][r] = v.x; Gs[j0 + 1][r] = v.y;
            Gs[j0 + 2][r] = v.z; Gs[j0 + 3][r] = v.w;
        }
        constexpr int WSLOTS = OT * 8;
#pragma unroll
        for (int i = 0; i < (WSLOTS + 255) / 256; ++i) {
            int idx = tid + i * 256;
            if (WSLOTS >= 256 || idx < WSLOTS) {
                int o  = idx & (OT - 1);
                int jg = idx / OT;
                int j0 = jg * 4;
                float4 v = *(const float4*)(W + (size_t)o * KF + k0 + j0);
                Ws[j0 + 0][o] = v.x; Ws[j0 + 1][o] = v.y;
                Ws[j0 + 2][o] = v.z; Ws[j0 + 3][o] = v.w;
            }
        }
        __syncthreads();
#pragma unroll
        for (int kk = 0; kk < 32; ++kk) {
            float4 g = *(const float4*)&Gs[kk][r0];
            float4 w = *(const float4*)&Ws[kk][o0];
            acc[0][0] += g.x * w.x; acc[0][1] += g.x * w.y; acc[0][2] += g.x * w.z; acc[0][3] += g.x * w.w;
            acc[1][0] += g.y * w.x; acc[1][1] += g.y * w.y; acc[1][2] += g.y * w.z; acc[1][3] += g.y * w.w;
            acc[2][0] += g.z * w.x; acc[2][1] += g.z * w.y; acc[2][2] += g.z * w.z; acc[2][3] += g.z * w.w;
            acc[3][0] += g.w * w.x; acc[3][1] += g.w * w.y; acc[3][2] += g.w * w.z; acc[3][3] += g.w * w.w;
        }
        __syncthreads();
    }

    float4 bv = *(const float4*)(bias + o0);
#pragma unroll
    for (int i = 0; i < 4; ++i) {
        int n = n0 + r0 + i;
        if (n >= Nv) continue;
        float v0 = acc[i][0] + bv.x;
        float v1 = acc[i][1] + bv.y;
        float v2 = acc[i][2] + bv.z;
        float v3 = acc[i][3] + bv.w;
        if (elu_flag) {
            v0 = v0 > 0.f ? v0 : expm1f(v0);
            v1 = v1 > 0.f ? v1 : expm1f(v1);
            v2 = v2 > 0.f ? v2 : expm1f(v2);
            v3 = v3 > 0.f ? v3 : expm1f(v3);
        }
        if (n == Nv - 1) { v0 = v1 = v2 = v3 = 0.f; }
        *(float4*)(y + ((size_t)b * Nv + n) * O + o0) = make_float4(v0, v1, v2, v3);
    }
}

// ---------------------------------------------------------------------------
// Fallback spiral conv (F=3 or O=3 layers only).
// ---------------------------------------------------------------------------
__global__ __launch_bounds__(256) void spiral_conv_kernel(
    const float* __restrict__ x, const int* __restrict__ S,
    const float* __restrict__ W, const float* __restrict__ bias,
    float* __restrict__ y, int Nv, int F, int O, int KF, int NT, int elu_flag)
{
    __shared__ float g[8192];
    const int b   = blockIdx.y;
    const int n0  = blockIdx.x * NT;
    const int tid = threadIdx.x;

    const int total = NT * KF;
    for (int j = tid; j < total; j += 256) {
        int r  = j / KF;
        int jj = j - r * KF;
        int n  = n0 + r;
        if (n < Nv) {
            int k = jj / F;
            int f = jj - k * F;
            int src = S[n * SPK + k];
            g[j] = x[((size_t)b * Nv + src) * F + f];
        }
    }
    __syncthreads();

    const int outs = NT * O;
    for (int t = tid; t < outs; t += 256) {
        int r = t / O;
        int o = t - r * O;
        int n = n0 + r;
        if (n >= Nv) continue;
        float res;
        if (n == Nv - 1) {
            res = 0.f;
        } else {
            const float* wrow = W + (size_t)o * KF;
            const float* grow = g + r * KF;
            float a0 = 0.f, a1 = 0.f, a2 = 0.f, a3 = 0.f;
            for (int j = 0; j < KF; j += 4) {
                float4 wv = *(const float4*)(wrow + j);
                float4 gv = *(const float4*)(grow + j);
                a0 += wv.x * gv.x;
                a1 += wv.y * gv.y;
                a2 += wv.z * gv.z;
                a3 += wv.w * gv.w;
            }
            float accv = (a0 + a1) + (a2 + a3) + bias[o];
            res = (elu_flag && accv <= 0.f) ? expm1f(accv) : accv;
        }
        y[((size_t)b * Nv + n) * O + o] = res;
    }
}

// ---------------------------------------------------------------------------
// VALU down/up-sample (small levels 2-3 only).
// ---------------------------------------------------------------------------
__global__ __launch_bounds__(256) void dsamp_kernel(
    const float* __restrict__ A, const float* __restrict__ X,
    float* __restrict__ Y, int M, int N, int F)
{
    __shared__ float As[16][68];
    __shared__ float Xs[16][64];

    const int m0  = blockIdx.x * 64;
    const int c0  = blockIdx.y * 64;
    const int tid = threadIdx.x;
    const int tx  = tid & 15;
    const int ty  = tid >> 4;

    float acc[4][4];
#pragma unroll
    for (int i = 0; i < 4; ++i)
#pragma unroll
        for (int j = 0; j < 4; ++j) acc[i][j] = 0.f;

    for (int k0 = 0; k0 < N; k0 += 16) {
#pragma unroll
        for (int p = 0; p < 4; ++p) {
            int r  = (tid >> 4) + p * 16;
            int kk = tid & 15;
            int m  = m0 + r;
            int n  = k0 + kk;
            float v = 0.f;
            if (m < M && n < N) v = A[(size_t)m * N + n];
            As[kk][r] = v;
        }
        {
            int kk = tid >> 4;
            int cc = (tid & 15) * 4;
            int n  = k0 + kk;
            float4 v = make_float4(0.f, 0.f, 0.f, 0.f);
            if (n < N) {
                int c  = c0 + cc;
                int bb = c / F;
                int f  = c - bb * F;
                v = *(const float4*)(X + ((size_t)bb * N + n) * F + f);
            }
            *(float4*)&Xs[kk][cc] = v;
        }
        __syncthreads();
#pragma unroll
        for (int kk = 0; kk < 16; ++kk) {
            float4 av = *(const float4*)&As[kk][ty * 4];
            float4 xv = *(const float4*)&Xs[kk][tx * 4];
            acc[0][0] += av.x * xv.x; acc[0][1] += av.x * xv.y; acc[0][2] += av.x * xv.z; acc[0][3] += av.x * xv.w;
            acc[1][0] += av.y * xv.x; acc[1][1] += av.y * xv.y; acc[1][2] += av.y * xv.z; acc[1][3] += av.y * xv.w;
            acc[2][0] += av.z * xv.x; acc[2][1] += av.z * xv.y; acc[2][2] += av.z * xv.z; acc[2][3] += av.z * xv.w;
            acc[3][0] += av.w * xv.x; acc[3][1] += av.w * xv.y; acc[3][2] += av.w * xv.z; acc[3][3] += av.w * xv.w;
        }
        __syncthreads();
    }

    const int cbase = c0 + tx * 4;
    const int bb = cbase / F;
    const int f  = cbase - bb * F;
#pragma unroll
    for (int i = 0; i < 4; ++i) {
        int m = m0 + ty * 4 + i;
        if (m < M) {
            float4 v = make_float4(acc[i][0], acc[i][1], acc[i][2], acc[i][3]);
            *(float4*)(Y + ((size_t)bb * M + m) * F + f) = v;
        }
    }
}

// ---------------------------------------------------------------------------
__global__ __launch_bounds__(256) void fc_kernel(
    const float* __restrict__ in, const float* __restrict__ W,
    const float* __restrict__ bias, float* __restrict__ out,
    int In, int O, int dup)
{
    int b = blockIdx.x;
    int o = blockIdx.y * blockDim.x + threadIdx.x;
    if (o >= O) return;
    const float* xr = in + (size_t)b * In;
    const int wstride = dup ? 2 * In : In;
    const float* wr = W + (size_t)o * wstride;
    float acc = bias[o];
    if (dup) {
        for (int k = 0; k < In; ++k) acc += xr[k] * (wr[k] + wr[In + k]);
    } else {
        for (int k = 0; k < In; ++k) acc += xr[k] * wr[k];
    }
    out[(size_t)b * O + o] = acc;
}

__global__ __launch_bounds__(256) void add_kernel(
    const float* __restrict__ a, const float* __restrict__ t,
    float* __restrict__ o, int n4)
{
    int i = blockIdx.x * blockDim.x + threadIdx.x;
    if (i < n4) {
        float4 av = ((const float4*)a)[i];
        float4 tv = ((const float4*)t)[i];
        ((float4*)o)[i] = make_float4(av.x + tv.x, av.y + tv.y, av.z + tv.z, av.w + tv.w);
    }
}

// ---------------------------------------------------------------------------

static inline int ilog2(int v) { int l = 0; while ((1 << l) < v) ++l; return l; }

static inline void conv_launch(const float* x, const int* S, const float* W,
                               const float* b, float* y, int Nv, int F, int O,
                               int elu, hipStream_t s)
{
    int KF = SPK * F;
    if ((F & (F - 1)) == 0 && F >= 16 && (O == 16 || O == 32 || O == 64 || O == 128)) {
        int logF = ilog2(F);
        if (O == 16) {
            dim3 grid((Nv + 255) / 256, BATCH);
            conv_gemm_kernel<256, 16><<<grid, 256, 0, s>>>(x, S, W, b, y, Nv, logF, O, KF, elu);
        } else if (O == 32) {
            dim3 grid((Nv + 127) / 128, BATCH);
            conv_gemm_kernel<128, 32><<<grid, 256, 0, s>>>(x, S, W, b, y, Nv, logF, O, KF, elu);
        } else if (O == 64) {
            dim3 grid((Nv + 63) / 64, BATCH);
            conv_gemm_kernel<64, 64><<<grid, 256, 0, s>>>(x, S, W, b, y, Nv, logF, O, KF, elu);
        } else {
            dim3 grid((Nv + 31) / 32, BATCH);
            conv_gemm_kernel<32, 128><<<grid, 256, 0, s>>>(x, S, W, b, y, Nv, logF, O, KF, elu);
        }
        return;
    }
    int nt_o = 256 / O; if (nt_o < 1) nt_o = 1;
    int nt_l = 8192 / KF;
    int NT = nt_o < nt_l ? nt_o : nt_l;
    if (NT < 1) NT = 1;
    dim3 grid((Nv + NT - 1) / NT, BATCH);
    spiral_conv_kernel<<<grid, 256, 0, s>>>(x, S, W, b, y, Nv, F, O, KF, NT, elu);
}

// MFMA path for big resampling GEMMs (F must be pow2 >= 16)
static inline void dsamp_mfma_launch(const float* A, const float* X, float* Y,
                                     int M, int K, int F, hipStream_t s)
{
    dim3 grid((M + 63) / 64, F);
    dsamp_mfma_kernel<<<grid, 256, 0, s>>>(A, X, Y, M, K, ilog2(F));
}

static inline void dsamp_launch(const float* A, const float* X, float* Y,
                                int M, int N, int F, hipStream_t s)
{
    dim3 grid((M + 63) / 64, F);
    dsamp_kernel<<<grid, 256, 0, s>>>(A, X, Y, M, N, F);
}

extern "C" void kernel_launch(void* const* d_in, const int* in_sizes, int n_in,
                              void* d_out, int out_size, void* d_ws, size_t ws_size,
                              hipStream_t stream)
{
    const float* x_talking = (const float*)d_in[0];
    const float* templ     = (const float*)d_in[1];
    const float* D0 = (const float*)d_in[2];
    const float* U0 = (const float*)d_in[3];
    const float* D1 = (const float*)d_in[4];
    const float* U1 = (const float*)d_in[5];
    const float* D2 = (const float*)d_in[6];
    const float* U2 = (const float*)d_in[7];
    const float* D3 = (const float*)d_in[8];
    const float* U3 = (const float*)d_in[9];
    const float* enc_w0 = (const float*)d_in[10]; const float* enc_b0 = (const float*)d_in[11];
    const float* enc_w1 = (const float*)d_in[12]; const float* enc_b1 = (const float*)d_in[13];
    const float* enc_w2 = (const float*)d_in[14]; const float* enc_b2 = (const float*)d_in[15];
    const float* enc_w3 = (const float*)d_in[16]; const float* enc_b3 = (const float*)d_in[17];
    const float* fc_enc_w = (const float*)d_in[18]; const float* fc_enc_b = (const float*)d_in[19];
    const float* fc_dec_w = (const float*)d_in[20]; const float* fc_dec_b = (const float*)d_in[21];
    const float* dec_w0 = (const float*)d_in[22]; const float* dec_b0 = (const float*)d_in[23];
    const float* dec_w1 = (const float*)d_in[24]; const float* dec_b1 = (const float*)d_in[25];
    const float* dec_w2 = (const float*)d_in[26]; const float* dec_b2 = (const float*)d_in[27];
    const float* dec_w3 = (const float*)d_in[28]; const float* dec_b3 = (const float*)d_in[29];
    const float* dec_w4 = (const float*)d_in[30]; const float* dec_b4 = (const float*)d_in[31];
    const int* S0 = (const int*)d_in[32];
    const int* S1 = (const int*)d_in[33];
    const int* S2 = (const int*)d_in[34];
    const int* S3 = (const int*)d_in[35];

    float* bufA = (float*)d_ws;            // 10,289,152 floats
    float* bufB = bufA + 10289152;         // 5,144,576 floats

    float* out0 = (float*)d_out;           // 964,608 floats
    float* out1 = out0 + 964608;

    // Deterministic ws initial state on EVERY call (incl. graph replays):
    // cures any residual read-before-write sensitivity to the 0xAA re-poison.
    size_t arena_bytes = (size_t)(10289152 + 5144576) * sizeof(float);
    if (arena_bytes > ws_size) arena_bytes = ws_size;
    hipMemsetAsync(d_ws, 0, arena_bytes, stream);

    // ---- encoder ----
    conv_launch(x_talking, S0, enc_w0, enc_b0, bufA, 5024, 3, 16, 1, stream);   // e0 (fallback: F=3)
    dsamp_mfma_launch(D0, bufA, bufB, 1257, 5024, 16, stream);                  // d0
    conv_launch(bufB, S1, enc_w1, enc_b1, bufA, 1257, 16, 32, 1, stream);       // e1
    dsamp_mfma_launch(D1, bufA, bufB, 315, 1257, 32, stream);                   // d1
    conv_launch(bufB, S2, enc_w2, enc_b2, bufA, 315, 32, 64, 1, stream);        // e2
    dsamp_launch(D2, bufA, bufB, 80, 315, 64, stream);                          // d2
    conv_launch(bufB, S3, enc_w3, enc_b3, bufA, 80, 64, 128, 1, stream);        // e3
    dsamp_launch(D3, bufA, bufB, 21, 80, 128, stream);                          // d3

    fc_kernel<<<dim3(64, 1), 128, 0, stream>>>(bufB, fc_enc_w, fc_enc_b, bufA, 2688, 128, 0);
    fc_kernel<<<dim3(64, 11), 256, 0, stream>>>(bufA, fc_dec_w, fc_dec_b, bufB, 128, 2688, 1);

    // ---- decoder ----
    dsamp_launch(U3, bufB, bufA, 80, 21, 128, stream);                          // u3
    conv_launch(bufA, S3, dec_w0, dec_b0, bufB, 80, 128, 64, 1, stream);        // c0
    dsamp_launch(U2, bufB, bufA, 315, 80, 64, stream);                          // u2
    conv_launch(bufA, S2, dec_w1, dec_b1, bufB, 315, 64, 32, 1, stream);        // c1
    dsamp_mfma_launch(U1, bufB, bufA, 1257, 315, 32, stream);                   // u1
    conv_launch(bufA, S1, dec_w2, dec_b2, bufB, 1257, 32, 32, 1, stream);       // c2
    dsamp_mfma_launch(U0, bufB, bufA, 5024, 1257, 32, stream);                  // u0
    conv_launch(bufA, S0, dec_w3, dec_b3, bufB, 5024, 32, 16, 1, stream);       // c3
    conv_launch(bufB, S0, dec_w4, dec_b4, out0, 5024, 16, 3, 0, stream);        // c4 (fallback: O=3)

    int n4 = 964608 / 4;
    add_kernel<<<(n4 + 255) / 256, 256, 0, stream>>>(out0, templ, out1, n4);
}

// Round 4
// 2368.806 us; speedup vs baseline: 1.9359x; 1.0473x over previous
//
#include <hip/hip_runtime.h>
#include <cstddef>

// ---------------------------------------------------------------------------
// SpiralAutoencoder on MI355X — round 4:
//  * dsamp MFMA v2: K-split + fp32 atomicAdd (D0 ks=8, D1 ks=8), A-operand
//    direct from global (no A-LDS staging), double-buffered X-LDS, register
//    prefetch, one barrier per K-slab. U0/U1 use same kernel at ks=1.
//  * start-of-launch ws memset kept (replay determinism, proven round 3).
// ---------------------------------------------------------------------------

#define BATCH 64
#define SPK 12  // spiral length

typedef __attribute__((ext_vector_type(8))) short bf16x8;
typedef __attribute__((ext_vector_type(4))) float f32x4;

__device__ __forceinline__ unsigned short f2bf(float x) {
    union { float f; unsigned int u; } v; v.f = x;
    unsigned int r = v.u + 0x7FFF + ((v.u >> 16) & 1);  // RNE
    return (unsigned short)(r >> 16);
}

__device__ __forceinline__ bf16x8 pack8(const float* v) {
    bf16x8 r;
#pragma unroll
    for (int j = 0; j < 8; ++j) r[j] = (short)f2bf(v[j]);
    return r;
}

// ---------------------------------------------------------------------------
// dsamp_mfma2: Y[b,m,f] (+)= sum_{k in chunk} A[m,k] * X[b,k,f]
// GEMM view Y[M, C]=A[M,K]@Xc[K,C], C=64F, c=b*F+f. Grid: (mtiles, F, kchunks).
// 64x64 tile, 4 waves 2x2, each 32x32 via 2x2 mfma_16x16x32_bf16.
// A frags: direct global loads + in-reg bf16 convert (no LDS).
// X tile: LDS [c][k], PAD=40, double-buffered; 1 barrier/slab.
// atomic_flag: accumulate into pre-zeroed Y with atomicAdd (K-split).
// ---------------------------------------------------------------------------
__global__ __launch_bounds__(256) void dsamp_mfma2_kernel(
    const float* __restrict__ A, const float* __restrict__ X,
    float* __restrict__ Y, int M, int K, int logF, int kchunk, int atomic_flag)
{
    constexpr int PAD = 40;
    __shared__ unsigned short Xs[2][64 * PAD];

    const int fmask = (1 << logF) - 1;
    const int m0   = blockIdx.x * 64;
    const int c0   = blockIdx.y * 64;
    const int kbeg = blockIdx.z * kchunk;
    int kend = kbeg + kchunk; if (kend > K) kend = K;
    const int nslab = (kend - kbeg + 31) >> 5;

    const int tid  = threadIdx.x;
    const int lane = tid & 63;
    const int wave = tid >> 6;
    const int wm   = (wave >> 1) * 32;
    const int wn   = (wave & 1) * 32;
    const int l15  = lane & 15;
    const int quad = lane >> 4;

    // X staging coords: slot0 kk=tid>>4, slot1 kk=16+(tid>>4); cols scg..scg+3
    const int skk  = tid >> 4;
    const int scg  = (tid & 15) * 4;
    const int cB   = c0 + scg;
    const int xbb  = cB >> logF;
    const int xf   = cB & fmask;
    const size_t xrowbase = (((size_t)xbb * K) << logF) + xf;

    const int mA0 = m0 + wm + l15;
    const int mA1 = mA0 + 16;
    const int kaoff = quad * 8;

    f32x4 acc[2][2];
    acc[0][0] = acc[0][1] = acc[1][0] = acc[1][1] = (f32x4){0.f, 0.f, 0.f, 0.f};

    float4 xn0, xn1;
    float ac0[8], ac1[8], an0[8], an1[8];

    // ---- prologue: slab 0 ----
    {
        int k = kbeg + skk;
        xn0 = make_float4(0.f, 0.f, 0.f, 0.f);
        if (k < kend) xn0 = *(const float4*)(X + xrowbase + ((size_t)k << logF));
        k = kbeg + 16 + skk;
        xn1 = make_float4(0.f, 0.f, 0.f, 0.f);
        if (k < kend) xn1 = *(const float4*)(X + xrowbase + ((size_t)k << logF));
        int ka = kbeg + kaoff;
#pragma unroll
        for (int j = 0; j < 8; ++j) {
            ac0[j] = (mA0 < M && ka + j < kend) ? A[(size_t)mA0 * K + ka + j] : 0.f;
            ac1[j] = (mA1 < M && ka + j < kend) ? A[(size_t)mA1 * K + ka + j] : 0.f;
        }
        unsigned short* p = &Xs[0][0];
        p[(scg + 0) * PAD + skk] = f2bf(xn0.x);
        p[(scg + 1) * PAD + skk] = f2bf(xn0.y);
        p[(scg + 2) * PAD + skk] = f2bf(xn0.z);
        p[(scg + 3) * PAD + skk] = f2bf(xn0.w);
        int kk1 = 16 + skk;
        p[(scg + 0) * PAD + kk1] = f2bf(xn1.x);
        p[(scg + 1) * PAD + kk1] = f2bf(xn1.y);
        p[(scg + 2) * PAD + kk1] = f2bf(xn1.z);
        p[(scg + 3) * PAD + kk1] = f2bf(xn1.w);
    }
    __syncthreads();

    for (int s = 0; s < nslab; ++s) {
        const int cur = s & 1;
        const bool more = (s + 1 < nslab);
        // ---- prefetch slab s+1 into registers ----
        if (more) {
            int k0 = kbeg + (s + 1) * 32;
            int k = k0 + skk;
            xn0 = make_float4(0.f, 0.f, 0.f, 0.f);
            if (k < kend) xn0 = *(const float4*)(X + xrowbase + ((size_t)k << logF));
            k = k0 + 16 + skk;
            xn1 = make_float4(0.f, 0.f, 0.f, 0.f);
            if (k < kend) xn1 = *(const float4*)(X + xrowbase + ((size_t)k << logF));
            int ka = k0 + kaoff;
#pragma unroll
            for (int j = 0; j < 8; ++j) {
                an0[j] = (mA0 < M && ka + j < kend) ? A[(size_t)mA0 * K + ka + j] : 0.f;
                an1[j] = (mA1 < M && ka + j < kend) ? A[(size_t)mA1 * K + ka + j] : 0.f;
            }
        }
        // ---- compute slab s ----
        {
            const unsigned short* p = &Xs[cur][0];
            bf16x8 b0 = *(const bf16x8*)&p[(wn +      l15) * PAD + quad * 8];
            bf16x8 b1 = *(const bf16x8*)&p[(wn + 16 + l15) * PAD + quad * 8];
            bf16x8 a0 = pack8(ac0);
            bf16x8 a1 = pack8(ac1);
            acc[0][0] = __builtin_amdgcn_mfma_f32_16x16x32_bf16(a0, b0, acc[0][0], 0, 0, 0);
            acc[0][1] = __builtin_amdgcn_mfma_f32_16x16x32_bf16(a0, b1, acc[0][1], 0, 0, 0);
            acc[1][0] = __builtin_amdgcn_mfma_f32_16x16x32_bf16(a1, b0, acc[1][0], 0, 0, 0);
            acc[1][1] = __builtin_amdgcn_mfma_f32_16x16x32_bf16(a1, b1, acc[1][1], 0, 0, 0);
        }
        // ---- write prefetched X to other buffer; single barrier ----
        if (more) {
            unsigned short* q = &Xs[cur ^ 1][0];
            q[(scg + 0) * PAD + skk] = f2bf(xn0.x);
            q[(scg + 1) * PAD + skk] = f2bf(xn0.y);
            q[(scg + 2) * PAD + skk] = f2bf(xn0.z);
            q[(scg + 3) * PAD + skk] = f2bf(xn0.w);
            int kk1 = 16 + skk;
            q[(scg + 0) * PAD + kk1] = f2bf(xn1.x);
            q[(scg + 1) * PAD + kk1] = f2bf(xn1.y);
            q[(scg + 2) * PAD + kk1] = f2bf(xn1.z);
            q[(scg + 3) * PAD + kk1] = f2bf(xn1.w);
            __syncthreads();
#pragma unroll
            for (int j = 0; j < 8; ++j) { ac0[j] = an0[j]; ac1[j] = an1[j]; }
        }
    }

    // ---- epilogue: C/D layout col=lane&15, row=quad*4+reg ----
#pragma unroll
    for (int tm = 0; tm < 2; ++tm)
#pragma unroll
        for (int tn = 0; tn < 2; ++tn)
#pragma unroll
            for (int reg = 0; reg < 4; ++reg) {
                int m  = m0 + wm + tm * 16 + quad * 4 + reg;
                int cc = c0 + wn + tn * 16 + l15;
                if (m < M) {
                    int bb = cc >> logF, f = cc & fmask;
                    float* dst = Y + (((size_t)bb * M + m) << logF) + f;
                    if (atomic_flag) atomicAdd(dst, acc[tm][tn][reg]);
                    else *dst = acc[tm][tn][reg];
                }
            }
}

// ---------------------------------------------------------------------------
// conv_gemm (unchanged — verified)
// ---------------------------------------------------------------------------
template<int MT, int OT>
__global__ __launch_bounds__(256) void conv_gemm_kernel(
    const float* __restrict__ x, const int* __restrict__ S,
    const float* __restrict__ W, const float* __restrict__ bias,
    float* __restrict__ y, int Nv, int logF, int O, int KF, int elu_flag)
{
    constexpr int CT = OT / 4;
    constexpr int RT = 256 / CT;
    static_assert(RT * 4 == MT, "tile shape");
    __shared__ float Gs[32][MT];
    __shared__ float Ws[32][OT];

    const int b   = blockIdx.y;
    const int n0  = blockIdx.x * MT;
    const int tid = threadIdx.x;
    const int cx  = tid % CT;
    const int ry  = tid / CT;
    const int r0  = ry * 4;
    const int o0  = cx * 4;
    const int fmask = (1 << logF) - 1;
    const size_t xb = (size_t)b * Nv;

    float acc[4][4];
#pragma unroll
    for (int i = 0; i < 4; ++i)
#pragma unroll
        for (int j = 0; j < 4; ++j) acc[i][j] = 0.f;

    for (int k0 = 0; k0 < KF; k0 += 32) {
        constexpr int GSLOTS = MT * 8;
#pragma unroll
        for (int i = 0; i < GSLOTS / 256; ++i) {
            int idx = tid + i * 256;
            int r   = idx & (MT - 1);
            int jg  = idx / MT;
            int j0  = jg * 4;
            int n   = n0 + r;
            float4 v = make_float4(0.f, 0.f, 0.f, 0.f);
            if (n < Nv) {
                int kf  = k0 + j0;
                int k   = kf >> logF;
                int f   = kf & fmask;
                int src = S[n * SPK + k];
                v = *(const float4*)(x + ((xb + src) << logF) + f);
            }
            Gs[j0 + 0][r] = v.x; Gs[j0 + 1][r] = v.y;
            Gs[j0 + 2][r] = v.z; Gs[j0 + 3][r] = v.w;
        }
        constexpr int WSLOTS = OT * 8;
#pragma unroll
        for (int i = 0; i < (WSLOTS + 255) / 256; ++i) {
            int idx = tid + i * 256;
            if (WSLOTS >= 256 || idx < WSLOTS) {
                int o  = idx & (OT - 1);
                int jg = idx / OT;
                int j0 = jg * 4;
                float4 v = *(const float4*)(W + (size_t)o * KF + k0 + j0);
                Ws[j0 + 0][o] = v.x; Ws[j0 + 1][o] = v.y;
                Ws[j0 + 2][o] = v.z; Ws[j0 + 3][o] = v.w;
            }
        }
        __syncthreads();
#pragma unroll
        for (int kk = 0; kk < 32; ++kk) {
            float4 g = *(const float4*)&Gs[kk][r0];
            float4 w = *(const float4*)&Ws[kk][o0];
            acc[0][0] += g.x * w.x; acc[0][1] += g.x * w.y; acc[0][2] += g.x * w.z; acc[0][3] += g.x * w.w;
            acc[1][0] += g.y * w.x; acc[1][1] += g.y * w.y; acc[1][2] += g.y * w.z; acc[1][3] += g.y * w.w;
            acc[2][0] += g.z * w.x; acc[2][1] += g.z * w.y; acc[2][2] += g.z * w.z; acc[2][3] += g.z * w.w;
            acc[3][0] += g.w * w.x; acc[3][1] += g.w * w.y; acc[3][2] += g.w * w.z; acc[3][3] += g.w * w.w;
        }
        __syncthreads();
    }

    float4 bv = *(const float4*)(bias + o0);
#pragma unroll
    for (int i = 0; i < 4; ++i) {
        int n = n0 + r0 + i;
        if (n >= Nv) continue;
        float v0 = acc[i][0] + bv.x;
        float v1 = acc[i][1] + bv.y;
        float v2 = acc[i][2] + bv.z;
        float v3 = acc[i][3] + bv.w;
        if (elu_flag) {
            v0 = v0 > 0.f ? v0 : expm1f(v0);
            v1 = v1 > 0.f ? v1 : expm1f(v1);
            v2 = v2 > 0.f ? v2 : expm1f(v2);
            v3 = v3 > 0.f ? v3 : expm1f(v3);
        }
        if (n == Nv - 1) { v0 = v1 = v2 = v3 = 0.f; }
        *(float4*)(y + ((size_t)b * Nv + n) * O + o0) = make_float4(v0, v1, v2, v3);
    }
}

// ---------------------------------------------------------------------------
// Fallback spiral conv (F=3 or O=3 layers only).
// ---------------------------------------------------------------------------
__global__ __launch_bounds__(256) void spiral_conv_kernel(
    const float* __restrict__ x, const int* __restrict__ S,
    const float* __restrict__ W, const float* __restrict__ bias,
    float* __restrict__ y, int Nv, int F, int O, int KF, int NT, int elu_flag)
{
    __shared__ float g[8192];
    const int b   = blockIdx.y;
    const int n0  = blockIdx.x * NT;
    const int tid = threadIdx.x;

    const int total = NT * KF;
    for (int j = tid; j < total; j += 256) {
        int r  = j / KF;
        int jj = j - r * KF;
        int n  = n0 + r;
        if (n < Nv) {
            int k = jj / F;
            int f = jj - k * F;
            int src = S[n * SPK + k];
            g[j] = x[((size_t)b * Nv + src) * F + f];
        }
    }
    __syncthreads();

    const int outs = NT * O;
    for (int t = tid; t < outs; t += 256) {
        int r = t / O;
        int o = t - r * O;
        int n = n0 + r;
        if (n >= Nv) continue;
        float res;
        if (n == Nv - 1) {
            res = 0.f;
        } else {
            const float* wrow = W + (size_t)o * KF;
            const float* grow = g + r * KF;
            float a0 = 0.f, a1 = 0.f, a2 = 0.f, a3 = 0.f;
            for (int j = 0; j < KF; j += 4) {
                float4 wv = *(const float4*)(wrow + j);
                float4 gv = *(const float4*)(grow + j);
                a0 += wv.x * gv.x;
                a1 += wv.y * gv.y;
                a2 += wv.z * gv.z;
                a3 += wv.w * gv.w;
            }
            float accv = (a0 + a1) + (a2 + a3) + bias[o];
            res = (elu_flag && accv <= 0.f) ? expm1f(accv) : accv;
        }
        y[((size_t)b * Nv + n) * O + o] = res;
    }
}

// ---------------------------------------------------------------------------
// VALU down/up-sample (small levels 2-3 only).
// ---------------------------------------------------------------------------
__global__ __launch_bounds__(256) void dsamp_kernel(
    const float* __restrict__ A, const float* __restrict__ X,
    float* __restrict__ Y, int M, int N, int F)
{
    __shared__ float As[16][68];
    __shared__ float Xs[16][64];

    const int m0  = blockIdx.x * 64;
    const int c0  = blockIdx.y * 64;
    const int tid = threadIdx.x;
    const int tx  = tid & 15;
    const int ty  = tid >> 4;

    float acc[4][4];
#pragma unroll
    for (int i = 0; i < 4; ++i)
#pragma unroll
        for (int j = 0; j < 4; ++j) acc[i][j] = 0.f;

    for (int k0 = 0; k0 < N; k0 += 16) {
#pragma unroll
        for (int p = 0; p < 4; ++p) {
            int r  = (tid >> 4) + p * 16;
            int kk = tid & 15;
            int m  = m0 + r;
            int n  = k0 + kk;
            float v = 0.f;
            if (m < M && n < N) v = A[(size_t)m * N + n];
            As[kk][r] = v;
        }
        {
            int kk = tid >> 4;
            int cc = (tid & 15) * 4;
            int n  = k0 + kk;
            float4 v = make_float4(0.f, 0.f, 0.f, 0.f);
            if (n < N) {
                int c  = c0 + cc;
                int bb = c / F;
                int f  = c - bb * F;
                v = *(const float4*)(X + ((size_t)bb * N + n) * F + f);
            }
            *(float4*)&Xs[kk][cc] = v;
        }
        __syncthreads();
#pragma unroll
        for (int kk = 0; kk < 16; ++kk) {
            float4 av = *(const float4*)&As[kk][ty * 4];
            float4 xv = *(const float4*)&Xs[kk][tx * 4];
            acc[0][0] += av.x * xv.x; acc[0][1] += av.x * xv.y; acc[0][2] += av.x * xv.z; acc[0][3] += av.x * xv.w;
            acc[1][0] += av.y * xv.x; acc[1][1] += av.y * xv.y; acc[1][2] += av.y * xv.z; acc[1][3] += av.y * xv.w;
            acc[2][0] += av.z * xv.x; acc[2][1] += av.z * xv.y; acc[2][2] += av.z * xv.z; acc[2][3] += av.z * xv.w;
            acc[3][0] += av.w * xv.x; acc[3][1] += av.w * xv.y; acc[3][2] += av.w * xv.z; acc[3][3] += av.w * xv.w;
        }
        __syncthreads();
    }

    const int cbase = c0 + tx * 4;
    const int bb = cbase / F;
    const int f  = cbase - bb * F;
#pragma unroll
    for (int i = 0; i < 4; ++i) {
        int m = m0 + ty * 4 + i;
        if (m < M) {
            float4 v = make_float4(acc[i][0], acc[i][1], acc[i][2], acc[i][3]);
            *(float4*)(Y + ((size_t)bb * M + m) * F + f) = v;
        }
    }
}

// ---------------------------------------------------------------------------
__global__ __launch_bounds__(256) void fc_kernel(
    const float* __restrict__ in, const float* __restrict__ W,
    const float* __restrict__ bias, float* __restrict__ out,
    int In, int O, int dup)
{
    int b = blockIdx.x;
    int o = blockIdx.y * blockDim.x + threadIdx.x;
    if (o >= O) return;
    const float* xr = in + (size_t)b * In;
    const int wstride = dup ? 2 * In : In;
    const float* wr = W + (size_t)o * wstride;
    float acc = bias[o];
    if (dup) {
        for (int k = 0; k < In; ++k) acc += xr[k] * (wr[k] + wr[In + k]);
    } else {
        for (int k = 0; k < In; ++k) acc += xr[k] * wr[k];
    }
    out[(size_t)b * O + o] = acc;
}

__global__ __launch_bounds__(256) void add_kernel(
    const float* __restrict__ a, const float* __restrict__ t,
    float* __restrict__ o, int n4)
{
    int i = blockIdx.x * blockDim.x + threadIdx.x;
    if (i < n4) {
        float4 av = ((const float4*)a)[i];
        float4 tv = ((const float4*)t)[i];
        ((float4*)o)[i] = make_float4(av.x + tv.x, av.y + tv.y, av.z + tv.z, av.w + tv.w);
    }
}

// ---------------------------------------------------------------------------

static inline int ilog2(int v) { int l = 0; while ((1 << l) < v) ++l; return l; }

static inline void conv_launch(const float* x, const int* S, const float* W,
                               const float* b, float* y, int Nv, int F, int O,
                               int elu, hipStream_t s)
{
    int KF = SPK * F;
    if ((F & (F - 1)) == 0 && F >= 16 && (O == 16 || O == 32 || O == 64 || O == 128)) {
        int logF = ilog2(F);
        if (O == 16) {
            dim3 grid((Nv + 255) / 256, BATCH);
            conv_gemm_kernel<256, 16><<<grid, 256, 0, s>>>(x, S, W, b, y, Nv, logF, O, KF, elu);
        } else if (O == 32) {
            dim3 grid((Nv + 127) / 128, BATCH);
            conv_gemm_kernel<128, 32><<<grid, 256, 0, s>>>(x, S, W, b, y, Nv, logF, O, KF, elu);
        } else if (O == 64) {
            dim3 grid((Nv + 63) / 64, BATCH);
            conv_gemm_kernel<64, 64><<<grid, 256, 0, s>>>(x, S, W, b, y, Nv, logF, O, KF, elu);
        } else {
            dim3 grid((Nv + 31) / 32, BATCH);
            conv_gemm_kernel<32, 128><<<grid, 256, 0, s>>>(x, S, W, b, y, Nv, logF, O, KF, elu);
        }
        return;
    }
    int nt_o = 256 / O; if (nt_o < 1) nt_o = 1;
    int nt_l = 8192 / KF;
    int NT = nt_o < nt_l ? nt_o : nt_l;
    if (NT < 1) NT = 1;
    dim3 grid((Nv + NT - 1) / NT, BATCH);
    spiral_conv_kernel<<<grid, 256, 0, s>>>(x, S, W, b, y, Nv, F, O, KF, NT, elu);
}

// MFMA resample; ks = K-split factor (>1 requires Y pre-zeroed; atomic adds)
static inline void dsamp_mfma2_launch(const float* A, const float* X, float* Y,
                                      int M, int K, int F, int ks, hipStream_t s)
{
    int kchunk = (K + ks - 1) / ks;
    kchunk = (kchunk + 31) & ~31;
    int ksz = (K + kchunk - 1) / kchunk;
    dim3 grid((M + 63) / 64, F, ksz);
    dsamp_mfma2_kernel<<<grid, 256, 0, s>>>(A, X, Y, M, K, ilog2(F), kchunk, ksz > 1 ? 1 : 0);
}

static inline void dsamp_launch(const float* A, const float* X, float* Y,
                                int M, int N, int F, hipStream_t s)
{
    dim3 grid((M + 63) / 64, F);
    dsamp_kernel<<<grid, 256, 0, s>>>(A, X, Y, M, N, F);
}

extern "C" void kernel_launch(void* const* d_in, const int* in_sizes, int n_in,
                              void* d_out, int out_size, void* d_ws, size_t ws_size,
                              hipStream_t stream)
{
    const float* x_talking = (const float*)d_in[0];
    const float* templ     = (const float*)d_in[1];
    const float* D0 = (const float*)d_in[2];
    const float* U0 = (const float*)d_in[3];
    const float* D1 = (const float*)d_in[4];
    const float* U1 = (const float*)d_in[5];
    const float* D2 = (const float*)d_in[6];
    const float* U2 = (const float*)d_in[7];
    const float* D3 = (const float*)d_in[8];
    const float* U3 = (const float*)d_in[9];
    const float* enc_w0 = (const float*)d_in[10]; const float* enc_b0 = (const float*)d_in[11];
    const float* enc_w1 = (const float*)d_in[12]; const float* enc_b1 = (const float*)d_in[13];
    const float* enc_w2 = (const float*)d_in[14]; const float* enc_b2 = (const float*)d_in[15];
    const float* enc_w3 = (const float*)d_in[16]; const float* enc_b3 = (const float*)d_in[17];
    const float* fc_enc_w = (const float*)d_in[18]; const float* fc_enc_b = (const float*)d_in[19];
    const float* fc_dec_w = (const float*)d_in[20]; const float* fc_dec_b = (const float*)d_in[21];
    const float* dec_w0 = (const float*)d_in[22]; const float* dec_b0 = (const float*)d_in[23];
    const float* dec_w1 = (const float*)d_in[24]; const float* dec_b1 = (const float*)d_in[25];
    const float* dec_w2 = (const float*)d_in[26]; const float* dec_b2 = (const float*)d_in[27];
    const float* dec_w3 = (const float*)d_in[28]; const float* dec_b3 = (const float*)d_in[29];
    const float* dec_w4 = (const float*)d_in[30]; const float* dec_b4 = (const float*)d_in[31];
    const int* S0 = (const int*)d_in[32];
    const int* S1 = (const int*)d_in[33];
    const int* S2 = (const int*)d_in[34];
    const int* S3 = (const int*)d_in[35];

    float* bufA = (float*)d_ws;            // 10,289,152 floats
    float* bufB = bufA + 10289152;         // 5,144,576 floats

    float* out0 = (float*)d_out;           // 964,608 floats
    float* out1 = out0 + 964608;

    // Deterministic ws initial state (replay correctness) + zeroes d0's
    // atomic-accumulation target (bufB is virgin until d0).
    size_t arena_bytes = (size_t)(10289152 + 5144576) * sizeof(float);
    if (arena_bytes > ws_size) arena_bytes = ws_size;
    hipMemsetAsync(d_ws, 0, arena_bytes, stream);

    // ---- encoder ----
    conv_launch(x_talking, S0, enc_w0, enc_b0, bufA, 5024, 3, 16, 1, stream);   // e0 (fallback: F=3)
    dsamp_mfma2_launch(D0, bufA, bufB, 1257, 5024, 16, 8, stream);              // d0 [atomic ks=8]
    conv_launch(bufB, S1, enc_w1, enc_b1, bufA, 1257, 16, 32, 1, stream);       // e1
    hipMemsetAsync(bufB, 0, (size_t)645120 * sizeof(float), stream);            // zero d1 target
    dsamp_mfma2_launch(D1, bufA, bufB, 315, 1257, 32, 8, stream);               // d1 [atomic ks=8]
    conv_launch(bufB, S2, enc_w2, enc_b2, bufA, 315, 32, 64, 1, stream);        // e2
    dsamp_launch(D2, bufA, bufB, 80, 315, 64, stream);                          // d2
    conv_launch(bufB, S3, enc_w3, enc_b3, bufA, 80, 64, 128, 1, stream);        // e3
    dsamp_launch(D3, bufA, bufB, 21, 80, 128, stream);                          // d3

    fc_kernel<<<dim3(64, 1), 128, 0, stream>>>(bufB, fc_enc_w, fc_enc_b, bufA, 2688, 128, 0);
    fc_kernel<<<dim3(64, 11), 256, 0, stream>>>(bufA, fc_dec_w, fc_dec_b, bufB, 128, 2688, 1);

    // ---- decoder ----
    dsamp_launch(U3, bufB, bufA, 80, 21, 128, stream);                          // u3
    conv_launch(bufA, S3, dec_w0, dec_b0, bufB, 80, 128, 64, 1, stream);        // c0
    dsamp_launch(U2, bufB, bufA, 315, 80, 64, stream);                          // u2
    conv_launch(bufA, S2, dec_w1, dec_b1, bufB, 315, 64, 32, 1, stream);        // c1
    dsamp_mfma2_launch(U1, bufB, bufA, 1257, 315, 32, 1, stream);               // u1 (plain)
    conv_launch(bufA, S1, dec_w2, dec_b2, bufB, 1257, 32, 32, 1, stream);       // c2
    dsamp_mfma2_launch(U0, bufB, bufA, 5024, 1257, 32, 1, stream);              // u0 (plain)
    conv_launch(bufA, S0, dec_w3, dec_b3, bufB, 5024, 32, 16, 1, stream);       // c3
    conv_launch(bufB, S0, dec_w4, dec_b4, out0, 5024, 16, 3, 0, stream);        // c4 (fallback: O=3)

    int n4 = 964608 / 4;
    add_kernel<<<(n4 + 255) / 256, 256, 0, stream>>>(out0, templ, out1, n4);
}

// Round 5
// 1652.188 us; speedup vs baseline: 2.7756x; 1.4337x over previous
//
#include <hip/hip_runtime.h>
#include <cstddef>

// ---------------------------------------------------------------------------
// SpiralAutoencoder on MI355X — round 5:
//  * D0/U0 GEMMs -> dsamp_mfma3: 128x128 tile, coalesced fp32->bf16 A staging,
//    pre-transposed bf16 Xt[c][k] B operand, double-buffered LDS, k-split.
//  * fallback spiral convs (e0, c4): W staged in LDS (kills W re-stream).
//  * D1/U1 stay on proven dsamp_mfma2; conv_gemm unchanged.
// ---------------------------------------------------------------------------

#define BATCH 64
#define SPK 12  // spiral length

typedef __attribute__((ext_vector_type(8))) short bf16x8;
typedef __attribute__((ext_vector_type(4))) short bf16x4;
typedef __attribute__((ext_vector_type(4))) float f32x4;

__device__ __forceinline__ unsigned short f2bf(float x) {
    union { float f; unsigned int u; } v; v.f = x;
    unsigned int r = v.u + 0x7FFF + ((v.u >> 16) & 1);  // RNE
    return (unsigned short)(r >> 16);
}

__device__ __forceinline__ bf16x8 pack8(const float* v) {
    bf16x8 r;
#pragma unroll
    for (int j = 0; j < 8; ++j) r[j] = (short)f2bf(v[j]);
    return r;
}

// ---------------------------------------------------------------------------
// Transpose-convert: x [b][k][f] fp32 -> xt [c][k] bf16, c = b*F+f, stride Kp.
// Pads k in [K, Kp) with zeros. Reads coalesced along c, writes 16B rows.
// ---------------------------------------------------------------------------
__global__ __launch_bounds__(256) void xpose_bf16_kernel(
    const float* __restrict__ x, unsigned short* __restrict__ xt,
    int K, int Kp, int logF)
{
    const int c  = blockIdx.y * 256 + threadIdx.x;
    const int k0 = blockIdx.x * 8;
    const int bb = c >> logF;
    const int f  = c & ((1 << logF) - 1);
    const float* src = x + (((size_t)bb * K) << logF) + f;
    bf16x8 r;
#pragma unroll
    for (int j = 0; j < 8; ++j) {
        int k = k0 + j;
        float v = (k < K) ? src[(size_t)k << logF] : 0.f;
        r[j] = (short)f2bf(v);
    }
    *(bf16x8*)(xt + (size_t)c * Kp + k0) = r;
}

// ---------------------------------------------------------------------------
// dsamp_mfma3: Y[b,m,f] (+)= sum_k A[m,k] * X[b,k,f]
//   A: fp32 [M x K]; Xt: bf16 [C x Kp] (pre-transposed); Y: fp32 [b][m][f].
// 128x128 block tile, BK=32, 4 waves (2x2) each 64x64 via 4x4 mfma 16x16x32.
// Coalesced A tile loads (float4, 8 lanes/row), bf16 conversion at LDS write.
// Double-buffered LDS + register prefetch; one barrier per slab.
// ---------------------------------------------------------------------------
__global__ __launch_bounds__(256) void dsamp_mfma3_kernel(
    const float* __restrict__ A, const unsigned short* __restrict__ Xt,
    float* __restrict__ Y, int M, int K, int Kp, int logF, int kchunk,
    int atomic_flag)
{
    constexpr int PAD = 40;
    __shared__ unsigned short As[2][128 * PAD];
    __shared__ unsigned short Bs[2][128 * PAD];

    const int fmask = (1 << logF) - 1;
    const int m0   = blockIdx.x * 128;
    const int c0   = blockIdx.y * 128;
    const int kbeg = blockIdx.z * kchunk;
    int kend = kbeg + kchunk; if (kend > Kp) kend = Kp;
    const int nslab = (kend - kbeg + 31) >> 5;

    const int tid  = threadIdx.x;
    const int lane = tid & 63;
    const int wave = tid >> 6;
    const int wm   = (wave >> 1) * 64;
    const int wn   = (wave & 1) * 64;
    const int l15  = lane & 15;
    const int quad = lane >> 4;

    // A staging: 1024 float4 slots (128 rows x 8): row=idx>>3, k4=(idx&7)*4
    const int ar_row = tid >> 3;        // 0..31 (+32 per iter)
    const int ar_k4  = (tid & 7) * 4;
    // B staging: 512 bf16x8 slots (128 rows x 4): row=idx>>2, k8=(idx&3)*8
    const int br_row = tid >> 2;        // 0..63 (+64 per iter)
    const int br_k8  = (tid & 3) * 8;

    f32x4 acc[4][4];
#pragma unroll
    for (int i = 0; i < 4; ++i)
#pragma unroll
        for (int j = 0; j < 4; ++j) acc[i][j] = (f32x4){0.f, 0.f, 0.f, 0.f};

    float4 apre[4];
    bf16x8 bpre[2];

    auto loadAB = [&](int ko) {
#pragma unroll
        for (int i = 0; i < 4; ++i) {
            int m = m0 + ar_row + i * 32;
            int k = ko + ar_k4;
            float4 v = make_float4(0.f, 0.f, 0.f, 0.f);
            if (m < M) {
                const float* ap = A + (size_t)m * K;
                if (k + 3 < K) v = *(const float4*)(ap + k);
                else {
                    v.x = (k     < K) ? ap[k]     : 0.f;
                    v.y = (k + 1 < K) ? ap[k + 1] : 0.f;
                    v.z = (k + 2 < K) ? ap[k + 2] : 0.f;
                    v.w = (k + 3 < K) ? ap[k + 3] : 0.f;
                }
            }
            apre[i] = v;
        }
#pragma unroll
        for (int i = 0; i < 2; ++i)
            bpre[i] = *(const bf16x8*)(Xt + (size_t)(c0 + br_row + i * 64) * Kp + ko + br_k8);
    };
    auto stage = [&](int buf) {
#pragma unroll
        for (int i = 0; i < 4; ++i) {
            bf16x4 t;
            t[0] = (short)f2bf(apre[i].x);
            t[1] = (short)f2bf(apre[i].y);
            t[2] = (short)f2bf(apre[i].z);
            t[3] = (short)f2bf(apre[i].w);
            *(bf16x4*)&As[buf][(ar_row + i * 32) * PAD + ar_k4] = t;
        }
#pragma unroll
        for (int i = 0; i < 2; ++i)
            *(bf16x8*)&Bs[buf][(br_row + i * 64) * PAD + br_k8] = bpre[i];
    };

    loadAB(kbeg);
    stage(0);
    __syncthreads();

    for (int s = 0; s < nslab; ++s) {
        const int cur = s & 1;
        const bool more = (s + 1) < nslab;
        if (more) loadAB(kbeg + (s + 1) * 32);

        bf16x8 af[4], bfr[4];
#pragma unroll
        for (int t = 0; t < 4; ++t) {
            af[t]  = *(const bf16x8*)&As[cur][(wm + t * 16 + l15) * PAD + quad * 8];
            bfr[t] = *(const bf16x8*)&Bs[cur][(wn + t * 16 + l15) * PAD + quad * 8];
        }
#pragma unroll
        for (int tm = 0; tm < 4; ++tm)
#pragma unroll
            for (int tn = 0; tn < 4; ++tn)
                acc[tm][tn] = __builtin_amdgcn_mfma_f32_16x16x32_bf16(af[tm], bfr[tn], acc[tm][tn], 0, 0, 0);

        if (more) { stage(cur ^ 1); __syncthreads(); }
    }

    // epilogue: C/D layout col=lane&15, row=quad*4+reg
#pragma unroll
    for (int tm = 0; tm < 4; ++tm)
#pragma unroll
        for (int tn = 0; tn < 4; ++tn)
#pragma unroll
            for (int reg = 0; reg < 4; ++reg) {
                int m  = m0 + wm + tm * 16 + quad * 4 + reg;
                int cc = c0 + wn + tn * 16 + l15;
                if (m < M) {
                    int bb = cc >> logF, f = cc & fmask;
                    float* dst = Y + (((size_t)bb * M + m) << logF) + f;
                    if (atomic_flag) atomicAdd(dst, acc[tm][tn][reg]);
                    else *dst = acc[tm][tn][reg];
                }
            }
}

// ---------------------------------------------------------------------------
// dsamp_mfma2 (round-4, proven): kept for D1/U1 (small K, small A).
// ---------------------------------------------------------------------------
__global__ __launch_bounds__(256) void dsamp_mfma2_kernel(
    const float* __restrict__ A, const float* __restrict__ X,
    float* __restrict__ Y, int M, int K, int logF, int kchunk, int atomic_flag)
{
    constexpr int PAD = 40;
    __shared__ unsigned short Xs[2][64 * PAD];

    const int fmask = (1 << logF) - 1;
    const int m0   = blockIdx.x * 64;
    const int c0   = blockIdx.y * 64;
    const int kbeg = blockIdx.z * kchunk;
    int kend = kbeg + kchunk; if (kend > K) kend = K;
    const int nslab = (kend - kbeg + 31) >> 5;

    const int tid  = threadIdx.x;
    const int lane = tid & 63;
    const int wave = tid >> 6;
    const int wm   = (wave >> 1) * 32;
    const int wn   = (wave & 1) * 32;
    const int l15  = lane & 15;
    const int quad = lane >> 4;

    const int skk  = tid >> 4;
    const int scg  = (tid & 15) * 4;
    const int cB   = c0 + scg;
    const int xbb  = cB >> logF;
    const int xf   = cB & fmask;
    const size_t xrowbase = (((size_t)xbb * K) << logF) + xf;

    const int mA0 = m0 + wm + l15;
    const int mA1 = mA0 + 16;
    const int kaoff = quad * 8;

    f32x4 acc[2][2];
    acc[0][0] = acc[0][1] = acc[1][0] = acc[1][1] = (f32x4){0.f, 0.f, 0.f, 0.f};

    float4 xn0, xn1;
    float ac0[8], ac1[8], an0[8], an1[8];

    {
        int k = kbeg + skk;
        xn0 = make_float4(0.f, 0.f, 0.f, 0.f);
        if (k < kend) xn0 = *(const float4*)(X + xrowbase + ((size_t)k << logF));
        k = kbeg + 16 + skk;
        xn1 = make_float4(0.f, 0.f, 0.f, 0.f);
        if (k < kend) xn1 = *(const float4*)(X + xrowbase + ((size_t)k << logF));
        int ka = kbeg + kaoff;
#pragma unroll
        for (int j = 0; j < 8; ++j) {
            ac0[j] = (mA0 < M && ka + j < kend) ? A[(size_t)mA0 * K + ka + j] : 0.f;
            ac1[j] = (mA1 < M && ka + j < kend) ? A[(size_t)mA1 * K + ka + j] : 0.f;
        }
        unsigned short* p = &Xs[0][0];
        p[(scg + 0) * PAD + skk] = f2bf(xn0.x);
        p[(scg + 1) * PAD + skk] = f2bf(xn0.y);
        p[(scg + 2) * PAD + skk] = f2bf(xn0.z);
        p[(scg + 3) * PAD + skk] = f2bf(xn0.w);
        int kk1 = 16 + skk;
        p[(scg + 0) * PAD + kk1] = f2bf(xn1.x);
        p[(scg + 1) * PAD + kk1] = f2bf(xn1.y);
        p[(scg + 2) * PAD + kk1] = f2bf(xn1.z);
        p[(scg + 3) * PAD + kk1] = f2bf(xn1.w);
    }
    __syncthreads();

    for (int s = 0; s < nslab; ++s) {
        const int cur = s & 1;
        const bool more = (s + 1 < nslab);
        if (more) {
            int k0 = kbeg + (s + 1) * 32;
            int k = k0 + skk;
            xn0 = make_float4(0.f, 0.f, 0.f, 0.f);
            if (k < kend) xn0 = *(const float4*)(X + xrowbase + ((size_t)k << logF));
            k = k0 + 16 + skk;
            xn1 = make_float4(0.f, 0.f, 0.f, 0.f);
            if (k < kend) xn1 = *(const float4*)(X + xrowbase + ((size_t)k << logF));
            int ka = k0 + kaoff;
#pragma unroll
            for (int j = 0; j < 8; ++j) {
                an0[j] = (mA0 < M && ka + j < kend) ? A[(size_t)mA0 * K + ka + j] : 0.f;
                an1[j] = (mA1 < M && ka + j < kend) ? A[(size_t)mA1 * K + ka + j] : 0.f;
            }
        }
        {
            const unsigned short* p = &Xs[cur][0];
            bf16x8 b0 = *(const bf16x8*)&p[(wn +      l15) * PAD + quad * 8];
            bf16x8 b1 = *(const bf16x8*)&p[(wn + 16 + l15) * PAD + quad * 8];
            bf16x8 a0 = pack8(ac0);
            bf16x8 a1 = pack8(ac1);
            acc[0][0] = __builtin_amdgcn_mfma_f32_16x16x32_bf16(a0, b0, acc[0][0], 0, 0, 0);
            acc[0][1] = __builtin_amdgcn_mfma_f32_16x16x32_bf16(a0, b1, acc[0][1], 0, 0, 0);
            acc[1][0] = __builtin_amdgcn_mfma_f32_16x16x32_bf16(a1, b0, acc[1][0], 0, 0, 0);
            acc[1][1] = __builtin_amdgcn_mfma_f32_16x16x32_bf16(a1, b1, acc[1][1], 0, 0, 0);
        }
        if (more) {
            unsigned short* q = &Xs[cur ^ 1][0];
            q[(scg + 0) * PAD + skk] = f2bf(xn0.x);
            q[(scg + 1) * PAD + skk] = f2bf(xn0.y);
            q[(scg + 2) * PAD + skk] = f2bf(xn0.z);
            q[(scg + 3) * PAD + skk] = f2bf(xn0.w);
            int kk1 = 16 + skk;
            q[(scg + 0) * PAD + kk1] = f2bf(xn1.x);
            q[(scg + 1) * PAD + kk1] = f2bf(xn1.y);
            q[(scg + 2) * PAD + kk1] = f2bf(xn1.z);
            q[(scg + 3) * PAD + kk1] = f2bf(xn1.w);
            __syncthreads();
#pragma unroll
            for (int j = 0; j < 8; ++j) { ac0[j] = an0[j]; ac1[j] = an1[j]; }
        }
    }

#pragma unroll
    for (int tm = 0; tm < 2; ++tm)
#pragma unroll
        for (int tn = 0; tn < 2; ++tn)
#pragma unroll
            for (int reg = 0; reg < 4; ++reg) {
                int m  = m0 + wm + tm * 16 + quad * 4 + reg;
                int cc = c0 + wn + tn * 16 + l15;
                if (m < M) {
                    int bb = cc >> logF, f = cc & fmask;
                    float* dst = Y + (((size_t)bb * M + m) << logF) + f;
                    if (atomic_flag) atomicAdd(dst, acc[tm][tn][reg]);
                    else *dst = acc[tm][tn][reg];
                }
            }
}

// ---------------------------------------------------------------------------
// conv_gemm (unchanged — verified)
// ---------------------------------------------------------------------------
template<int MT, int OT>
__global__ __launch_bounds__(256) void conv_gemm_kernel(
    const float* __restrict__ x, const int* __restrict__ S,
    const float* __restrict__ W, const float* __restrict__ bias,
    float* __restrict__ y, int Nv, int logF, int O, int KF, int elu_flag)
{
    constexpr int CT = OT / 4;
    constexpr int RT = 256 / CT;
    static_assert(RT * 4 == MT, "tile shape");
    __shared__ float Gs[32][MT];
    __shared__ float Ws[32][OT];

    const int b   = blockIdx.y;
    const int n0  = blockIdx.x * MT;
    const int tid = threadIdx.x;
    const int cx  = tid % CT;
    const int ry  = tid / CT;
    const int r0  = ry * 4;
    const int o0  = cx * 4;
    const int fmask = (1 << logF) - 1;
    const size_t xb = (size_t)b * Nv;

    float acc[4][4];
#pragma unroll
    for (int i = 0; i < 4; ++i)
#pragma unroll
        for (int j = 0; j < 4; ++j) acc[i][j] = 0.f;

    for (int k0 = 0; k0 < KF; k0 += 32) {
        constexpr int GSLOTS = MT * 8;
#pragma unroll
        for (int i = 0; i < GSLOTS / 256; ++i) {
            int idx = tid + i * 256;
            int r   = idx & (MT - 1);
            int jg  = idx / MT;
            int j0  = jg * 4;
            int n   = n0 + r;
            float4 v = make_float4(0.f, 0.f, 0.f, 0.f);
            if (n < Nv) {
                int kf  = k0 + j0;
                int k   = kf >> logF;
                int f   = kf & fmask;
                int src = S[n * SPK + k];
                v = *(const float4*)(x + ((xb + src) << logF) + f);
            }
            Gs[j0 + 0][r] = v.x; Gs[j0 + 1][r] = v.y;
            Gs[j0 + 2][r] = v.z; Gs[j0 + 3][r] = v.w;
        }
        constexpr int WSLOTS = OT * 8;
#pragma unroll
        for (int i = 0; i < (WSLOTS + 255) / 256; ++i) {
            int idx = tid + i * 256;
            if (WSLOTS >= 256 || idx < WSLOTS) {
                int o  = idx & (OT - 1);
                int jg = idx / OT;
                int j0 = jg * 4;
                float4 v = *(const float4*)(W + (size_t)o * KF + k0 + j0);
                Ws[j0 + 0][o] = v.x; Ws[j0 + 1][o] = v.y;
                Ws[j0 + 2][o] = v.z; Ws[j0 + 3][o] = v.w;
            }
        }
        __syncthreads();
#pragma unroll
        for (int kk = 0; kk < 32; ++kk) {
            float4 g = *(const float4*)&Gs[kk][r0];
            float4 w = *(const float4*)&Ws[kk][o0];
            acc[0][0] += g.x * w.x; acc[0][1] += g.x * w.y; acc[0][2] += g.x * w.z; acc[0][3] += g.x * w.w;
            acc[1][0] += g.y * w.x; acc[1][1] += g.y * w.y; acc[1][2] += g.y * w.z; acc[1][3] += g.y * w.w;
            acc[2][0] += g.z * w.x; acc[2][1] += g.z * w.y; acc[2][2] += g.z * w.z; acc[2][3] += g.z * w.w;
            acc[3][0] += g.w * w.x; acc[3][1] += g.w * w.y; acc[3][2] += g.w * w.z; acc[3][3] += g.w * w.w;
        }
        __syncthreads();
    }

    float4 bv = *(const float4*)(bias + o0);
#pragma unroll
    for (int i = 0; i < 4; ++i) {
        int n = n0 + r0 + i;
        if (n >= Nv) continue;
        float v0 = acc[i][0] + bv.x;
        float v1 = acc[i][1] + bv.y;
        float v2 = acc[i][2] + bv.z;
        float v3 = acc[i][3] + bv.w;
        if (elu_flag) {
            v0 = v0 > 0.f ? v0 : expm1f(v0);
            v1 = v1 > 0.f ? v1 : expm1f(v1);
            v2 = v2 > 0.f ? v2 : expm1f(v2);
            v3 = v3 > 0.f ? v3 : expm1f(v3);
        }
        if (n == Nv - 1) { v0 = v1 = v2 = v3 = 0.f; }
        *(float4*)(y + ((size_t)b * Nv + n) * O + o0) = make_float4(v0, v1, v2, v3);
    }
}

// ---------------------------------------------------------------------------
// Fallback spiral conv (F=3 / O=3 layers): W staged in LDS (O*KF <= 640).
// ---------------------------------------------------------------------------
__global__ __launch_bounds__(256) void spiral_conv_kernel(
    const float* __restrict__ x, const int* __restrict__ S,
    const float* __restrict__ W, const float* __restrict__ bias,
    float* __restrict__ y, int Nv, int F, int O, int KF, int NT, int elu_flag)
{
    __shared__ float g[8192];
    __shared__ float Wl[640];
    const int b   = blockIdx.y;
    const int n0  = blockIdx.x * NT;
    const int tid = threadIdx.x;

    for (int j = tid; j < O * KF; j += 256) Wl[j] = W[j];

    const int total = NT * KF;
    for (int j = tid; j < total; j += 256) {
        int r  = j / KF;
        int jj = j - r * KF;
        int n  = n0 + r;
        if (n < Nv) {
            int k = jj / F;
            int f = jj - k * F;
            int src = S[n * SPK + k];
            g[j] = x[((size_t)b * Nv + src) * F + f];
        }
    }
    __syncthreads();

    const int outs = NT * O;
    for (int t = tid; t < outs; t += 256) {
        int r = t / O;
        int o = t - r * O;
        int n = n0 + r;
        if (n >= Nv) continue;
        float res;
        if (n == Nv - 1) {
            res = 0.f;
        } else {
            const float* wrow = Wl + o * KF;
            const float* grow = g + r * KF;
            float a0 = 0.f, a1 = 0.f, a2 = 0.f, a3 = 0.f;
            for (int j = 0; j < KF; j += 4) {
                float4 wv = *(const float4*)(wrow + j);
                float4 gv = *(const float4*)(grow + j);
                a0 += wv.x * gv.x;
                a1 += wv.y * gv.y;
                a2 += wv.z * gv.z;
                a3 += wv.w * gv.w;
            }
            float accv = (a0 + a1) + (a2 + a3) + bias[o];
            res = (elu_flag && accv <= 0.f) ? expm1f(accv) : accv;
        }
        y[((size_t)b * Nv + n) * O + o] = res;
    }
}

// ---------------------------------------------------------------------------
// VALU down/up-sample (tiny levels 2-3 only).
// ---------------------------------------------------------------------------
__global__ __launch_bounds__(256) void dsamp_kernel(
    const float* __restrict__ A, const float* __restrict__ X,
    float* __restrict__ Y, int M, int N, int F)
{
    __shared__ float As[16][68];
    __shared__ float Xs[16][64];

    const int m0  = blockIdx.x * 64;
    const int c0  = blockIdx.y * 64;
    const int tid = threadIdx.x;
    const int tx  = tid & 15;
    const int ty  = tid >> 4;

    float acc[4][4];
#pragma unroll
    for (int i = 0; i < 4; ++i)
#pragma unroll
        for (int j = 0; j < 4; ++j) acc[i][j] = 0.f;

    for (int k0 = 0; k0 < N; k0 += 16) {
#pragma unroll
        for (int p = 0; p < 4; ++p) {
            int r  = (tid >> 4) + p * 16;
            int kk = tid & 15;
            int m  = m0 + r;
            int n  = k0 + kk;
            float v = 0.f;
            if (m < M && n < N) v = A[(size_t)m * N + n];
            As[kk][r] = v;
        }
        {
            int kk = tid >> 4;
            int cc = (tid & 15) * 4;
            int n  = k0 + kk;
            float4 v = make_float4(0.f, 0.f, 0.f, 0.f);
            if (n < N) {
                int c  = c0 + cc;
                int bb = c / F;
                int f  = c - bb * F;
                v = *(const float4*)(X + ((size_t)bb * N + n) * F + f);
            }
            *(float4*)&Xs[kk][cc] = v;
        }
        __syncthreads();
#pragma unroll
        for (int kk = 0; kk < 16; ++kk) {
            float4 av = *(const float4*)&As[kk][ty * 4];
            float4 xv = *(const float4*)&Xs[kk][tx * 4];
            acc[0][0] += av.x * xv.x; acc[0][1] += av.x * xv.y; acc[0][2] += av.x * xv.z; acc[0][3] += av.x * xv.w;
            acc[1][0] += av.y * xv.x; acc[1][1] += av.y * xv.y; acc[1][2] += av.y * xv.z; acc[1][3] += av.y * xv.w;
            acc[2][0] += av.z * xv.x; acc[2][1] += av.z * xv.y; acc[2][2] += av.z * xv.z; acc[2][3] += av.z * xv.w;
            acc[3][0] += av.w * xv.x; acc[3][1] += av.w * xv.y; acc[3][2] += av.w * xv.z; acc[3][3] += av.w * xv.w;
        }
        __syncthreads();
    }

    const int cbase = c0 + tx * 4;
    const int bb = cbase / F;
    const int f  = cbase - bb * F;
#pragma unroll
    for (int i = 0; i < 4; ++i) {
        int m = m0 + ty * 4 + i;
        if (m < M) {
            float4 v = make_float4(acc[i][0], acc[i][1], acc[i][2], acc[i][3]);
            *(float4*)(Y + ((size_t)bb * M + m) * F + f) = v;
        }
    }
}

// ---------------------------------------------------------------------------
__global__ __launch_bounds__(256) void fc_kernel(
    const float* __restrict__ in, const float* __restrict__ W,
    const float* __restrict__ bias, float* __restrict__ out,
    int In, int O, int dup)
{
    int b = blockIdx.x;
    int o = blockIdx.y * blockDim.x + threadIdx.x;
    if (o >= O) return;
    const float* xr = in + (size_t)b * In;
    const int wstride = dup ? 2 * In : In;
    const float* wr = W + (size_t)o * wstride;
    float acc = bias[o];
    if (dup) {
        for (int k = 0; k < In; ++k) acc += xr[k] * (wr[k] + wr[In + k]);
    } else {
        for (int k = 0; k < In; ++k) acc += xr[k] * wr[k];
    }
    out[(size_t)b * O + o] = acc;
}

__global__ __launch_bounds__(256) void add_kernel(
    const float* __restrict__ a, const float* __restrict__ t,
    float* __restrict__ o, int n4)
{
    int i = blockIdx.x * blockDim.x + threadIdx.x;
    if (i < n4) {
        float4 av = ((const float4*)a)[i];
        float4 tv = ((const float4*)t)[i];
        ((float4*)o)[i] = make_float4(av.x + tv.x, av.y + tv.y, av.z + tv.z, av.w + tv.w);
    }
}

// ---------------------------------------------------------------------------

static inline int ilog2(int v) { int l = 0; while ((1 << l) < v) ++l; return l; }

static inline void conv_launch(const float* x, const int* S, const float* W,
                               const float* b, float* y, int Nv, int F, int O,
                               int elu, hipStream_t s)
{
    int KF = SPK * F;
    if ((F & (F - 1)) == 0 && F >= 16 && (O == 16 || O == 32 || O == 64 || O == 128)) {
        int logF = ilog2(F);
        if (O == 16) {
            dim3 grid((Nv + 255) / 256, BATCH);
            conv_gemm_kernel<256, 16><<<grid, 256, 0, s>>>(x, S, W, b, y, Nv, logF, O, KF, elu);
        } else if (O == 32) {
            dim3 grid((Nv + 127) / 128, BATCH);
            conv_gemm_kernel<128, 32><<<grid, 256, 0, s>>>(x, S, W, b, y, Nv, logF, O, KF, elu);
        } else if (O == 64) {
            dim3 grid((Nv + 63) / 64, BATCH);
            conv_gemm_kernel<64, 64><<<grid, 256, 0, s>>>(x, S, W, b, y, Nv, logF, O, KF, elu);
        } else {
            dim3 grid((Nv + 31) / 32, BATCH);
            conv_gemm_kernel<32, 128><<<grid, 256, 0, s>>>(x, S, W, b, y, Nv, logF, O, KF, elu);
        }
        return;
    }
    int nt_o = 256 / O; if (nt_o < 1) nt_o = 1;
    int nt_l = 8192 / KF;
    int NT = nt_o < nt_l ? nt_o : nt_l;
    if (NT < 1) NT = 1;
    dim3 grid((Nv + NT - 1) / NT, BATCH);
    spiral_conv_kernel<<<grid, 256, 0, s>>>(x, S, W, b, y, Nv, F, O, KF, NT, elu);
}

static inline void dsamp_mfma2_launch(const float* A, const float* X, float* Y,
                                      int M, int K, int F, int ks, hipStream_t s)
{
    int kchunk = (K + ks - 1) / ks;
    kchunk = (kchunk + 31) & ~31;
    int ksz = (K + kchunk - 1) / kchunk;
    dim3 grid((M + 63) / 64, F, ksz);
    dsamp_mfma2_kernel<<<grid, 256, 0, s>>>(A, X, Y, M, K, ilog2(F), kchunk, ksz > 1 ? 1 : 0);
}

static inline void dsamp_mfma3_launch(const float* A, const unsigned short* Xt,
                                      float* Y, int M, int K, int Kp, int F,
                                      int ks, hipStream_t s)
{
    int slabs = Kp >> 5;
    int kchunk = ((slabs + ks - 1) / ks) * 32;
    int ksz = (Kp + kchunk - 1) / kchunk;
    dim3 grid((M + 127) / 128, (BATCH * F) / 128, ksz);
    dsamp_mfma3_kernel<<<grid, 256, 0, s>>>(A, Xt, Y, M, K, Kp, ilog2(F), kchunk,
                                            ksz > 1 ? 1 : 0);
}

static inline void dsamp_launch(const float* A, const float* X, float* Y,
                                int M, int N, int F, hipStream_t s)
{
    dim3 grid((M + 63) / 64, F);
    dsamp_kernel<<<grid, 256, 0, s>>>(A, X, Y, M, N, F);
}

extern "C" void kernel_launch(void* const* d_in, const int* in_sizes, int n_in,
                              void* d_out, int out_size, void* d_ws, size_t ws_size,
                              hipStream_t stream)
{
    const float* x_talking = (const float*)d_in[0];
    const float* templ     = (const float*)d_in[1];
    const float* D0 = (const float*)d_in[2];
    const float* U0 = (const float*)d_in[3];
    const float* D1 = (const float*)d_in[4];
    const float* U1 = (const float*)d_in[5];
    const float* D2 = (const float*)d_in[6];
    const float* U2 = (const float*)d_in[7];
    const float* D3 = (const float*)d_in[8];
    const float* U3 = (const float*)d_in[9];
    const float* enc_w0 = (const float*)d_in[10]; const float* enc_b0 = (const float*)d_in[11];
    const float* enc_w1 = (const float*)d_in[12]; const float* enc_b1 = (const float*)d_in[13];
    const float* enc_w2 = (const float*)d_in[14]; const float* enc_b2 = (const float*)d_in[15];
    const float* enc_w3 = (const float*)d_in[16]; const float* enc_b3 = (const float*)d_in[17];
    const float* fc_enc_w = (const float*)d_in[18]; const float* fc_enc_b = (const float*)d_in[19];
    const float* fc_dec_w = (const float*)d_in[20]; const float* fc_dec_b = (const float*)d_in[21];
    const float* dec_w0 = (const float*)d_in[22]; const float* dec_b0 = (const float*)d_in[23];
    const float* dec_w1 = (const float*)d_in[24]; const float* dec_b1 = (const float*)d_in[25];
    const float* dec_w2 = (const float*)d_in[26]; const float* dec_b2 = (const float*)d_in[27];
    const float* dec_w3 = (const float*)d_in[28]; const float* dec_b3 = (const float*)d_in[29];
    const float* dec_w4 = (const float*)d_in[30]; const float* dec_b4 = (const float*)d_in[31];
    const int* S0 = (const int*)d_in[32];
    const int* S1 = (const int*)d_in[33];
    const int* S2 = (const int*)d_in[34];
    const int* S3 = (const int*)d_in[35];

    float* bufA = (float*)d_ws;            // 10,289,152 floats (41.2 MB)
    float* bufB = bufA + 10289152;         // 5,144,576 floats (20.6 MB)

    float* out0 = (float*)d_out;           // 964,608 floats
    float* out1 = out0 + 964608;

    // Workspace aliases (audited against live regions):
    //  d0 phase: Xt_e0 bf16 [1024 x 5024] at bufB+1,290,240 fl (d0-out ends 1,287,168)
    //  u0 phase: Xt_c2 bf16 [2048 x 1280] at bufB+2,574,336 fl (after c2out)
    unsigned short* Xt_e0 = (unsigned short*)(bufB + 1290240);
    unsigned short* Xt_c2 = (unsigned short*)(bufB + 2574336);

    // Deterministic ws initial state (replay correctness) + zeroes d0's
    // atomic target and the Xt padding regions.
    size_t arena_bytes = (size_t)(10289152 + 5144576) * sizeof(float);
    if (arena_bytes > ws_size) arena_bytes = ws_size;
    hipMemsetAsync(d_ws, 0, arena_bytes, stream);

    // ---- encoder ----
    conv_launch(x_talking, S0, enc_w0, enc_b0, bufA, 5024, 3, 16, 1, stream);   // e0 (fallback F=3)
    xpose_bf16_kernel<<<dim3(628, 4), 256, 0, stream>>>(bufA, Xt_e0, 5024, 5024, 4);
    dsamp_mfma3_launch(D0, Xt_e0, bufB, 1257, 5024, 5024, 16, 8, stream);       // d0 [atomic ks=8]
    conv_launch(bufB, S1, enc_w1, enc_b1, bufA, 1257, 16, 32, 1, stream);       // e1
    hipMemsetAsync(bufB, 0, (size_t)645120 * sizeof(float), stream);            // zero d1 target
    dsamp_mfma2_launch(D1, bufA, bufB, 315, 1257, 32, 8, stream);               // d1 [atomic ks=8]
    conv_launch(bufB, S2, enc_w2, enc_b2, bufA, 315, 32, 64, 1, stream);        // e2
    dsamp_launch(D2, bufA, bufB, 80, 315, 64, stream);                          // d2
    conv_launch(bufB, S3, enc_w3, enc_b3, bufA, 80, 64, 128, 1, stream);        // e3
    dsamp_launch(D3, bufA, bufB, 21, 80, 128, stream);                          // d3

    fc_kernel<<<dim3(64, 1), 128, 0, stream>>>(bufB, fc_enc_w, fc_enc_b, bufA, 2688, 128, 0);
    fc_kernel<<<dim3(64, 11), 256, 0, stream>>>(bufA, fc_dec_w, fc_dec_b, bufB, 128, 2688, 1);

    // ---- decoder ----
    dsamp_launch(U3, bufB, bufA, 80, 21, 128, stream);                          // u3
    conv_launch(bufA, S3, dec_w0, dec_b0, bufB, 80, 128, 64, 1, stream);        // c0
    dsamp_launch(U2, bufB, bufA, 315, 80, 64, stream);                          // u2
    conv_launch(bufA, S2, dec_w1, dec_b1, bufB, 315, 64, 32, 1, stream);        // c1
    dsamp_mfma2_launch(U1, bufB, bufA, 1257, 315, 32, 1, stream);               // u1 (plain)
    conv_launch(bufA, S1, dec_w2, dec_b2, bufB, 1257, 32, 32, 1, stream);       // c2
    xpose_bf16_kernel<<<dim3(160, 8), 256, 0, stream>>>(bufB, Xt_c2, 1257, 1280, 5);
    hipMemsetAsync(bufA, 0, (size_t)10289152 * sizeof(float), stream);          // zero u0 target
    dsamp_mfma3_launch(U0, Xt_c2, bufA, 5024, 1257, 1280, 32, 2, stream);       // u0 [atomic ks=2]
    conv_launch(bufA, S0, dec_w3, dec_b3, bufB, 5024, 32, 16, 1, stream);       // c3
    conv_launch(bufB, S0, dec_w4, dec_b4, out0, 5024, 16, 3, 0, stream);        // c4 (fallback O=3)

    int n4 = 964608 / 4;
    add_kernel<<<(n4 + 255) / 256, 256, 0, stream>>>(out0, templ, out1, n4);
}

// Round 6
// 1332.331 us; speedup vs baseline: 3.4419x; 1.2401x over previous
//
#include <hip/hip_runtime.h>
#include <cstddef>

// ---------------------------------------------------------------------------
// SpiralAutoencoder on MI355X — round 6:
//  * fc_enc/fc_dec -> fc_wave_kernel: one wave per output element, coalesced
//    lane-strided loads + shuffle reduction (was: 8192-thread serial-row walk,
//    1.5% occupancy, 257 us).
//  * everything else unchanged (proven in rounds 2-5).
// ---------------------------------------------------------------------------

#define BATCH 64
#define SPK 12  // spiral length

typedef __attribute__((ext_vector_type(8))) short bf16x8;
typedef __attribute__((ext_vector_type(4))) short bf16x4;
typedef __attribute__((ext_vector_type(4))) float f32x4;

__device__ __forceinline__ unsigned short f2bf(float x) {
    union { float f; unsigned int u; } v; v.f = x;
    unsigned int r = v.u + 0x7FFF + ((v.u >> 16) & 1);  // RNE
    return (unsigned short)(r >> 16);
}

__device__ __forceinline__ bf16x8 pack8(const float* v) {
    bf16x8 r;
#pragma unroll
    for (int j = 0; j < 8; ++j) r[j] = (short)f2bf(v[j]);
    return r;
}

// ---------------------------------------------------------------------------
// Transpose-convert: x [b][k][f] fp32 -> xt [c][k] bf16, c = b*F+f, stride Kp.
// ---------------------------------------------------------------------------
__global__ __launch_bounds__(256) void xpose_bf16_kernel(
    const float* __restrict__ x, unsigned short* __restrict__ xt,
    int K, int Kp, int logF)
{
    const int c  = blockIdx.y * 256 + threadIdx.x;
    const int k0 = blockIdx.x * 8;
    const int bb = c >> logF;
    const int f  = c & ((1 << logF) - 1);
    const float* src = x + (((size_t)bb * K) << logF) + f;
    bf16x8 r;
#pragma unroll
    for (int j = 0; j < 8; ++j) {
        int k = k0 + j;
        float v = (k < K) ? src[(size_t)k << logF] : 0.f;
        r[j] = (short)f2bf(v);
    }
    *(bf16x8*)(xt + (size_t)c * Kp + k0) = r;
}

// ---------------------------------------------------------------------------
// dsamp_mfma3: 128x128 tile MFMA resample (round-5, proven).
// ---------------------------------------------------------------------------
__global__ __launch_bounds__(256) void dsamp_mfma3_kernel(
    const float* __restrict__ A, const unsigned short* __restrict__ Xt,
    float* __restrict__ Y, int M, int K, int Kp, int logF, int kchunk,
    int atomic_flag)
{
    constexpr int PAD = 40;
    __shared__ unsigned short As[2][128 * PAD];
    __shared__ unsigned short Bs[2][128 * PAD];

    const int fmask = (1 << logF) - 1;
    const int m0   = blockIdx.x * 128;
    const int c0   = blockIdx.y * 128;
    const int kbeg = blockIdx.z * kchunk;
    int kend = kbeg + kchunk; if (kend > Kp) kend = Kp;
    const int nslab = (kend - kbeg + 31) >> 5;

    const int tid  = threadIdx.x;
    const int lane = tid & 63;
    const int wave = tid >> 6;
    const int wm   = (wave >> 1) * 64;
    const int wn   = (wave & 1) * 64;
    const int l15  = lane & 15;
    const int quad = lane >> 4;

    const int ar_row = tid >> 3;
    const int ar_k4  = (tid & 7) * 4;
    const int br_row = tid >> 2;
    const int br_k8  = (tid & 3) * 8;

    f32x4 acc[4][4];
#pragma unroll
    for (int i = 0; i < 4; ++i)
#pragma unroll
        for (int j = 0; j < 4; ++j) acc[i][j] = (f32x4){0.f, 0.f, 0.f, 0.f};

    float4 apre[4];
    bf16x8 bpre[2];

    auto loadAB = [&](int ko) {
#pragma unroll
        for (int i = 0; i < 4; ++i) {
            int m = m0 + ar_row + i * 32;
            int k = ko + ar_k4;
            float4 v = make_float4(0.f, 0.f, 0.f, 0.f);
            if (m < M) {
                const float* ap = A + (size_t)m * K;
                if (k + 3 < K) v = *(const float4*)(ap + k);
                else {
                    v.x = (k     < K) ? ap[k]     : 0.f;
                    v.y = (k + 1 < K) ? ap[k + 1] : 0.f;
                    v.z = (k + 2 < K) ? ap[k + 2] : 0.f;
                    v.w = (k + 3 < K) ? ap[k + 3] : 0.f;
                }
            }
            apre[i] = v;
        }
#pragma unroll
        for (int i = 0; i < 2; ++i)
            bpre[i] = *(const bf16x8*)(Xt + (size_t)(c0 + br_row + i * 64) * Kp + ko + br_k8);
    };
    auto stage = [&](int buf) {
#pragma unroll
        for (int i = 0; i < 4; ++i) {
            bf16x4 t;
            t[0] = (short)f2bf(apre[i].x);
            t[1] = (short)f2bf(apre[i].y);
            t[2] = (short)f2bf(apre[i].z);
            t[3] = (short)f2bf(apre[i].w);
            *(bf16x4*)&As[buf][(ar_row + i * 32) * PAD + ar_k4] = t;
        }
#pragma unroll
        for (int i = 0; i < 2; ++i)
            *(bf16x8*)&Bs[buf][(br_row + i * 64) * PAD + br_k8] = bpre[i];
    };

    loadAB(kbeg);
    stage(0);
    __syncthreads();

    for (int s = 0; s < nslab; ++s) {
        const int cur = s & 1;
        const bool more = (s + 1) < nslab;
        if (more) loadAB(kbeg + (s + 1) * 32);

        bf16x8 af[4], bfr[4];
#pragma unroll
        for (int t = 0; t < 4; ++t) {
            af[t]  = *(const bf16x8*)&As[cur][(wm + t * 16 + l15) * PAD + quad * 8];
            bfr[t] = *(const bf16x8*)&Bs[cur][(wn + t * 16 + l15) * PAD + quad * 8];
        }
#pragma unroll
        for (int tm = 0; tm < 4; ++tm)
#pragma unroll
            for (int tn = 0; tn < 4; ++tn)
                acc[tm][tn] = __builtin_amdgcn_mfma_f32_16x16x32_bf16(af[tm], bfr[tn], acc[tm][tn], 0, 0, 0);

        if (more) { stage(cur ^ 1); __syncthreads(); }
    }

#pragma unroll
    for (int tm = 0; tm < 4; ++tm)
#pragma unroll
        for (int tn = 0; tn < 4; ++tn)
#pragma unroll
            for (int reg = 0; reg < 4; ++reg) {
                int m  = m0 + wm + tm * 16 + quad * 4 + reg;
                int cc = c0 + wn + tn * 16 + l15;
                if (m < M) {
                    int bb = cc >> logF, f = cc & fmask;
                    float* dst = Y + (((size_t)bb * M + m) << logF) + f;
                    if (atomic_flag) atomicAdd(dst, acc[tm][tn][reg]);
                    else *dst = acc[tm][tn][reg];
                }
            }
}

// ---------------------------------------------------------------------------
// dsamp_mfma2 (round-4, proven): D1/U1.
// ---------------------------------------------------------------------------
__global__ __launch_bounds__(256) void dsamp_mfma2_kernel(
    const float* __restrict__ A, const float* __restrict__ X,
    float* __restrict__ Y, int M, int K, int logF, int kchunk, int atomic_flag)
{
    constexpr int PAD = 40;
    __shared__ unsigned short Xs[2][64 * PAD];

    const int fmask = (1 << logF) - 1;
    const int m0   = blockIdx.x * 64;
    const int c0   = blockIdx.y * 64;
    const int kbeg = blockIdx.z * kchunk;
    int kend = kbeg + kchunk; if (kend > K) kend = K;
    const int nslab = (kend - kbeg + 31) >> 5;

    const int tid  = threadIdx.x;
    const int lane = tid & 63;
    const int wave = tid >> 6;
    const int wm   = (wave >> 1) * 32;
    const int wn   = (wave & 1) * 32;
    const int l15  = lane & 15;
    const int quad = lane >> 4;

    const int skk  = tid >> 4;
    const int scg  = (tid & 15) * 4;
    const int cB   = c0 + scg;
    const int xbb  = cB >> logF;
    const int xf   = cB & fmask;
    const size_t xrowbase = (((size_t)xbb * K) << logF) + xf;

    const int mA0 = m0 + wm + l15;
    const int mA1 = mA0 + 16;
    const int kaoff = quad * 8;

    f32x4 acc[2][2];
    acc[0][0] = acc[0][1] = acc[1][0] = acc[1][1] = (f32x4){0.f, 0.f, 0.f, 0.f};

    float4 xn0, xn1;
    float ac0[8], ac1[8], an0[8], an1[8];

    {
        int k = kbeg + skk;
        xn0 = make_float4(0.f, 0.f, 0.f, 0.f);
        if (k < kend) xn0 = *(const float4*)(X + xrowbase + ((size_t)k << logF));
        k = kbeg + 16 + skk;
        xn1 = make_float4(0.f, 0.f, 0.f, 0.f);
        if (k < kend) xn1 = *(const float4*)(X + xrowbase + ((size_t)k << logF));
        int ka = kbeg + kaoff;
#pragma unroll
        for (int j = 0; j < 8; ++j) {
            ac0[j] = (mA0 < M && ka + j < kend) ? A[(size_t)mA0 * K + ka + j] : 0.f;
            ac1[j] = (mA1 < M && ka + j < kend) ? A[(size_t)mA1 * K + ka + j] : 0.f;
        }
        unsigned short* p = &Xs[0][0];
        p[(scg + 0) * PAD + skk] = f2bf(xn0.x);
        p[(scg + 1) * PAD + skk] = f2bf(xn0.y);
        p[(scg + 2) * PAD + skk] = f2bf(xn0.z);
        p[(scg + 3) * PAD + skk] = f2bf(xn0.w);
        int kk1 = 16 + skk;
        p[(scg + 0) * PAD + kk1] = f2bf(xn1.x);
        p[(scg + 1) * PAD + kk1] = f2bf(xn1.y);
        p[(scg + 2) * PAD + kk1] = f2bf(xn1.z);
        p[(scg + 3) * PAD + kk1] = f2bf(xn1.w);
    }
    __syncthreads();

    for (int s = 0; s < nslab; ++s) {
        const int cur = s & 1;
        const bool more = (s + 1 < nslab);
        if (more) {
            int k0 = kbeg + (s + 1) * 32;
            int k = k0 + skk;
            xn0 = make_float4(0.f, 0.f, 0.f, 0.f);
            if (k < kend) xn0 = *(const float4*)(X + xrowbase + ((size_t)k << logF));
            k = k0 + 16 + skk;
            xn1 = make_float4(0.f, 0.f, 0.f, 0.f);
            if (k < kend) xn1 = *(const float4*)(X + xrowbase + ((size_t)k << logF));
            int ka = k0 + kaoff;
#pragma unroll
            for (int j = 0; j < 8; ++j) {
                an0[j] = (mA0 < M && ka + j < kend) ? A[(size_t)mA0 * K + ka + j] : 0.f;
                an1[j] = (mA1 < M && ka + j < kend) ? A[(size_t)mA1 * K + ka + j] : 0.f;
            }
        }
        {
            const unsigned short* p = &Xs[cur][0];
            bf16x8 b0 = *(const bf16x8*)&p[(wn +      l15) * PAD + quad * 8];
            bf16x8 b1 = *(const bf16x8*)&p[(wn + 16 + l15) * PAD + quad * 8];
            bf16x8 a0 = pack8(ac0);
            bf16x8 a1 = pack8(ac1);
            acc[0][0] = __builtin_amdgcn_mfma_f32_16x16x32_bf16(a0, b0, acc[0][0], 0, 0, 0);
            acc[0][1] = __builtin_amdgcn_mfma_f32_16x16x32_bf16(a0, b1, acc[0][1], 0, 0, 0);
            acc[1][0] = __builtin_amdgcn_mfma_f32_16x16x32_bf16(a1, b0, acc[1][0], 0, 0, 0);
            acc[1][1] = __builtin_amdgcn_mfma_f32_16x16x32_bf16(a1, b1, acc[1][1], 0, 0, 0);
        }
        if (more) {
            unsigned short* q = &Xs[cur ^ 1][0];
            q[(scg + 0) * PAD + skk] = f2bf(xn0.x);
            q[(scg + 1) * PAD + skk] = f2bf(xn0.y);
            q[(scg + 2) * PAD + skk] = f2bf(xn0.z);
            q[(scg + 3) * PAD + skk] = f2bf(xn0.w);
            int kk1 = 16 + skk;
            q[(scg + 0) * PAD + kk1] = f2bf(xn1.x);
            q[(scg + 1) * PAD + kk1] = f2bf(xn1.y);
            q[(scg + 2) * PAD + kk1] = f2bf(xn1.z);
            q[(scg + 3) * PAD + kk1] = f2bf(xn1.w);
            __syncthreads();
#pragma unroll
            for (int j = 0; j < 8; ++j) { ac0[j] = an0[j]; ac1[j] = an1[j]; }
        }
    }

#pragma unroll
    for (int tm = 0; tm < 2; ++tm)
#pragma unroll
        for (int tn = 0; tn < 2; ++tn)
#pragma unroll
            for (int reg = 0; reg < 4; ++reg) {
                int m  = m0 + wm + tm * 16 + quad * 4 + reg;
                int cc = c0 + wn + tn * 16 + l15;
                if (m < M) {
                    int bb = cc >> logF, f = cc & fmask;
                    float* dst = Y + (((size_t)bb * M + m) << logF) + f;
                    if (atomic_flag) atomicAdd(dst, acc[tm][tn][reg]);
                    else *dst = acc[tm][tn][reg];
                }
            }
}

// ---------------------------------------------------------------------------
// conv_gemm (unchanged — verified)
// ---------------------------------------------------------------------------
template<int MT, int OT>
__global__ __launch_bounds__(256) void conv_gemm_kernel(
    const float* __restrict__ x, const int* __restrict__ S,
    const float* __restrict__ W, const float* __restrict__ bias,
    float* __restrict__ y, int Nv, int logF, int O, int KF, int elu_flag)
{
    constexpr int CT = OT / 4;
    constexpr int RT = 256 / CT;
    static_assert(RT * 4 == MT, "tile shape");
    __shared__ float Gs[32][MT];
    __shared__ float Ws[32][OT];

    const int b   = blockIdx.y;
    const int n0  = blockIdx.x * MT;
    const int tid = threadIdx.x;
    const int cx  = tid % CT;
    const int ry  = tid / CT;
    const int r0  = ry * 4;
    const int o0  = cx * 4;
    const int fmask = (1 << logF) - 1;
    const size_t xb = (size_t)b * Nv;

    float acc[4][4];
#pragma unroll
    for (int i = 0; i < 4; ++i)
#pragma unroll
        for (int j = 0; j < 4; ++j) acc[i][j] = 0.f;

    for (int k0 = 0; k0 < KF; k0 += 32) {
        constexpr int GSLOTS = MT * 8;
#pragma unroll
        for (int i = 0; i < GSLOTS / 256; ++i) {
            int idx = tid + i * 256;
            int r   = idx & (MT - 1);
            int jg  = idx / MT;
            int j0  = jg * 4;
            int n   = n0 + r;
            float4 v = make_float4(0.f, 0.f, 0.f, 0.f);
            if (n < Nv) {
                int kf  = k0 + j0;
                int k   = kf >> logF;
                int f   = kf & fmask;
                int src = S[n * SPK + k];
                v = *(const float4*)(x + ((xb + src) << logF) + f);
            }
            Gs[j0 + 0][r] = v.x; Gs[j0 + 1][r] = v.y;
            Gs[j0 + 2][r] = v.z; Gs[j0 + 3][r] = v.w;
        }
        constexpr int WSLOTS = OT * 8;
#pragma unroll
        for (int i = 0; i < (WSLOTS + 255) / 256; ++i) {
            int idx = tid + i * 256;
            if (WSLOTS >= 256 || idx < WSLOTS) {
                int o  = idx & (OT - 1);
                int jg = idx / OT;
                int j0 = jg * 4;
                float4 v = *(const float4*)(W + (size_t)o * KF + k0 + j0);
                Ws[j0 + 0][o] = v.x; Ws[j0 + 1][o] = v.y;
                Ws[j0 + 2][o] = v.z; Ws[j0 + 3][o] = v.w;
            }
        }
        __syncthreads();
#pragma unroll
        for (int kk = 0; kk < 32; ++kk) {
            float4 g = *(const float4*)&Gs[kk][r0];
            float4 w = *(const float4*)&Ws[kk][o0];
            acc[0][0] += g.x * w.x; acc[0][1] += g.x * w.y; acc[0][2] += g.x * w.z; acc[0][3] += g.x * w.w;
            acc[1][0] += g.y * w.x; acc[1][1] += g.y * w.y; acc[1][2] += g.y * w.z; acc[1][3] += g.y * w.w;
            acc[2][0] += g.z * w.x; acc[2][1] += g.z * w.y; acc[2][2] += g.z * w.z; acc[2][3] += g.z * w.w;
            acc[3][0] += g.w * w.x; acc[3][1] += g.w * w.y; acc[3][2] += g.w * w.z; acc[3][3] += g.w * w.w;
        }
        __syncthreads();
    }

    float4 bv = *(const float4*)(bias + o0);
#pragma unroll
    for (int i = 0; i < 4; ++i) {
        int n = n0 + r0 + i;
        if (n >= Nv) continue;
        float v0 = acc[i][0] + bv.x;
        float v1 = acc[i][1] + bv.y;
        float v2 = acc[i][2] + bv.z;
        float v3 = acc[i][3] + bv.w;
        if (elu_flag) {
            v0 = v0 > 0.f ? v0 : expm1f(v0);
            v1 = v1 > 0.f ? v1 : expm1f(v1);
            v2 = v2 > 0.f ? v2 : expm1f(v2);
            v3 = v3 > 0.f ? v3 : expm1f(v3);
        }
        if (n == Nv - 1) { v0 = v1 = v2 = v3 = 0.f; }
        *(float4*)(y + ((size_t)b * Nv + n) * O + o0) = make_float4(v0, v1, v2, v3);
    }
}

// ---------------------------------------------------------------------------
// Fallback spiral conv (F=3 / O=3 layers): W staged in LDS.
// ---------------------------------------------------------------------------
__global__ __launch_bounds__(256) void spiral_conv_kernel(
    const float* __restrict__ x, const int* __restrict__ S,
    const float* __restrict__ W, const float* __restrict__ bias,
    float* __restrict__ y, int Nv, int F, int O, int KF, int NT, int elu_flag)
{
    __shared__ float g[8192];
    __shared__ float Wl[640];
    const int b   = blockIdx.y;
    const int n0  = blockIdx.x * NT;
    const int tid = threadIdx.x;

    for (int j = tid; j < O * KF; j += 256) Wl[j] = W[j];

    const int total = NT * KF;
    for (int j = tid; j < total; j += 256) {
        int r  = j / KF;
        int jj = j - r * KF;
        int n  = n0 + r;
        if (n < Nv) {
            int k = jj / F;
            int f = jj - k * F;
            int src = S[n * SPK + k];
            g[j] = x[((size_t)b * Nv + src) * F + f];
        }
    }
    __syncthreads();

    const int outs = NT * O;
    for (int t = tid; t < outs; t += 256) {
        int r = t / O;
        int o = t - r * O;
        int n = n0 + r;
        if (n >= Nv) continue;
        float res;
        if (n == Nv - 1) {
            res = 0.f;
        } else {
            const float* wrow = Wl + o * KF;
            const float* grow = g + r * KF;
            float a0 = 0.f, a1 = 0.f, a2 = 0.f, a3 = 0.f;
            for (int j = 0; j < KF; j += 4) {
                float4 wv = *(const float4*)(wrow + j);
                float4 gv = *(const float4*)(grow + j);
                a0 += wv.x * gv.x;
                a1 += wv.y * gv.y;
                a2 += wv.z * gv.z;
                a3 += wv.w * gv.w;
            }
            float accv = (a0 + a1) + (a2 + a3) + bias[o];
            res = (elu_flag && accv <= 0.f) ? expm1f(accv) : accv;
        }
        y[((size_t)b * Nv + n) * O + o] = res;
    }
}

// ---------------------------------------------------------------------------
// VALU down/up-sample (tiny levels 2-3 only).
// ---------------------------------------------------------------------------
__global__ __launch_bounds__(256) void dsamp_kernel(
    const float* __restrict__ A, const float* __restrict__ X,
    float* __restrict__ Y, int M, int N, int F)
{
    __shared__ float As[16][68];
    __shared__ float Xs[16][64];

    const int m0  = blockIdx.x * 64;
    const int c0  = blockIdx.y * 64;
    const int tid = threadIdx.x;
    const int tx  = tid & 15;
    const int ty  = tid >> 4;

    float acc[4][4];
#pragma unroll
    for (int i = 0; i < 4; ++i)
#pragma unroll
        for (int j = 0; j < 4; ++j) acc[i][j] = 0.f;

    for (int k0 = 0; k0 < N; k0 += 16) {
#pragma unroll
        for (int p = 0; p < 4; ++p) {
            int r  = (tid >> 4) + p * 16;
            int kk = tid & 15;
            int m  = m0 + r;
            int n  = k0 + kk;
            float v = 0.f;
            if (m < M && n < N) v = A[(size_t)m * N + n];
            As[kk][r] = v;
        }
        {
            int kk = tid >> 4;
            int cc = (tid & 15) * 4;
            int n  = k0 + kk;
            float4 v = make_float4(0.f, 0.f, 0.f, 0.f);
            if (n < N) {
                int c  = c0 + cc;
                int bb = c / F;
                int f  = c - bb * F;
                v = *(const float4*)(X + ((size_t)bb * N + n) * F + f);
            }
            *(float4*)&Xs[kk][cc] = v;
        }
        __syncthreads();
#pragma unroll
        for (int kk = 0; kk < 16; ++kk) {
            float4 av = *(const float4*)&As[kk][ty * 4];
            float4 xv = *(const float4*)&Xs[kk][tx * 4];
            acc[0][0] += av.x * xv.x; acc[0][1] += av.x * xv.y; acc[0][2] += av.x * xv.z; acc[0][3] += av.x * xv.w;
            acc[1][0] += av.y * xv.x; acc[1][1] += av.y * xv.y; acc[1][2] += av.y * xv.z; acc[1][3] += av.y * xv.w;
            acc[2][0] += av.z * xv.x; acc[2][1] += av.z * xv.y; acc[2][2] += av.z * xv.z; acc[2][3] += av.z * xv.w;
            acc[3][0] += av.w * xv.x; acc[3][1] += av.w * xv.y; acc[3][2] += av.w * xv.z; acc[3][3] += av.w * xv.w;
        }
        __syncthreads();
    }

    const int cbase = c0 + tx * 4;
    const int bb = cbase / F;
    const int f  = cbase - bb * F;
#pragma unroll
    for (int i = 0; i < 4; ++i) {
        int m = m0 + ty * 4 + i;
        if (m < M) {
            float4 v = make_float4(acc[i][0], acc[i][1], acc[i][2], acc[i][3]);
            *(float4*)(Y + ((size_t)bb * M + m) * F + f) = v;
        }
    }
}

// ---------------------------------------------------------------------------
// fc_wave: one 64-lane wave per output element out[b,o].
// Lane-strided coalesced loads; shuffle butterfly reduction.
// dup: W has 2*In cols (concat([z,z])): use W[o,k] + W[o,k+In].
// Grid: (B*O/4) blocks of 256 (4 waves).
// ---------------------------------------------------------------------------
__global__ __launch_bounds__(256) void fc_wave_kernel(
    const float* __restrict__ in, const float* __restrict__ W,
    const float* __restrict__ bias, float* __restrict__ out,
    int In, int O, int dup)
{
    const int gw   = blockIdx.x * 4 + (threadIdx.x >> 6);
    const int lane = threadIdx.x & 63;
    const int b = gw / O;
    const int o = gw - b * O;
    const float* xr = in + (size_t)b * In;
    float acc = 0.f;
    if (dup) {
        const float* wr = W + (size_t)o * (2 * In);
        for (int k = lane; k < In; k += 64)
            acc += xr[k] * (wr[k] + wr[In + k]);
    } else {
        const float* wr = W + (size_t)o * In;
        for (int k = lane; k < In; k += 64)
            acc += xr[k] * wr[k];
    }
#pragma unroll
    for (int off = 32; off > 0; off >>= 1)
        acc += __shfl_down(acc, off, 64);
    if (lane == 0) out[(size_t)b * O + o] = acc + bias[o];
}

__global__ __launch_bounds__(256) void add_kernel(
    const float* __restrict__ a, const float* __restrict__ t,
    float* __restrict__ o, int n4)
{
    int i = blockIdx.x * blockDim.x + threadIdx.x;
    if (i < n4) {
        float4 av = ((const float4*)a)[i];
        float4 tv = ((const float4*)t)[i];
        ((float4*)o)[i] = make_float4(av.x + tv.x, av.y + tv.y, av.z + tv.z, av.w + tv.w);
    }
}

// ---------------------------------------------------------------------------

static inline int ilog2(int v) { int l = 0; while ((1 << l) < v) ++l; return l; }

static inline void conv_launch(const float* x, const int* S, const float* W,
                               const float* b, float* y, int Nv, int F, int O,
                               int elu, hipStream_t s)
{
    int KF = SPK * F;
    if ((F & (F - 1)) == 0 && F >= 16 && (O == 16 || O == 32 || O == 64 || O == 128)) {
        int logF = ilog2(F);
        if (O == 16) {
            dim3 grid((Nv + 255) / 256, BATCH);
            conv_gemm_kernel<256, 16><<<grid, 256, 0, s>>>(x, S, W, b, y, Nv, logF, O, KF, elu);
        } else if (O == 32) {
            dim3 grid((Nv + 127) / 128, BATCH);
            conv_gemm_kernel<128, 32><<<grid, 256, 0, s>>>(x, S, W, b, y, Nv, logF, O, KF, elu);
        } else if (O == 64) {
            dim3 grid((Nv + 63) / 64, BATCH);
            conv_gemm_kernel<64, 64><<<grid, 256, 0, s>>>(x, S, W, b, y, Nv, logF, O, KF, elu);
        } else {
            dim3 grid((Nv + 31) / 32, BATCH);
            conv_gemm_kernel<32, 128><<<grid, 256, 0, s>>>(x, S, W, b, y, Nv, logF, O, KF, elu);
        }
        return;
    }
    int nt_o = 256 / O; if (nt_o < 1) nt_o = 1;
    int nt_l = 8192 / KF;
    int NT = nt_o < nt_l ? nt_o : nt_l;
    if (NT < 1) NT = 1;
    dim3 grid((Nv + NT - 1) / NT, BATCH);
    spiral_conv_kernel<<<grid, 256, 0, s>>>(x, S, W, b, y, Nv, F, O, KF, NT, elu);
}

static inline void dsamp_mfma2_launch(const float* A, const float* X, float* Y,
                                      int M, int K, int F, int ks, hipStream_t s)
{
    int kchunk = (K + ks - 1) / ks;
    kchunk = (kchunk + 31) & ~31;
    int ksz = (K + kchunk - 1) / kchunk;
    dim3 grid((M + 63) / 64, F, ksz);
    dsamp_mfma2_kernel<<<grid, 256, 0, s>>>(A, X, Y, M, K, ilog2(F), kchunk, ksz > 1 ? 1 : 0);
}

static inline void dsamp_mfma3_launch(const float* A, const unsigned short* Xt,
                                      float* Y, int M, int K, int Kp, int F,
                                      int ks, hipStream_t s)
{
    int slabs = Kp >> 5;
    int kchunk = ((slabs + ks - 1) / ks) * 32;
    int ksz = (Kp + kchunk - 1) / kchunk;
    dim3 grid((M + 127) / 128, (BATCH * F) / 128, ksz);
    dsamp_mfma3_kernel<<<grid, 256, 0, s>>>(A, Xt, Y, M, K, Kp, ilog2(F), kchunk,
                                            ksz > 1 ? 1 : 0);
}

static inline void dsamp_launch(const float* A, const float* X, float* Y,
                                int M, int N, int F, hipStream_t s)
{
    dim3 grid((M + 63) / 64, F);
    dsamp_kernel<<<grid, 256, 0, s>>>(A, X, Y, M, N, F);
}

extern "C" void kernel_launch(void* const* d_in, const int* in_sizes, int n_in,
                              void* d_out, int out_size, void* d_ws, size_t ws_size,
                              hipStream_t stream)
{
    const float* x_talking = (const float*)d_in[0];
    const float* templ     = (const float*)d_in[1];
    const float* D0 = (const float*)d_in[2];
    const float* U0 = (const float*)d_in[3];
    const float* D1 = (const float*)d_in[4];
    const float* U1 = (const float*)d_in[5];
    const float* D2 = (const float*)d_in[6];
    const float* U2 = (const float*)d_in[7];
    const float* D3 = (const float*)d_in[8];
    const float* U3 = (const float*)d_in[9];
    const float* enc_w0 = (const float*)d_in[10]; const float* enc_b0 = (const float*)d_in[11];
    const float* enc_w1 = (const float*)d_in[12]; const float* enc_b1 = (const float*)d_in[13];
    const float* enc_w2 = (const float*)d_in[14]; const float* enc_b2 = (const float*)d_in[15];
    const float* enc_w3 = (const float*)d_in[16]; const float* enc_b3 = (const float*)d_in[17];
    const float* fc_enc_w = (const float*)d_in[18]; const float* fc_enc_b = (const float*)d_in[19];
    const float* fc_dec_w = (const float*)d_in[20]; const float* fc_dec_b = (const float*)d_in[21];
    const float* dec_w0 = (const float*)d_in[22]; const float* dec_b0 = (const float*)d_in[23];
    const float* dec_w1 = (const float*)d_in[24]; const float* dec_b1 = (const float*)d_in[25];
    const float* dec_w2 = (const float*)d_in[26]; const float* dec_b2 = (const float*)d_in[27];
    const float* dec_w3 = (const float*)d_in[28]; const float* dec_b3 = (const float*)d_in[29];
    const float* dec_w4 = (const float*)d_in[30]; const float* dec_b4 = (const float*)d_in[31];
    const int* S0 = (const int*)d_in[32];
    const int* S1 = (const int*)d_in[33];
    const int* S2 = (const int*)d_in[34];
    const int* S3 = (const int*)d_in[35];

    float* bufA = (float*)d_ws;            // 10,289,152 floats (41.2 MB)
    float* bufB = bufA + 10289152;         // 5,144,576 floats (20.6 MB)

    float* out0 = (float*)d_out;           // 964,608 floats
    float* out1 = out0 + 964608;

    unsigned short* Xt_e0 = (unsigned short*)(bufB + 1290240);
    unsigned short* Xt_c2 = (unsigned short*)(bufB + 2574336);

    size_t arena_bytes = (size_t)(10289152 + 5144576) * sizeof(float);
    if (arena_bytes > ws_size) arena_bytes = ws_size;
    hipMemsetAsync(d_ws, 0, arena_bytes, stream);

    // ---- encoder ----
    conv_launch(x_talking, S0, enc_w0, enc_b0, bufA, 5024, 3, 16, 1, stream);   // e0 (fallback F=3)
    xpose_bf16_kernel<<<dim3(628, 4), 256, 0, stream>>>(bufA, Xt_e0, 5024, 5024, 4);
    dsamp_mfma3_launch(D0, Xt_e0, bufB, 1257, 5024, 5024, 16, 8, stream);       // d0 [atomic ks=8]
    conv_launch(bufB, S1, enc_w1, enc_b1, bufA, 1257, 16, 32, 1, stream);       // e1
    hipMemsetAsync(bufB, 0, (size_t)645120 * sizeof(float), stream);            // zero d1 target
    dsamp_mfma2_launch(D1, bufA, bufB, 315, 1257, 32, 8, stream);               // d1 [atomic ks=8]
    conv_launch(bufB, S2, enc_w2, enc_b2, bufA, 315, 32, 64, 1, stream);        // e2
    dsamp_launch(D2, bufA, bufB, 80, 315, 64, stream);                          // d2
    conv_launch(bufB, S3, enc_w3, enc_b3, bufA, 80, 64, 128, 1, stream);        // e3
    dsamp_launch(D3, bufA, bufB, 21, 80, 128, stream);                          // d3

    // z: [64,128] <- bufB[64,2688];  h: [64,2688] <- z
    fc_wave_kernel<<<dim3((BATCH * 128) / 4), 256, 0, stream>>>(bufB, fc_enc_w, fc_enc_b, bufA, 2688, 128, 0);
    fc_wave_kernel<<<dim3((BATCH * 2688) / 4), 256, 0, stream>>>(bufA, fc_dec_w, fc_dec_b, bufB, 128, 2688, 1);

    // ---- decoder ----
    dsamp_launch(U3, bufB, bufA, 80, 21, 128, stream);                          // u3
    conv_launch(bufA, S3, dec_w0, dec_b0, bufB, 80, 128, 64, 1, stream);        // c0
    dsamp_launch(U2, bufB, bufA, 315, 80, 64, stream);                          // u2
    conv_launch(bufA, S2, dec_w1, dec_b1, bufB, 315, 64, 32, 1, stream);        // c1
    dsamp_mfma2_launch(U1, bufB, bufA, 1257, 315, 32, 1, stream);               // u1 (plain)
    conv_launch(bufA, S1, dec_w2, dec_b2, bufB, 1257, 32, 32, 1, stream);       // c2
    xpose_bf16_kernel<<<dim3(160, 8), 256, 0, stream>>>(bufB, Xt_c2, 1257, 1280, 5);
    hipMemsetAsync(bufA, 0, (size_t)10289152 * sizeof(float), stream);          // zero u0 target
    dsamp_mfma3_launch(U0, Xt_c2, bufA, 5024, 1257, 1280, 32, 2, stream);       // u0 [atomic ks=2]
    conv_launch(bufA, S0, dec_w3, dec_b3, bufB, 5024, 32, 16, 1, stream);       // c3
    conv_launch(bufB, S0, dec_w4, dec_b4, out0, 5024, 16, 3, 0, stream);        // c4 (fallback O=3)

    int n4 = 964608 / 4;
    add_kernel<<<(n4 + 255) / 256, 256, 0, stream>>>(out0, templ, out1, n4);
}

// Round 7
// 1295.351 us; speedup vs baseline: 3.5402x; 1.0285x over previous
//
#include <hip/hip_runtime.h>
#include <cstddef>

// ---------------------------------------------------------------------------
// SpiralAutoencoder on MI355X — round 7:
//  * e0 (F=3) and c4 (O=3) rerouted through conv_gemm via padding:
//      e0: x padded to F=4 (KF 48, K-padded to 64 w/ KFr guard), W remapped.
//      c4: W/bias padded to O=16; padded output extracted+template-added.
//    (was: fallback spiral_conv at 194 us — 21-way LDS conflicts, half-idle.)
//  * conv_gemm gains KFr (real-K guard). Fallback conv + add_kernel deleted.
// ---------------------------------------------------------------------------

#define BATCH 64
#define SPK 12  // spiral length

typedef __attribute__((ext_vector_type(8))) short bf16x8;
typedef __attribute__((ext_vector_type(4))) short bf16x4;
typedef __attribute__((ext_vector_type(4))) float f32x4;

__device__ __forceinline__ unsigned short f2bf(float x) {
    union { float f; unsigned int u; } v; v.f = x;
    unsigned int r = v.u + 0x7FFF + ((v.u >> 16) & 1);  // RNE
    return (unsigned short)(r >> 16);
}

__device__ __forceinline__ bf16x8 pack8(const float* v) {
    bf16x8 r;
#pragma unroll
    for (int j = 0; j < 8; ++j) r[j] = (short)f2bf(v[j]);
    return r;
}

// ---------------------------------------------------------------------------
// Transpose-convert: x [b][k][f] fp32 -> xt [c][k] bf16, c = b*F+f, stride Kp.
// ---------------------------------------------------------------------------
__global__ __launch_bounds__(256) void xpose_bf16_kernel(
    const float* __restrict__ x, unsigned short* __restrict__ xt,
    int K, int Kp, int logF)
{
    const int c  = blockIdx.y * 256 + threadIdx.x;
    const int k0 = blockIdx.x * 8;
    const int bb = c >> logF;
    const int f  = c & ((1 << logF) - 1);
    const float* src = x + (((size_t)bb * K) << logF) + f;
    bf16x8 r;
#pragma unroll
    for (int j = 0; j < 8; ++j) {
        int k = k0 + j;
        float v = (k < K) ? src[(size_t)k << logF] : 0.f;
        r[j] = (short)f2bf(v);
    }
    *(bf16x8*)(xt + (size_t)c * Kp + k0) = r;
}

// ---------------------------------------------------------------------------
// dsamp_mfma3: 128x128 tile MFMA resample (round-5, proven). D0/U0.
// ---------------------------------------------------------------------------
__global__ __launch_bounds__(256) void dsamp_mfma3_kernel(
    const float* __restrict__ A, const unsigned short* __restrict__ Xt,
    float* __restrict__ Y, int M, int K, int Kp, int logF, int kchunk,
    int atomic_flag)
{
    constexpr int PAD = 40;
    __shared__ unsigned short As[2][128 * PAD];
    __shared__ unsigned short Bs[2][128 * PAD];

    const int fmask = (1 << logF) - 1;
    const int m0   = blockIdx.x * 128;
    const int c0   = blockIdx.y * 128;
    const int kbeg = blockIdx.z * kchunk;
    int kend = kbeg + kchunk; if (kend > Kp) kend = Kp;
    const int nslab = (kend - kbeg + 31) >> 5;

    const int tid  = threadIdx.x;
    const int lane = tid & 63;
    const int wave = tid >> 6;
    const int wm   = (wave >> 1) * 64;
    const int wn   = (wave & 1) * 64;
    const int l15  = lane & 15;
    const int quad = lane >> 4;

    const int ar_row = tid >> 3;
    const int ar_k4  = (tid & 7) * 4;
    const int br_row = tid >> 2;
    const int br_k8  = (tid & 3) * 8;

    f32x4 acc[4][4];
#pragma unroll
    for (int i = 0; i < 4; ++i)
#pragma unroll
        for (int j = 0; j < 4; ++j) acc[i][j] = (f32x4){0.f, 0.f, 0.f, 0.f};

    float4 apre[4];
    bf16x8 bpre[2];

    auto loadAB = [&](int ko) {
#pragma unroll
        for (int i = 0; i < 4; ++i) {
            int m = m0 + ar_row + i * 32;
            int k = ko + ar_k4;
            float4 v = make_float4(0.f, 0.f, 0.f, 0.f);
            if (m < M) {
                const float* ap = A + (size_t)m * K;
                if (k + 3 < K) v = *(const float4*)(ap + k);
                else {
                    v.x = (k     < K) ? ap[k]     : 0.f;
                    v.y = (k + 1 < K) ? ap[k + 1] : 0.f;
                    v.z = (k + 2 < K) ? ap[k + 2] : 0.f;
                    v.w = (k + 3 < K) ? ap[k + 3] : 0.f;
                }
            }
            apre[i] = v;
        }
#pragma unroll
        for (int i = 0; i < 2; ++i)
            bpre[i] = *(const bf16x8*)(Xt + (size_t)(c0 + br_row + i * 64) * Kp + ko + br_k8);
    };
    auto stage = [&](int buf) {
#pragma unroll
        for (int i = 0; i < 4; ++i) {
            bf16x4 t;
            t[0] = (short)f2bf(apre[i].x);
            t[1] = (short)f2bf(apre[i].y);
            t[2] = (short)f2bf(apre[i].z);
            t[3] = (short)f2bf(apre[i].w);
            *(bf16x4*)&As[buf][(ar_row + i * 32) * PAD + ar_k4] = t;
        }
#pragma unroll
        for (int i = 0; i < 2; ++i)
            *(bf16x8*)&Bs[buf][(br_row + i * 64) * PAD + br_k8] = bpre[i];
    };

    loadAB(kbeg);
    stage(0);
    __syncthreads();

    for (int s = 0; s < nslab; ++s) {
        const int cur = s & 1;
        const bool more = (s + 1) < nslab;
        if (more) loadAB(kbeg + (s + 1) * 32);

        bf16x8 af[4], bfr[4];
#pragma unroll
        for (int t = 0; t < 4; ++t) {
            af[t]  = *(const bf16x8*)&As[cur][(wm + t * 16 + l15) * PAD + quad * 8];
            bfr[t] = *(const bf16x8*)&Bs[cur][(wn + t * 16 + l15) * PAD + quad * 8];
        }
#pragma unroll
        for (int tm = 0; tm < 4; ++tm)
#pragma unroll
            for (int tn = 0; tn < 4; ++tn)
                acc[tm][tn] = __builtin_amdgcn_mfma_f32_16x16x32_bf16(af[tm], bfr[tn], acc[tm][tn], 0, 0, 0);

        if (more) { stage(cur ^ 1); __syncthreads(); }
    }

#pragma unroll
    for (int tm = 0; tm < 4; ++tm)
#pragma unroll
        for (int tn = 0; tn < 4; ++tn)
#pragma unroll
            for (int reg = 0; reg < 4; ++reg) {
                int m  = m0 + wm + tm * 16 + quad * 4 + reg;
                int cc = c0 + wn + tn * 16 + l15;
                if (m < M) {
                    int bb = cc >> logF, f = cc & fmask;
                    float* dst = Y + (((size_t)bb * M + m) << logF) + f;
                    if (atomic_flag) atomicAdd(dst, acc[tm][tn][reg]);
                    else *dst = acc[tm][tn][reg];
                }
            }
}

// ---------------------------------------------------------------------------
// dsamp_mfma2 (round-4, proven): D1/U1.
// ---------------------------------------------------------------------------
__global__ __launch_bounds__(256) void dsamp_mfma2_kernel(
    const float* __restrict__ A, const float* __restrict__ X,
    float* __restrict__ Y, int M, int K, int logF, int kchunk, int atomic_flag)
{
    constexpr int PAD = 40;
    __shared__ unsigned short Xs[2][64 * PAD];

    const int fmask = (1 << logF) - 1;
    const int m0   = blockIdx.x * 64;
    const int c0   = blockIdx.y * 64;
    const int kbeg = blockIdx.z * kchunk;
    int kend = kbeg + kchunk; if (kend > K) kend = K;
    const int nslab = (kend - kbeg + 31) >> 5;

    const int tid  = threadIdx.x;
    const int lane = tid & 63;
    const int wave = tid >> 6;
    const int wm   = (wave >> 1) * 32;
    const int wn   = (wave & 1) * 32;
    const int l15  = lane & 15;
    const int quad = lane >> 4;

    const int skk  = tid >> 4;
    const int scg  = (tid & 15) * 4;
    const int cB   = c0 + scg;
    const int xbb  = cB >> logF;
    const int xf   = cB & fmask;
    const size_t xrowbase = (((size_t)xbb * K) << logF) + xf;

    const int mA0 = m0 + wm + l15;
    const int mA1 = mA0 + 16;
    const int kaoff = quad * 8;

    f32x4 acc[2][2];
    acc[0][0] = acc[0][1] = acc[1][0] = acc[1][1] = (f32x4){0.f, 0.f, 0.f, 0.f};

    float4 xn0, xn1;
    float ac0[8], ac1[8], an0[8], an1[8];

    {
        int k = kbeg + skk;
        xn0 = make_float4(0.f, 0.f, 0.f, 0.f);
        if (k < kend) xn0 = *(const float4*)(X + xrowbase + ((size_t)k << logF));
        k = kbeg + 16 + skk;
        xn1 = make_float4(0.f, 0.f, 0.f, 0.f);
        if (k < kend) xn1 = *(const float4*)(X + xrowbase + ((size_t)k << logF));
        int ka = kbeg + kaoff;
#pragma unroll
        for (int j = 0; j < 8; ++j) {
            ac0[j] = (mA0 < M && ka + j < kend) ? A[(size_t)mA0 * K + ka + j] : 0.f;
            ac1[j] = (mA1 < M && ka + j < kend) ? A[(size_t)mA1 * K + ka + j] : 0.f;
        }
        unsigned short* p = &Xs[0][0];
        p[(scg + 0) * PAD + skk] = f2bf(xn0.x);
        p[(scg + 1) * PAD + skk] = f2bf(xn0.y);
        p[(scg + 2) * PAD + skk] = f2bf(xn0.z);
        p[(scg + 3) * PAD + skk] = f2bf(xn0.w);
        int kk1 = 16 + skk;
        p[(scg + 0) * PAD + kk1] = f2bf(xn1.x);
        p[(scg + 1) * PAD + kk1] = f2bf(xn1.y);
        p[(scg + 2) * PAD + kk1] = f2bf(xn1.z);
        p[(scg + 3) * PAD + kk1] = f2bf(xn1.w);
    }
    __syncthreads();

    for (int s = 0; s < nslab; ++s) {
        const int cur = s & 1;
        const bool more = (s + 1 < nslab);
        if (more) {
            int k0 = kbeg + (s + 1) * 32;
            int k = k0 + skk;
            xn0 = make_float4(0.f, 0.f, 0.f, 0.f);
            if (k < kend) xn0 = *(const float4*)(X + xrowbase + ((size_t)k << logF));
            k = k0 + 16 + skk;
            xn1 = make_float4(0.f, 0.f, 0.f, 0.f);
            if (k < kend) xn1 = *(const float4*)(X + xrowbase + ((size_t)k << logF));
            int ka = k0 + kaoff;
#pragma unroll
            for (int j = 0; j < 8; ++j) {
                an0[j] = (mA0 < M && ka + j < kend) ? A[(size_t)mA0 * K + ka + j] : 0.f;
                an1[j] = (mA1 < M && ka + j < kend) ? A[(size_t)mA1 * K + ka + j] : 0.f;
            }
        }
        {
            const unsigned short* p = &Xs[cur][0];
            bf16x8 b0 = *(const bf16x8*)&p[(wn +      l15) * PAD + quad * 8];
            bf16x8 b1 = *(const bf16x8*)&p[(wn + 16 + l15) * PAD + quad * 8];
            bf16x8 a0 = pack8(ac0);
            bf16x8 a1 = pack8(ac1);
            acc[0][0] = __builtin_amdgcn_mfma_f32_16x16x32_bf16(a0, b0, acc[0][0], 0, 0, 0);
            acc[0][1] = __builtin_amdgcn_mfma_f32_16x16x32_bf16(a0, b1, acc[0][1], 0, 0, 0);
            acc[1][0] = __builtin_amdgcn_mfma_f32_16x16x32_bf16(a1, b0, acc[1][0], 0, 0, 0);
            acc[1][1] = __builtin_amdgcn_mfma_f32_16x16x32_bf16(a1, b1, acc[1][1], 0, 0, 0);
        }
        if (more) {
            unsigned short* q = &Xs[cur ^ 1][0];
            q[(scg + 0) * PAD + skk] = f2bf(xn0.x);
            q[(scg + 1) * PAD + skk] = f2bf(xn0.y);
            q[(scg + 2) * PAD + skk] = f2bf(xn0.z);
            q[(scg + 3) * PAD + skk] = f2bf(xn0.w);
            int kk1 = 16 + skk;
            q[(scg + 0) * PAD + kk1] = f2bf(xn1.x);
            q[(scg + 1) * PAD + kk1] = f2bf(xn1.y);
            q[(scg + 2) * PAD + kk1] = f2bf(xn1.z);
            q[(scg + 3) * PAD + kk1] = f2bf(xn1.w);
            __syncthreads();
#pragma unroll
            for (int j = 0; j < 8; ++j) { ac0[j] = an0[j]; ac1[j] = an1[j]; }
        }
    }

#pragma unroll
    for (int tm = 0; tm < 2; ++tm)
#pragma unroll
        for (int tn = 0; tn < 2; ++tn)
#pragma unroll
            for (int reg = 0; reg < 4; ++reg) {
                int m  = m0 + wm + tm * 16 + quad * 4 + reg;
                int cc = c0 + wn + tn * 16 + l15;
                if (m < M) {
                    int bb = cc >> logF, f = cc & fmask;
                    float* dst = Y + (((size_t)bb * M + m) << logF) + f;
                    if (atomic_flag) atomicAdd(dst, acc[tm][tn][reg]);
                    else *dst = acc[tm][tn][reg];
                }
            }
}

// ---------------------------------------------------------------------------
// conv_gemm with KFr guard: kf in [KFr, KF) contributes zero (K padding).
// ---------------------------------------------------------------------------
template<int MT, int OT>
__global__ __launch_bounds__(256) void conv_gemm_kernel(
    const float* __restrict__ x, const int* __restrict__ S,
    const float* __restrict__ W, const float* __restrict__ bias,
    float* __restrict__ y, int Nv, int logF, int O, int KF, int KFr,
    int elu_flag)
{
    constexpr int CT = OT / 4;
    constexpr int RT = 256 / CT;
    static_assert(RT * 4 == MT, "tile shape");
    __shared__ float Gs[32][MT];
    __shared__ float Ws[32][OT];

    const int b   = blockIdx.y;
    const int n0  = blockIdx.x * MT;
    const int tid = threadIdx.x;
    const int cx  = tid % CT;
    const int ry  = tid / CT;
    const int r0  = ry * 4;
    const int o0  = cx * 4;
    const int fmask = (1 << logF) - 1;
    const size_t xb = (size_t)b * Nv;

    float acc[4][4];
#pragma unroll
    for (int i = 0; i < 4; ++i)
#pragma unroll
        for (int j = 0; j < 4; ++j) acc[i][j] = 0.f;

    for (int k0 = 0; k0 < KF; k0 += 32) {
        constexpr int GSLOTS = MT * 8;
#pragma unroll
        for (int i = 0; i < GSLOTS / 256; ++i) {
            int idx = tid + i * 256;
            int r   = idx & (MT - 1);
            int jg  = idx / MT;
            int j0  = jg * 4;
            int n   = n0 + r;
            int kf  = k0 + j0;
            float4 v = make_float4(0.f, 0.f, 0.f, 0.f);
            if (n < Nv && kf < KFr) {
                int k   = kf >> logF;
                int f   = kf & fmask;
                int src = S[n * SPK + k];
                v = *(const float4*)(x + ((xb + src) << logF) + f);
            }
            Gs[j0 + 0][r] = v.x; Gs[j0 + 1][r] = v.y;
            Gs[j0 + 2][r] = v.z; Gs[j0 + 3][r] = v.w;
        }
        constexpr int WSLOTS = OT * 8;
#pragma unroll
        for (int i = 0; i < (WSLOTS + 255) / 256; ++i) {
            int idx = tid + i * 256;
            if (WSLOTS >= 256 || idx < WSLOTS) {
                int o  = idx & (OT - 1);
                int jg = idx / OT;
                int j0 = jg * 4;
                float4 v = *(const float4*)(W + (size_t)o * KF + k0 + j0);
                Ws[j0 + 0][o] = v.x; Ws[j0 + 1][o] = v.y;
                Ws[j0 + 2][o] = v.z; Ws[j0 + 3][o] = v.w;
            }
        }
        __syncthreads();
#pragma unroll
        for (int kk = 0; kk < 32; ++kk) {
            float4 g = *(const float4*)&Gs[kk][r0];
            float4 w = *(const float4*)&Ws[kk][o0];
            acc[0][0] += g.x * w.x; acc[0][1] += g.x * w.y; acc[0][2] += g.x * w.z; acc[0][3] += g.x * w.w;
            acc[1][0] += g.y * w.x; acc[1][1] += g.y * w.y; acc[1][2] += g.y * w.z; acc[1][3] += g.y * w.w;
            acc[2][0] += g.z * w.x; acc[2][1] += g.z * w.y; acc[2][2] += g.z * w.z; acc[2][3] += g.z * w.w;
            acc[3][0] += g.w * w.x; acc[3][1] += g.w * w.y; acc[3][2] += g.w * w.z; acc[3][3] += g.w * w.w;
        }
        __syncthreads();
    }

    float4 bv = *(const float4*)(bias + o0);
#pragma unroll
    for (int i = 0; i < 4; ++i) {
        int n = n0 + r0 + i;
        if (n >= Nv) continue;
        float v0 = acc[i][0] + bv.x;
        float v1 = acc[i][1] + bv.y;
        float v2 = acc[i][2] + bv.z;
        float v3 = acc[i][3] + bv.w;
        if (elu_flag) {
            v0 = v0 > 0.f ? v0 : expm1f(v0);
            v1 = v1 > 0.f ? v1 : expm1f(v1);
            v2 = v2 > 0.f ? v2 : expm1f(v2);
            v3 = v3 > 0.f ? v3 : expm1f(v3);
        }
        if (n == Nv - 1) { v0 = v1 = v2 = v3 = 0.f; }
        *(float4*)(y + ((size_t)b * Nv + n) * O + o0) = make_float4(v0, v1, v2, v3);
    }
}

// ---------------------------------------------------------------------------
// VALU down/up-sample (tiny levels 2-3 only).
// ---------------------------------------------------------------------------
__global__ __launch_bounds__(256) void dsamp_kernel(
    const float* __restrict__ A, const float* __restrict__ X,
    float* __restrict__ Y, int M, int N, int F)
{
    __shared__ float As[16][68];
    __shared__ float Xs[16][64];

    const int m0  = blockIdx.x * 64;
    const int c0  = blockIdx.y * 64;
    const int tid = threadIdx.x;
    const int tx  = tid & 15;
    const int ty  = tid >> 4;

    float acc[4][4];
#pragma unroll
    for (int i = 0; i < 4; ++i)
#pragma unroll
        for (int j = 0; j < 4; ++j) acc[i][j] = 0.f;

    for (int k0 = 0; k0 < N; k0 += 16) {
#pragma unroll
        for (int p = 0; p < 4; ++p) {
            int r  = (tid >> 4) + p * 16;
            int kk = tid & 15;
            int m  = m0 + r;
            int n  = k0 + kk;
            float v = 0.f;
            if (m < M && n < N) v = A[(size_t)m * N + n];
            As[kk][r] = v;
        }
        {
            int kk = tid >> 4;
            int cc = (tid & 15) * 4;
            int n  = k0 + kk;
            float4 v = make_float4(0.f, 0.f, 0.f, 0.f);
            if (n < N) {
                int c  = c0 + cc;
                int bb = c / F;
                int f  = c - bb * F;
                v = *(const float4*)(X + ((size_t)bb * N + n) * F + f);
            }
            *(float4*)&Xs[kk][cc] = v;
        }
        __syncthreads();
#pragma unroll
        for (int kk = 0; kk < 16; ++kk) {
            float4 av = *(const float4*)&As[kk][ty * 4];
            float4 xv = *(const float4*)&Xs[kk][tx * 4];
            acc[0][0] += av.x * xv.x; acc[0][1] += av.x * xv.y; acc[0][2] += av.x * xv.z; acc[0][3] += av.x * xv.w;
            acc[1][0] += av.y * xv.x; acc[1][1] += av.y * xv.y; acc[1][2] += av.y * xv.z; acc[1][3] += av.y * xv.w;
            acc[2][0] += av.z * xv.x; acc[2][1] += av.z * xv.y; acc[2][2] += av.z * xv.z; acc[2][3] += av.z * xv.w;
            acc[3][0] += av.w * xv.x; acc[3][1] += av.w * xv.y; acc[3][2] += av.w * xv.z; acc[3][3] += av.w * xv.w;
        }
        __syncthreads();
    }

    const int cbase = c0 + tx * 4;
    const int bb = cbase / F;
    const int f  = cbase - bb * F;
#pragma unroll
    for (int i = 0; i < 4; ++i) {
        int m = m0 + ty * 4 + i;
        if (m < M) {
            float4 v = make_float4(acc[i][0], acc[i][1], acc[i][2], acc[i][3]);
            *(float4*)(Y + ((size_t)bb * M + m) * F + f) = v;
        }
    }
}

// ---------------------------------------------------------------------------
// fc_wave: one 64-lane wave per output element (round-6, proven).
// ---------------------------------------------------------------------------
__global__ __launch_bounds__(256) void fc_wave_kernel(
    const float* __restrict__ in, const float* __restrict__ W,
    const float* __restrict__ bias, float* __restrict__ out,
    int In, int O, int dup)
{
    const int gw   = blockIdx.x * 4 + (threadIdx.x >> 6);
    const int lane = threadIdx.x & 63;
    const int b = gw / O;
    const int o = gw - b * O;
    const float* xr = in + (size_t)b * In;
    float acc = 0.f;
    if (dup) {
        const float* wr = W + (size_t)o * (2 * In);
        for (int k = lane; k < In; k += 64)
            acc += xr[k] * (wr[k] + wr[In + k]);
    } else {
        const float* wr = W + (size_t)o * In;
        for (int k = lane; k < In; k += 64)
            acc += xr[k] * wr[k];
    }
#pragma unroll
    for (int off = 32; off > 0; off >>= 1)
        acc += __shfl_down(acc, off, 64);
    if (lane == 0) out[(size_t)b * O + o] = acc + bias[o];
}

// ---------------------------------------------------------------------------
// Padding / extraction helpers (round 7).
// ---------------------------------------------------------------------------
// enc_w0 [16][36] (kf=k*3+f) -> wp [16][64] (kf=k*4+f, f<3, k<12; else 0)
__global__ __launch_bounds__(256) void pad_e0_w_kernel(
    const float* __restrict__ w, float* __restrict__ wp)
{
    int i = blockIdx.x * 256 + threadIdx.x;
    if (i < 1024) {
        int o = i >> 6, kf = i & 63;
        int k = kf >> 2, f = kf & 3;
        wp[i] = (f < 3 && k < 12) ? w[o * 36 + k * 3 + f] : 0.f;
    }
}
// x [.,3] -> xp [.,4] zero-padded
__global__ __launch_bounds__(256) void pad_x4_kernel(
    const float* __restrict__ x, float* __restrict__ xp, int n)
{
    int i = blockIdx.x * 256 + threadIdx.x;
    if (i < n) {
        int f = i & 3, nb = i >> 2;
        xp[i] = (f < 3) ? x[nb * 3 + f] : 0.f;
    }
}
// dec_w4 [3][192], dec_b4 [3] -> [16][192], [16] zero-padded in O
__global__ __launch_bounds__(256) void pad_c4_w_kernel(
    const float* __restrict__ w, const float* __restrict__ b,
    float* __restrict__ wp, float* __restrict__ bp)
{
    int i = blockIdx.x * 256 + threadIdx.x;
    if (i < 3072) {
        int o = i / 192;
        wp[i] = (o < 3) ? w[i] : 0.f;
    }
    if (i < 16) bp[i] = (i < 3) ? b[i] : 0.f;
}
// cp[b][n][16] -> out0[b][n][3], out1 = out0 + template
__global__ __launch_bounds__(256) void extract_add_kernel(
    const float* __restrict__ cp, const float* __restrict__ t,
    float* __restrict__ o0, float* __restrict__ o1, int n)
{
    int i = blockIdx.x * 256 + threadIdx.x;
    if (i < n) {
        int f = i % 3, nb = i / 3;
        float v = cp[(size_t)nb * 16 + f];
        o0[i] = v;
        o1[i] = v + t[i];
    }
}

// ---------------------------------------------------------------------------

static inline int ilog2(int v) { int l = 0; while ((1 << l) < v) ++l; return l; }

static inline void conv_launch(const float* x, const int* S, const float* W,
                               const float* b, float* y, int Nv, int F, int O,
                               int elu, hipStream_t s)
{
    int KF = SPK * F;
    int logF = ilog2(F);
    if (O == 16) {
        dim3 grid((Nv + 255) / 256, BATCH);
        conv_gemm_kernel<256, 16><<<grid, 256, 0, s>>>(x, S, W, b, y, Nv, logF, O, KF, KF, elu);
    } else if (O == 32) {
        dim3 grid((Nv + 127) / 128, BATCH);
        conv_gemm_kernel<128, 32><<<grid, 256, 0, s>>>(x, S, W, b, y, Nv, logF, O, KF, KF, elu);
    } else if (O == 64) {
        dim3 grid((Nv + 63) / 64, BATCH);
        conv_gemm_kernel<64, 64><<<grid, 256, 0, s>>>(x, S, W, b, y, Nv, logF, O, KF, KF, elu);
    } else {
        dim3 grid((Nv + 31) / 32, BATCH);
        conv_gemm_kernel<32, 128><<<grid, 256, 0, s>>>(x, S, W, b, y, Nv, logF, O, KF, KF, elu);
    }
}

static inline void dsamp_mfma2_launch(const float* A, const float* X, float* Y,
                                      int M, int K, int F, int ks, hipStream_t s)
{
    int kchunk = (K + ks - 1) / ks;
    kchunk = (kchunk + 31) & ~31;
    int ksz = (K + kchunk - 1) / kchunk;
    dim3 grid((M + 63) / 64, F, ksz);
    dsamp_mfma2_kernel<<<grid, 256, 0, s>>>(A, X, Y, M, K, ilog2(F), kchunk, ksz > 1 ? 1 : 0);
}

static inline void dsamp_mfma3_launch(const float* A, const unsigned short* Xt,
                                      float* Y, int M, int K, int Kp, int F,
                                      int ks, hipStream_t s)
{
    int slabs = Kp >> 5;
    int kchunk = ((slabs + ks - 1) / ks) * 32;
    int ksz = (Kp + kchunk - 1) / kchunk;
    dim3 grid((M + 127) / 128, (BATCH * F) / 128, ksz);
    dsamp_mfma3_kernel<<<grid, 256, 0, s>>>(A, Xt, Y, M, K, Kp, ilog2(F), kchunk,
                                            ksz > 1 ? 1 : 0);
}

static inline void dsamp_launch(const float* A, const float* X, float* Y,
                                int M, int N, int F, hipStream_t s)
{
    dim3 grid((M + 63) / 64, F);
    dsamp_kernel<<<grid, 256, 0, s>>>(A, X, Y, M, N, F);
}

extern "C" void kernel_launch(void* const* d_in, const int* in_sizes, int n_in,
                              void* d_out, int out_size, void* d_ws, size_t ws_size,
                              hipStream_t stream)
{
    const float* x_talking = (const float*)d_in[0];
    const float* templ     = (const float*)d_in[1];
    const float* D0 = (const float*)d_in[2];
    const float* U0 = (const float*)d_in[3];
    const float* D1 = (const float*)d_in[4];
    const float* U1 = (const float*)d_in[5];
    const float* D2 = (const float*)d_in[6];
    const float* U2 = (const float*)d_in[7];
    const float* D3 = (const float*)d_in[8];
    const float* U3 = (const float*)d_in[9];
    const float* enc_w0 = (const float*)d_in[10]; const float* enc_b0 = (const float*)d_in[11];
    const float* enc_w1 = (const float*)d_in[12]; const float* enc_b1 = (const float*)d_in[13];
    const float* enc_w2 = (const float*)d_in[14]; const float* enc_b2 = (const float*)d_in[15];
    const float* enc_w3 = (const float*)d_in[16]; const float* enc_b3 = (const float*)d_in[17];
    const float* fc_enc_w = (const float*)d_in[18]; const float* fc_enc_b = (const float*)d_in[19];
    const float* fc_dec_w = (const float*)d_in[20]; const float* fc_dec_b = (const float*)d_in[21];
    const float* dec_w0 = (const float*)d_in[22]; const float* dec_b0 = (const float*)d_in[23];
    const float* dec_w1 = (const float*)d_in[24]; const float* dec_b1 = (const float*)d_in[25];
    const float* dec_w2 = (const float*)d_in[26]; const float* dec_b2 = (const float*)d_in[27];
    const float* dec_w3 = (const float*)d_in[28]; const float* dec_b3 = (const float*)d_in[29];
    const float* dec_w4 = (const float*)d_in[30]; const float* dec_b4 = (const float*)d_in[31];
    const int* S0 = (const int*)d_in[32];
    const int* S1 = (const int*)d_in[33];
    const int* S2 = (const int*)d_in[34];
    const int* S3 = (const int*)d_in[35];

    float* bufA = (float*)d_ws;            // 10,289,152 floats (41.2 MB)
    float* bufB = bufA + 10289152;         // 5,144,576 floats (20.6 MB)

    float* out0 = (float*)d_out;           // 964,608 floats
    float* out1 = out0 + 964608;

    // Workspace aliases (lifetimes audited):
    unsigned short* Xt_e0 = (unsigned short*)(bufB + 1290240);  // d0-phase B operand
    unsigned short* Xt_c2 = (unsigned short*)(bufB + 2574336);  // u0-phase B operand
    float* xpad   = bufA + 5200000;   // e0 input padded to F=4 (1,286,144 fl)
    float* WpE0   = bufA + 6600000;   // e0 W padded [16][64]   (dead before u1)
    float* WpC4   = bufA + 6700000;   // c4 W padded [16][192]  (written after c3)
    float* BpC4   = bufA + 6705000;   // c4 bias padded [16]
    // c4pad output reuses bufA[0..5,144,576] (u0 data dead after c3 reads it)

    size_t arena_bytes = (size_t)(10289152 + 5144576) * sizeof(float);
    if (arena_bytes > ws_size) arena_bytes = ws_size;
    hipMemsetAsync(d_ws, 0, arena_bytes, stream);

    // ---- encoder ----
    pad_e0_w_kernel<<<4, 256, 0, stream>>>(enc_w0, WpE0);
    pad_x4_kernel<<<5024, 256, 0, stream>>>(x_talking, xpad, 1286144);
    {   // e0: F=4(pad), KF=64 (KFr=48), O=16
        dim3 grid((5024 + 255) / 256, BATCH);
        conv_gemm_kernel<256, 16><<<grid, 256, 0, stream>>>(
            xpad, S0, WpE0, enc_b0, bufA, 5024, 2, 16, 64, 48, 1);
    }
    xpose_bf16_kernel<<<dim3(628, 4), 256, 0, stream>>>(bufA, Xt_e0, 5024, 5024, 4);
    dsamp_mfma3_launch(D0, Xt_e0, bufB, 1257, 5024, 5024, 16, 8, stream);       // d0 [atomic ks=8]
    conv_launch(bufB, S1, enc_w1, enc_b1, bufA, 1257, 16, 32, 1, stream);       // e1
    hipMemsetAsync(bufB, 0, (size_t)645120 * sizeof(float), stream);            // zero d1 target
    dsamp_mfma2_launch(D1, bufA, bufB, 315, 1257, 32, 8, stream);               // d1 [atomic ks=8]
    conv_launch(bufB, S2, enc_w2, enc_b2, bufA, 315, 32, 64, 1, stream);        // e2
    dsamp_launch(D2, bufA, bufB, 80, 315, 64, stream);                          // d2
    conv_launch(bufB, S3, enc_w3, enc_b3, bufA, 80, 64, 128, 1, stream);        // e3
    dsamp_launch(D3, bufA, bufB, 21, 80, 128, stream);                          // d3

    fc_wave_kernel<<<dim3((BATCH * 128) / 4), 256, 0, stream>>>(bufB, fc_enc_w, fc_enc_b, bufA, 2688, 128, 0);
    fc_wave_kernel<<<dim3((BATCH * 2688) / 4), 256, 0, stream>>>(bufA, fc_dec_w, fc_dec_b, bufB, 128, 2688, 1);

    // ---- decoder ----
    dsamp_launch(U3, bufB, bufA, 80, 21, 128, stream);                          // u3
    conv_launch(bufA, S3, dec_w0, dec_b0, bufB, 80, 128, 64, 1, stream);        // c0
    dsamp_launch(U2, bufB, bufA, 315, 80, 64, stream);                          // u2
    conv_launch(bufA, S2, dec_w1, dec_b1, bufB, 315, 64, 32, 1, stream);        // c1
    dsamp_mfma2_launch(U1, bufB, bufA, 1257, 315, 32, 1, stream);               // u1 (plain)
    conv_launch(bufA, S1, dec_w2, dec_b2, bufB, 1257, 32, 32, 1, stream);       // c2
    xpose_bf16_kernel<<<dim3(160, 8), 256, 0, stream>>>(bufB, Xt_c2, 1257, 1280, 5);
    hipMemsetAsync(bufA, 0, (size_t)10289152 * sizeof(float), stream);          // zero u0 target
    dsamp_mfma3_launch(U0, Xt_c2, bufA, 5024, 1257, 1280, 32, 2, stream);       // u0 [atomic ks=2]
    conv_launch(bufA, S0, dec_w3, dec_b3, bufB, 5024, 32, 16, 1, stream);       // c3
    pad_c4_w_kernel<<<12, 256, 0, stream>>>(dec_w4, dec_b4, WpC4, BpC4);
    {   // c4: F=16, O=16(pad, rows 3..15 zero), identity act -> c4pad in bufA
        dim3 grid((5024 + 255) / 256, BATCH);
        conv_gemm_kernel<256, 16><<<grid, 256, 0, stream>>>(
            bufB, S0, WpC4, BpC4, bufA, 5024, 4, 16, 192, 192, 0);
    }
    extract_add_kernel<<<(964608 + 255) / 256, 256, 0, stream>>>(bufA, templ, out0, out1, 964608);
}

// Round 8
// 1109.227 us; speedup vs baseline: 4.1342x; 1.1678x over previous
//
#include <hip/hip_runtime.h>
#include <cstddef>

// ---------------------------------------------------------------------------
// SpiralAutoencoder on MI355X — round 8:
//  * c3/c4 gather operands converted to bf16 (halves random-gather bytes);
//    new conv_gemm_bf16 kernel (same proven structure, bf16x4 gathers).
//  * all conv_gemm grids swapped to (batch, mtile): batch -> XCD affinity,
//    pinning each batch's activation slab to one XCD's L2.
// ---------------------------------------------------------------------------

#define BATCH 64
#define SPK 12  // spiral length

typedef __attribute__((ext_vector_type(8))) short bf16x8;
typedef __attribute__((ext_vector_type(4))) short bf16x4;
typedef __attribute__((ext_vector_type(4))) float f32x4;

__device__ __forceinline__ unsigned short f2bf(float x) {
    union { float f; unsigned int u; } v; v.f = x;
    unsigned int r = v.u + 0x7FFF + ((v.u >> 16) & 1);  // RNE
    return (unsigned short)(r >> 16);
}
__device__ __forceinline__ float bf2f(unsigned short u) {
    union { unsigned int i; float f; } v; v.i = ((unsigned int)u) << 16;
    return v.f;
}

__device__ __forceinline__ bf16x8 pack8(const float* v) {
    bf16x8 r;
#pragma unroll
    for (int j = 0; j < 8; ++j) r[j] = (short)f2bf(v[j]);
    return r;
}

// ---------------------------------------------------------------------------
// Flat fp32 -> bf16 convert (8 elems/thread).
// ---------------------------------------------------------------------------
__global__ __launch_bounds__(256) void f32_to_bf16_kernel(
    const float* __restrict__ in, unsigned short* __restrict__ out, int n8)
{
    int i = blockIdx.x * 256 + threadIdx.x;
    if (i < n8) {
        const float* p = in + (size_t)i * 8;
        bf16x8 r;
#pragma unroll
        for (int j = 0; j < 8; ++j) r[j] = (short)f2bf(p[j]);
        *(bf16x8*)(out + (size_t)i * 8) = r;
    }
}

// ---------------------------------------------------------------------------
// Transpose-convert: x [b][k][f] fp32 -> xt [c][k] bf16, c = b*F+f, stride Kp.
// ---------------------------------------------------------------------------
__global__ __launch_bounds__(256) void xpose_bf16_kernel(
    const float* __restrict__ x, unsigned short* __restrict__ xt,
    int K, int Kp, int logF)
{
    const int c  = blockIdx.y * 256 + threadIdx.x;
    const int k0 = blockIdx.x * 8;
    const int bb = c >> logF;
    const int f  = c & ((1 << logF) - 1);
    const float* src = x + (((size_t)bb * K) << logF) + f;
    bf16x8 r;
#pragma unroll
    for (int j = 0; j < 8; ++j) {
        int k = k0 + j;
        float v = (k < K) ? src[(size_t)k << logF] : 0.f;
        r[j] = (short)f2bf(v);
    }
    *(bf16x8*)(xt + (size_t)c * Kp + k0) = r;
}

// ---------------------------------------------------------------------------
// dsamp_mfma3: 128x128 tile MFMA resample (round-5, proven). D0/U0.
// ---------------------------------------------------------------------------
__global__ __launch_bounds__(256) void dsamp_mfma3_kernel(
    const float* __restrict__ A, const unsigned short* __restrict__ Xt,
    float* __restrict__ Y, int M, int K, int Kp, int logF, int kchunk,
    int atomic_flag)
{
    constexpr int PAD = 40;
    __shared__ unsigned short As[2][128 * PAD];
    __shared__ unsigned short Bs[2][128 * PAD];

    const int fmask = (1 << logF) - 1;
    const int m0   = blockIdx.x * 128;
    const int c0   = blockIdx.y * 128;
    const int kbeg = blockIdx.z * kchunk;
    int kend = kbeg + kchunk; if (kend > Kp) kend = Kp;
    const int nslab = (kend - kbeg + 31) >> 5;

    const int tid  = threadIdx.x;
    const int lane = tid & 63;
    const int wave = tid >> 6;
    const int wm   = (wave >> 1) * 64;
    const int wn   = (wave & 1) * 64;
    const int l15  = lane & 15;
    const int quad = lane >> 4;

    const int ar_row = tid >> 3;
    const int ar_k4  = (tid & 7) * 4;
    const int br_row = tid >> 2;
    const int br_k8  = (tid & 3) * 8;

    f32x4 acc[4][4];
#pragma unroll
    for (int i = 0; i < 4; ++i)
#pragma unroll
        for (int j = 0; j < 4; ++j) acc[i][j] = (f32x4){0.f, 0.f, 0.f, 0.f};

    float4 apre[4];
    bf16x8 bpre[2];

    auto loadAB = [&](int ko) {
#pragma unroll
        for (int i = 0; i < 4; ++i) {
            int m = m0 + ar_row + i * 32;
            int k = ko + ar_k4;
            float4 v = make_float4(0.f, 0.f, 0.f, 0.f);
            if (m < M) {
                const float* ap = A + (size_t)m * K;
                if (k + 3 < K) v = *(const float4*)(ap + k);
                else {
                    v.x = (k     < K) ? ap[k]     : 0.f;
                    v.y = (k + 1 < K) ? ap[k + 1] : 0.f;
                    v.z = (k + 2 < K) ? ap[k + 2] : 0.f;
                    v.w = (k + 3 < K) ? ap[k + 3] : 0.f;
                }
            }
            apre[i] = v;
        }
#pragma unroll
        for (int i = 0; i < 2; ++i)
            bpre[i] = *(const bf16x8*)(Xt + (size_t)(c0 + br_row + i * 64) * Kp + ko + br_k8);
    };
    auto stage = [&](int buf) {
#pragma unroll
        for (int i = 0; i < 4; ++i) {
            bf16x4 t;
            t[0] = (short)f2bf(apre[i].x);
            t[1] = (short)f2bf(apre[i].y);
            t[2] = (short)f2bf(apre[i].z);
            t[3] = (short)f2bf(apre[i].w);
            *(bf16x4*)&As[buf][(ar_row + i * 32) * PAD + ar_k4] = t;
        }
#pragma unroll
        for (int i = 0; i < 2; ++i)
            *(bf16x8*)&Bs[buf][(br_row + i * 64) * PAD + br_k8] = bpre[i];
    };

    loadAB(kbeg);
    stage(0);
    __syncthreads();

    for (int s = 0; s < nslab; ++s) {
        const int cur = s & 1;
        const bool more = (s + 1) < nslab;
        if (more) loadAB(kbeg + (s + 1) * 32);

        bf16x8 af[4], bfr[4];
#pragma unroll
        for (int t = 0; t < 4; ++t) {
            af[t]  = *(const bf16x8*)&As[cur][(wm + t * 16 + l15) * PAD + quad * 8];
            bfr[t] = *(const bf16x8*)&Bs[cur][(wn + t * 16 + l15) * PAD + quad * 8];
        }
#pragma unroll
        for (int tm = 0; tm < 4; ++tm)
#pragma unroll
            for (int tn = 0; tn < 4; ++tn)
                acc[tm][tn] = __builtin_amdgcn_mfma_f32_16x16x32_bf16(af[tm], bfr[tn], acc[tm][tn], 0, 0, 0);

        if (more) { stage(cur ^ 1); __syncthreads(); }
    }

#pragma unroll
    for (int tm = 0; tm < 4; ++tm)
#pragma unroll
        for (int tn = 0; tn < 4; ++tn)
#pragma unroll
            for (int reg = 0; reg < 4; ++reg) {
                int m  = m0 + wm + tm * 16 + quad * 4 + reg;
                int cc = c0 + wn + tn * 16 + l15;
                if (m < M) {
                    int bb = cc >> logF, f = cc & fmask;
                    float* dst = Y + (((size_t)bb * M + m) << logF) + f;
                    if (atomic_flag) atomicAdd(dst, acc[tm][tn][reg]);
                    else *dst = acc[tm][tn][reg];
                }
            }
}

// ---------------------------------------------------------------------------
// dsamp_mfma2 (round-4, proven): D1/U1.
// ---------------------------------------------------------------------------
__global__ __launch_bounds__(256) void dsamp_mfma2_kernel(
    const float* __restrict__ A, const float* __restrict__ X,
    float* __restrict__ Y, int M, int K, int logF, int kchunk, int atomic_flag)
{
    constexpr int PAD = 40;
    __shared__ unsigned short Xs[2][64 * PAD];

    const int fmask = (1 << logF) - 1;
    const int m0   = blockIdx.x * 64;
    const int c0   = blockIdx.y * 64;
    const int kbeg = blockIdx.z * kchunk;
    int kend = kbeg + kchunk; if (kend > K) kend = K;
    const int nslab = (kend - kbeg + 31) >> 5;

    const int tid  = threadIdx.x;
    const int lane = tid & 63;
    const int wave = tid >> 6;
    const int wm   = (wave >> 1) * 32;
    const int wn   = (wave & 1) * 32;
    const int l15  = lane & 15;
    const int quad = lane >> 4;

    const int skk  = tid >> 4;
    const int scg  = (tid & 15) * 4;
    const int cB   = c0 + scg;
    const int xbb  = cB >> logF;
    const int xf   = cB & fmask;
    const size_t xrowbase = (((size_t)xbb * K) << logF) + xf;

    const int mA0 = m0 + wm + l15;
    const int mA1 = mA0 + 16;
    const int kaoff = quad * 8;

    f32x4 acc[2][2];
    acc[0][0] = acc[0][1] = acc[1][0] = acc[1][1] = (f32x4){0.f, 0.f, 0.f, 0.f};

    float4 xn0, xn1;
    float ac0[8], ac1[8], an0[8], an1[8];

    {
        int k = kbeg + skk;
        xn0 = make_float4(0.f, 0.f, 0.f, 0.f);
        if (k < kend) xn0 = *(const float4*)(X + xrowbase + ((size_t)k << logF));
        k = kbeg + 16 + skk;
        xn1 = make_float4(0.f, 0.f, 0.f, 0.f);
        if (k < kend) xn1 = *(const float4*)(X + xrowbase + ((size_t)k << logF));
        int ka = kbeg + kaoff;
#pragma unroll
        for (int j = 0; j < 8; ++j) {
            ac0[j] = (mA0 < M && ka + j < kend) ? A[(size_t)mA0 * K + ka + j] : 0.f;
            ac1[j] = (mA1 < M && ka + j < kend) ? A[(size_t)mA1 * K + ka + j] : 0.f;
        }
        unsigned short* p = &Xs[0][0];
        p[(scg + 0) * PAD + skk] = f2bf(xn0.x);
        p[(scg + 1) * PAD + skk] = f2bf(xn0.y);
        p[(scg + 2) * PAD + skk] = f2bf(xn0.z);
        p[(scg + 3) * PAD + skk] = f2bf(xn0.w);
        int kk1 = 16 + skk;
        p[(scg + 0) * PAD + kk1] = f2bf(xn1.x);
        p[(scg + 1) * PAD + kk1] = f2bf(xn1.y);
        p[(scg + 2) * PAD + kk1] = f2bf(xn1.z);
        p[(scg + 3) * PAD + kk1] = f2bf(xn1.w);
    }
    __syncthreads();

    for (int s = 0; s < nslab; ++s) {
        const int cur = s & 1;
        const bool more = (s + 1 < nslab);
        if (more) {
            int k0 = kbeg + (s + 1) * 32;
            int k = k0 + skk;
            xn0 = make_float4(0.f, 0.f, 0.f, 0.f);
            if (k < kend) xn0 = *(const float4*)(X + xrowbase + ((size_t)k << logF));
            k = k0 + 16 + skk;
            xn1 = make_float4(0.f, 0.f, 0.f, 0.f);
            if (k < kend) xn1 = *(const float4*)(X + xrowbase + ((size_t)k << logF));
            int ka = k0 + kaoff;
#pragma unroll
            for (int j = 0; j < 8; ++j) {
                an0[j] = (mA0 < M && ka + j < kend) ? A[(size_t)mA0 * K + ka + j] : 0.f;
                an1[j] = (mA1 < M && ka + j < kend) ? A[(size_t)mA1 * K + ka + j] : 0.f;
            }
        }
        {
            const unsigned short* p = &Xs[cur][0];
            bf16x8 b0 = *(const bf16x8*)&p[(wn +      l15) * PAD + quad * 8];
            bf16x8 b1 = *(const bf16x8*)&p[(wn + 16 + l15) * PAD + quad * 8];
            bf16x8 a0 = pack8(ac0);
            bf16x8 a1 = pack8(ac1);
            acc[0][0] = __builtin_amdgcn_mfma_f32_16x16x32_bf16(a0, b0, acc[0][0], 0, 0, 0);
            acc[0][1] = __builtin_amdgcn_mfma_f32_16x16x32_bf16(a0, b1, acc[0][1], 0, 0, 0);
            acc[1][0] = __builtin_amdgcn_mfma_f32_16x16x32_bf16(a1, b0, acc[1][0], 0, 0, 0);
            acc[1][1] = __builtin_amdgcn_mfma_f32_16x16x32_bf16(a1, b1, acc[1][1], 0, 0, 0);
        }
        if (more) {
            unsigned short* q = &Xs[cur ^ 1][0];
            q[(scg + 0) * PAD + skk] = f2bf(xn0.x);
            q[(scg + 1) * PAD + skk] = f2bf(xn0.y);
            q[(scg + 2) * PAD + skk] = f2bf(xn0.z);
            q[(scg + 3) * PAD + skk] = f2bf(xn0.w);
            int kk1 = 16 + skk;
            q[(scg + 0) * PAD + kk1] = f2bf(xn1.x);
            q[(scg + 1) * PAD + kk1] = f2bf(xn1.y);
            q[(scg + 2) * PAD + kk1] = f2bf(xn1.z);
            q[(scg + 3) * PAD + kk1] = f2bf(xn1.w);
            __syncthreads();
#pragma unroll
            for (int j = 0; j < 8; ++j) { ac0[j] = an0[j]; ac1[j] = an1[j]; }
        }
    }

#pragma unroll
    for (int tm = 0; tm < 2; ++tm)
#pragma unroll
        for (int tn = 0; tn < 2; ++tn)
#pragma unroll
            for (int reg = 0; reg < 4; ++reg) {
                int m  = m0 + wm + tm * 16 + quad * 4 + reg;
                int cc = c0 + wn + tn * 16 + l15;
                if (m < M) {
                    int bb = cc >> logF, f = cc & fmask;
                    float* dst = Y + (((size_t)bb * M + m) << logF) + f;
                    if (atomic_flag) atomicAdd(dst, acc[tm][tn][reg]);
                    else *dst = acc[tm][tn][reg];
                }
            }
}

// ---------------------------------------------------------------------------
// conv_gemm (fp32 gather). Grid: (batch, mtile) — batch -> XCD affinity.
// ---------------------------------------------------------------------------
template<int MT, int OT>
__global__ __launch_bounds__(256) void conv_gemm_kernel(
    const float* __restrict__ x, const int* __restrict__ S,
    const float* __restrict__ W, const float* __restrict__ bias,
    float* __restrict__ y, int Nv, int logF, int O, int KF, int KFr,
    int elu_flag)
{
    constexpr int CT = OT / 4;
    constexpr int RT = 256 / CT;
    static_assert(RT * 4 == MT, "tile shape");
    __shared__ float Gs[32][MT];
    __shared__ float Ws[32][OT];

    const int b   = blockIdx.x;
    const int n0  = blockIdx.y * MT;
    const int tid = threadIdx.x;
    const int cx  = tid % CT;
    const int ry  = tid / CT;
    const int r0  = ry * 4;
    const int o0  = cx * 4;
    const int fmask = (1 << logF) - 1;
    const size_t xb = (size_t)b * Nv;

    float acc[4][4];
#pragma unroll
    for (int i = 0; i < 4; ++i)
#pragma unroll
        for (int j = 0; j < 4; ++j) acc[i][j] = 0.f;

    for (int k0 = 0; k0 < KF; k0 += 32) {
        constexpr int GSLOTS = MT * 8;
#pragma unroll
        for (int i = 0; i < GSLOTS / 256; ++i) {
            int idx = tid + i * 256;
            int r   = idx & (MT - 1);
            int jg  = idx / MT;
            int j0  = jg * 4;
            int n   = n0 + r;
            int kf  = k0 + j0;
            float4 v = make_float4(0.f, 0.f, 0.f, 0.f);
            if (n < Nv && kf < KFr) {
                int k   = kf >> logF;
                int f   = kf & fmask;
                int src = S[n * SPK + k];
                v = *(const float4*)(x + ((xb + src) << logF) + f);
            }
            Gs[j0 + 0][r] = v.x; Gs[j0 + 1][r] = v.y;
            Gs[j0 + 2][r] = v.z; Gs[j0 + 3][r] = v.w;
        }
        constexpr int WSLOTS = OT * 8;
#pragma unroll
        for (int i = 0; i < (WSLOTS + 255) / 256; ++i) {
            int idx = tid + i * 256;
            if (WSLOTS >= 256 || idx < WSLOTS) {
                int o  = idx & (OT - 1);
                int jg = idx / OT;
                int j0 = jg * 4;
                float4 v = *(const float4*)(W + (size_t)o * KF + k0 + j0);
                Ws[j0 + 0][o] = v.x; Ws[j0 + 1][o] = v.y;
                Ws[j0 + 2][o] = v.z; Ws[j0 + 3][o] = v.w;
            }
        }
        __syncthreads();
#pragma unroll
        for (int kk = 0; kk < 32; ++kk) {
            float4 g = *(const float4*)&Gs[kk][r0];
            float4 w = *(const float4*)&Ws[kk][o0];
            acc[0][0] += g.x * w.x; acc[0][1] += g.x * w.y; acc[0][2] += g.x * w.z; acc[0][3] += g.x * w.w;
            acc[1][0] += g.y * w.x; acc[1][1] += g.y * w.y; acc[1][2] += g.y * w.z; acc[1][3] += g.y * w.w;
            acc[2][0] += g.z * w.x; acc[2][1] += g.z * w.y; acc[2][2] += g.z * w.z; acc[2][3] += g.z * w.w;
            acc[3][0] += g.w * w.x; acc[3][1] += g.w * w.y; acc[3][2] += g.w * w.z; acc[3][3] += g.w * w.w;
        }
        __syncthreads();
    }

    float4 bv = *(const float4*)(bias + o0);
#pragma unroll
    for (int i = 0; i < 4; ++i) {
        int n = n0 + r0 + i;
        if (n >= Nv) continue;
        float v0 = acc[i][0] + bv.x;
        float v1 = acc[i][1] + bv.y;
        float v2 = acc[i][2] + bv.z;
        float v3 = acc[i][3] + bv.w;
        if (elu_flag) {
            v0 = v0 > 0.f ? v0 : expm1f(v0);
            v1 = v1 > 0.f ? v1 : expm1f(v1);
            v2 = v2 > 0.f ? v2 : expm1f(v2);
            v3 = v3 > 0.f ? v3 : expm1f(v3);
        }
        if (n == Nv - 1) { v0 = v1 = v2 = v3 = 0.f; }
        *(float4*)(y + ((size_t)b * Nv + n) * O + o0) = make_float4(v0, v1, v2, v3);
    }
}

// ---------------------------------------------------------------------------
// conv_gemm_bf16: same structure, x is bf16 (halves random-gather bytes).
// ---------------------------------------------------------------------------
template<int MT, int OT>
__global__ __launch_bounds__(256) void conv_gemm_bf16_kernel(
    const unsigned short* __restrict__ x, const int* __restrict__ S,
    const float* __restrict__ W, const float* __restrict__ bias,
    float* __restrict__ y, int Nv, int logF, int O, int KF, int elu_flag)
{
    constexpr int CT = OT / 4;
    constexpr int RT = 256 / CT;
    static_assert(RT * 4 == MT, "tile shape");
    __shared__ float Gs[32][MT];
    __shared__ float Ws[32][OT];

    const int b   = blockIdx.x;
    const int n0  = blockIdx.y * MT;
    const int tid = threadIdx.x;
    const int cx  = tid % CT;
    const int ry  = tid / CT;
    const int r0  = ry * 4;
    const int o0  = cx * 4;
    const int fmask = (1 << logF) - 1;
    const size_t xb = (size_t)b * Nv;

    float acc[4][4];
#pragma unroll
    for (int i = 0; i < 4; ++i)
#pragma unroll
        for (int j = 0; j < 4; ++j) acc[i][j] = 0.f;

    for (int k0 = 0; k0 < KF; k0 += 32) {
        constexpr int GSLOTS = MT * 8;
#pragma unroll
        for (int i = 0; i < GSLOTS / 256; ++i) {
            int idx = tid + i * 256;
            int r   = idx & (MT - 1);
            int jg  = idx / MT;
            int j0  = jg * 4;
            int n   = n0 + r;
            float v0 = 0.f, v1 = 0.f, v2 = 0.f, v3 = 0.f;
            if (n < Nv) {
                int kf  = k0 + j0;
                int k   = kf >> logF;
                int f   = kf & fmask;
                int src = S[n * SPK + k];
                bf16x4 t = *(const bf16x4*)(x + ((xb + src) << logF) + f);
                v0 = bf2f((unsigned short)t[0]);
                v1 = bf2f((unsigned short)t[1]);
                v2 = bf2f((unsigned short)t[2]);
                v3 = bf2f((unsigned short)t[3]);
            }
            Gs[j0 + 0][r] = v0; Gs[j0 + 1][r] = v1;
            Gs[j0 + 2][r] = v2; Gs[j0 + 3][r] = v3;
        }
        constexpr int WSLOTS = OT * 8;
#pragma unroll
        for (int i = 0; i < (WSLOTS + 255) / 256; ++i) {
            int idx = tid + i * 256;
            if (WSLOTS >= 256 || idx < WSLOTS) {
                int o  = idx & (OT - 1);
                int jg = idx / OT;
                int j0 = jg * 4;
                float4 v = *(const float4*)(W + (size_t)o * KF + k0 + j0);
                Ws[j0 + 0][o] = v.x; Ws[j0 + 1][o] = v.y;
                Ws[j0 + 2][o] = v.z; Ws[j0 + 3][o] = v.w;
            }
        }
        __syncthreads();
#pragma unroll
        for (int kk = 0; kk < 32; ++kk) {
            float4 g = *(const float4*)&Gs[kk][r0];
            float4 w = *(const float4*)&Ws[kk][o0];
            acc[0][0] += g.x * w.x; acc[0][1] += g.x * w.y; acc[0][2] += g.x * w.z; acc[0][3] += g.x * w.w;
            acc[1][0] += g.y * w.x; acc[1][1] += g.y * w.y; acc[1][2] += g.y * w.z; acc[1][3] += g.y * w.w;
            acc[2][0] += g.z * w.x; acc[2][1] += g.z * w.y; acc[2][2] += g.z * w.z; acc[2][3] += g.z * w.w;
            acc[3][0] += g.w * w.x; acc[3][1] += g.w * w.y; acc[3][2] += g.w * w.z; acc[3][3] += g.w * w.w;
        }
        __syncthreads();
    }

    float4 bv = *(const float4*)(bias + o0);
#pragma unroll
    for (int i = 0; i < 4; ++i) {
        int n = n0 + r0 + i;
        if (n >= Nv) continue;
        float v0 = acc[i][0] + bv.x;
        float v1 = acc[i][1] + bv.y;
        float v2 = acc[i][2] + bv.z;
        float v3 = acc[i][3] + bv.w;
        if (elu_flag) {
            v0 = v0 > 0.f ? v0 : expm1f(v0);
            v1 = v1 > 0.f ? v1 : expm1f(v1);
            v2 = v2 > 0.f ? v2 : expm1f(v2);
            v3 = v3 > 0.f ? v3 : expm1f(v3);
        }
        if (n == Nv - 1) { v0 = v1 = v2 = v3 = 0.f; }
        *(float4*)(y + ((size_t)b * Nv + n) * O + o0) = make_float4(v0, v1, v2, v3);
    }
}

// ---------------------------------------------------------------------------
// VALU down/up-sample (tiny levels 2-3 only).
// ---------------------------------------------------------------------------
__global__ __launch_bounds__(256) void dsamp_kernel(
    const float* __restrict__ A, const float* __restrict__ X,
    float* __restrict__ Y, int M, int N, int F)
{
    __shared__ float As[16][68];
    __shared__ float Xs[16][64];

    const int m0  = blockIdx.x * 64;
    const int c0  = blockIdx.y * 64;
    const int tid = threadIdx.x;
    const int tx  = tid & 15;
    const int ty  = tid >> 4;

    float acc[4][4];
#pragma unroll
    for (int i = 0; i < 4; ++i)
#pragma unroll
        for (int j = 0; j < 4; ++j) acc[i][j] = 0.f;

    for (int k0 = 0; k0 < N; k0 += 16) {
#pragma unroll
        for (int p = 0; p < 4; ++p) {
            int r  = (tid >> 4) + p * 16;
            int kk = tid & 15;
            int m  = m0 + r;
            int n  = k0 + kk;
            float v = 0.f;
            if (m < M && n < N) v = A[(size_t)m * N + n];
            As[kk][r] = v;
        }
        {
            int kk = tid >> 4;
            int cc = (tid & 15) * 4;
            int n  = k0 + kk;
            float4 v = make_float4(0.f, 0.f, 0.f, 0.f);
            if (n < N) {
                int c  = c0 + cc;
                int bb = c / F;
                int f  = c - bb * F;
                v = *(const float4*)(X + ((size_t)bb * N + n) * F + f);
            }
            *(float4*)&Xs[kk][cc] = v;
        }
        __syncthreads();
#pragma unroll
        for (int kk = 0; kk < 16; ++kk) {
            float4 av = *(const float4*)&As[kk][ty * 4];
            float4 xv = *(const float4*)&Xs[kk][tx * 4];
            acc[0][0] += av.x * xv.x; acc[0][1] += av.x * xv.y; acc[0][2] += av.x * xv.z; acc[0][3] += av.x * xv.w;
            acc[1][0] += av.y * xv.x; acc[1][1] += av.y * xv.y; acc[1][2] += av.y * xv.z; acc[1][3] += av.y * xv.w;
            acc[2][0] += av.z * xv.x; acc[2][1] += av.z * xv.y; acc[2][2] += av.z * xv.z; acc[2][3] += av.z * xv.w;
            acc[3][0] += av.w * xv.x; acc[3][1] += av.w * xv.y; acc[3][2] += av.w * xv.z; acc[3][3] += av.w * xv.w;
        }
        __syncthreads();
    }

    const int cbase = c0 + tx * 4;
    const int bb = cbase / F;
    const int f  = cbase - bb * F;
#pragma unroll
    for (int i = 0; i < 4; ++i) {
        int m = m0 + ty * 4 + i;
        if (m < M) {
            float4 v = make_float4(acc[i][0], acc[i][1], acc[i][2], acc[i][3]);
            *(float4*)(Y + ((size_t)bb * M + m) * F + f) = v;
        }
    }
}

// ---------------------------------------------------------------------------
// fc_wave: one 64-lane wave per output element (round-6, proven).
// ---------------------------------------------------------------------------
__global__ __launch_bounds__(256) void fc_wave_kernel(
    const float* __restrict__ in, const float* __restrict__ W,
    const float* __restrict__ bias, float* __restrict__ out,
    int In, int O, int dup)
{
    const int gw   = blockIdx.x * 4 + (threadIdx.x >> 6);
    const int lane = threadIdx.x & 63;
    const int b = gw / O;
    const int o = gw - b * O;
    const float* xr = in + (size_t)b * In;
    float acc = 0.f;
    if (dup) {
        const float* wr = W + (size_t)o * (2 * In);
        for (int k = lane; k < In; k += 64)
            acc += xr[k] * (wr[k] + wr[In + k]);
    } else {
        const float* wr = W + (size_t)o * In;
        for (int k = lane; k < In; k += 64)
            acc += xr[k] * wr[k];
    }
#pragma unroll
    for (int off = 32; off > 0; off >>= 1)
        acc += __shfl_down(acc, off, 64);
    if (lane == 0) out[(size_t)b * O + o] = acc + bias[o];
}

// ---------------------------------------------------------------------------
// Padding / extraction helpers.
// ---------------------------------------------------------------------------
__global__ __launch_bounds__(256) void pad_e0_w_kernel(
    const float* __restrict__ w, float* __restrict__ wp)
{
    int i = blockIdx.x * 256 + threadIdx.x;
    if (i < 1024) {
        int o = i >> 6, kf = i & 63;
        int k = kf >> 2, f = kf & 3;
        wp[i] = (f < 3 && k < 12) ? w[o * 36 + k * 3 + f] : 0.f;
    }
}
__global__ __launch_bounds__(256) void pad_x4_kernel(
    const float* __restrict__ x, float* __restrict__ xp, int n)
{
    int i = blockIdx.x * 256 + threadIdx.x;
    if (i < n) {
        int f = i & 3, nb = i >> 2;
        xp[i] = (f < 3) ? x[nb * 3 + f] : 0.f;
    }
}
__global__ __launch_bounds__(256) void pad_c4_w_kernel(
    const float* __restrict__ w, const float* __restrict__ b,
    float* __restrict__ wp, float* __restrict__ bp)
{
    int i = blockIdx.x * 256 + threadIdx.x;
    if (i < 3072) {
        int o = i / 192;
        wp[i] = (o < 3) ? w[i] : 0.f;
    }
    if (i < 16) bp[i] = (i < 3) ? b[i] : 0.f;
}
__global__ __launch_bounds__(256) void extract_add_kernel(
    const float* __restrict__ cp, const float* __restrict__ t,
    float* __restrict__ o0, float* __restrict__ o1, int n)
{
    int i = blockIdx.x * 256 + threadIdx.x;
    if (i < n) {
        int f = i % 3, nb = i / 3;
        float v = cp[(size_t)nb * 16 + f];
        o0[i] = v;
        o1[i] = v + t[i];
    }
}

// ---------------------------------------------------------------------------

static inline int ilog2(int v) { int l = 0; while ((1 << l) < v) ++l; return l; }

static inline void conv_launch(const float* x, const int* S, const float* W,
                               const float* b, float* y, int Nv, int F, int O,
                               int elu, hipStream_t s)
{
    int KF = SPK * F;
    int logF = ilog2(F);
    if (O == 16) {
        dim3 grid(BATCH, (Nv + 255) / 256);
        conv_gemm_kernel<256, 16><<<grid, 256, 0, s>>>(x, S, W, b, y, Nv, logF, O, KF, KF, elu);
    } else if (O == 32) {
        dim3 grid(BATCH, (Nv + 127) / 128);
        conv_gemm_kernel<128, 32><<<grid, 256, 0, s>>>(x, S, W, b, y, Nv, logF, O, KF, KF, elu);
    } else if (O == 64) {
        dim3 grid(BATCH, (Nv + 63) / 64);
        conv_gemm_kernel<64, 64><<<grid, 256, 0, s>>>(x, S, W, b, y, Nv, logF, O, KF, KF, elu);
    } else {
        dim3 grid(BATCH, (Nv + 31) / 32);
        conv_gemm_kernel<32, 128><<<grid, 256, 0, s>>>(x, S, W, b, y, Nv, logF, O, KF, KF, elu);
    }
}

static inline void dsamp_mfma2_launch(const float* A, const float* X, float* Y,
                                      int M, int K, int F, int ks, hipStream_t s)
{
    int kchunk = (K + ks - 1) / ks;
    kchunk = (kchunk + 31) & ~31;
    int ksz = (K + kchunk - 1) / kchunk;
    dim3 grid((M + 63) / 64, F, ksz);
    dsamp_mfma2_kernel<<<grid, 256, 0, s>>>(A, X, Y, M, K, ilog2(F), kchunk, ksz > 1 ? 1 : 0);
}

static inline void dsamp_mfma3_launch(const float* A, const unsigned short* Xt,
                                      float* Y, int M, int K, int Kp, int F,
                                      int ks, hipStream_t s)
{
    int slabs = Kp >> 5;
    int kchunk = ((slabs + ks - 1) / ks) * 32;
    int ksz = (Kp + kchunk - 1) / kchunk;
    dim3 grid((M + 127) / 128, (BATCH * F) / 128, ksz);
    dsamp_mfma3_kernel<<<grid, 256, 0, s>>>(A, Xt, Y, M, K, Kp, ilog2(F), kchunk,
                                            ksz > 1 ? 1 : 0);
}

static inline void dsamp_launch(const float* A, const float* X, float* Y,
                                int M, int N, int F, hipStream_t s)
{
    dim3 grid((M + 63) / 64, F);
    dsamp_kernel<<<grid, 256, 0, s>>>(A, X, Y, M, N, F);
}

extern "C" void kernel_launch(void* const* d_in, const int* in_sizes, int n_in,
                              void* d_out, int out_size, void* d_ws, size_t ws_size,
                              hipStream_t stream)
{
    const float* x_talking = (const float*)d_in[0];
    const float* templ     = (const float*)d_in[1];
    const float* D0 = (const float*)d_in[2];
    const float* U0 = (const float*)d_in[3];
    const float* D1 = (const float*)d_in[4];
    const float* U1 = (const float*)d_in[5];
    const float* D2 = (const float*)d_in[6];
    const float* U2 = (const float*)d_in[7];
    const float* D3 = (const float*)d_in[8];
    const float* U3 = (const float*)d_in[9];
    const float* enc_w0 = (const float*)d_in[10]; const float* enc_b0 = (const float*)d_in[11];
    const float* enc_w1 = (const float*)d_in[12]; const float* enc_b1 = (const float*)d_in[13];
    const float* enc_w2 = (const float*)d_in[14]; const float* enc_b2 = (const float*)d_in[15];
    const float* enc_w3 = (const float*)d_in[16]; const float* enc_b3 = (const float*)d_in[17];
    const float* fc_enc_w = (const float*)d_in[18]; const float* fc_enc_b = (const float*)d_in[19];
    const float* fc_dec_w = (const float*)d_in[20]; const float* fc_dec_b = (const float*)d_in[21];
    const float* dec_w0 = (const float*)d_in[22]; const float* dec_b0 = (const float*)d_in[23];
    const float* dec_w1 = (const float*)d_in[24]; const float* dec_b1 = (const float*)d_in[25];
    const float* dec_w2 = (const float*)d_in[26]; const float* dec_b2 = (const float*)d_in[27];
    const float* dec_w3 = (const float*)d_in[28]; const float* dec_b3 = (const float*)d_in[29];
    const float* dec_w4 = (const float*)d_in[30]; const float* dec_b4 = (const float*)d_in[31];
    const int* S0 = (const int*)d_in[32];
    const int* S1 = (const int*)d_in[33];
    const int* S2 = (const int*)d_in[34];
    const int* S3 = (const int*)d_in[35];

    float* bufA = (float*)d_ws;            // 10,289,152 floats (41.2 MB)
    float* bufB = bufA + 10289152;         // 5,144,576 floats (20.6 MB)

    float* out0 = (float*)d_out;           // 964,608 floats
    float* out1 = out0 + 964608;

    // Workspace aliases (lifetimes audited):
    unsigned short* Xt_e0 = (unsigned short*)(bufB + 1290240);  // d0-phase B operand
    unsigned short* Xt_c2 = (unsigned short*)(bufB + 2574336);  // u0-phase B operand
    float* xpad   = bufA + 5200000;   // e0 input padded to F=4 (encoder phase)
    float* WpE0   = bufA + 6600000;   // e0 W padded [16][64]   (encoder phase)
    unsigned short* Xb_c3 = (unsigned short*)bufB;          // c3 bf16 input [64,5024,32] (all of bufB; c2-out/Xt_c2 dead)
    unsigned short* Xb_c4 = (unsigned short*)(bufA + 5200000); // c4 bf16 input [64,5024,16] (u0 fp32 dead)
    float* WpC4   = bufA + 8000000;   // c4 W padded [16][192]
    float* BpC4   = bufA + 8003072;   // c4 bias padded [16]

    size_t arena_bytes = (size_t)(10289152 + 5144576) * sizeof(float);
    if (arena_bytes > ws_size) arena_bytes = ws_size;
    hipMemsetAsync(d_ws, 0, arena_bytes, stream);

    // ---- encoder ----
    pad_e0_w_kernel<<<4, 256, 0, stream>>>(enc_w0, WpE0);
    pad_x4_kernel<<<5024, 256, 0, stream>>>(x_talking, xpad, 1286144);
    {   // e0: F=4(pad), KF=64 (KFr=48), O=16
        dim3 grid(BATCH, (5024 + 255) / 256);
        conv_gemm_kernel<256, 16><<<grid, 256, 0, stream>>>(
            xpad, S0, WpE0, enc_b0, bufA, 5024, 2, 16, 64, 48, 1);
    }
    xpose_bf16_kernel<<<dim3(628, 4), 256, 0, stream>>>(bufA, Xt_e0, 5024, 5024, 4);
    dsamp_mfma3_launch(D0, Xt_e0, bufB, 1257, 5024, 5024, 16, 8, stream);       // d0 [atomic ks=8]
    conv_launch(bufB, S1, enc_w1, enc_b1, bufA, 1257, 16, 32, 1, stream);       // e1
    hipMemsetAsync(bufB, 0, (size_t)645120 * sizeof(float), stream);            // zero d1 target
    dsamp_mfma2_launch(D1, bufA, bufB, 315, 1257, 32, 8, stream);               // d1 [atomic ks=8]
    conv_launch(bufB, S2, enc_w2, enc_b2, bufA, 315, 32, 64, 1, stream);        // e2
    dsamp_launch(D2, bufA, bufB, 80, 315, 64, stream);                          // d2
    conv_launch(bufB, S3, enc_w3, enc_b3, bufA, 80, 64, 128, 1, stream);        // e3
    dsamp_launch(D3, bufA, bufB, 21, 80, 128, stream);                          // d3

    fc_wave_kernel<<<dim3((BATCH * 128) / 4), 256, 0, stream>>>(bufB, fc_enc_w, fc_enc_b, bufA, 2688, 128, 0);
    fc_wave_kernel<<<dim3((BATCH * 2688) / 4), 256, 0, stream>>>(bufA, fc_dec_w, fc_dec_b, bufB, 128, 2688, 1);

    // ---- decoder ----
    dsamp_launch(U3, bufB, bufA, 80, 21, 128, stream);                          // u3
    conv_launch(bufA, S3, dec_w0, dec_b0, bufB, 80, 128, 64, 1, stream);        // c0
    dsamp_launch(U2, bufB, bufA, 315, 80, 64, stream);                          // u2
    conv_launch(bufA, S2, dec_w1, dec_b1, bufB, 315, 64, 32, 1, stream);        // c1
    dsamp_mfma2_launch(U1, bufB, bufA, 1257, 315, 32, 1, stream);               // u1 (plain)
    conv_launch(bufA, S1, dec_w2, dec_b2, bufB, 1257, 32, 32, 1, stream);       // c2
    xpose_bf16_kernel<<<dim3(160, 8), 256, 0, stream>>>(bufB, Xt_c2, 1257, 1280, 5);
    hipMemsetAsync(bufA, 0, (size_t)10289152 * sizeof(float), stream);          // zero u0 target
    dsamp_mfma3_launch(U0, Xt_c2, bufA, 5024, 1257, 1280, 32, 2, stream);       // u0 [atomic ks=2]

    // u0-out (bufA, fp32 [64,5024,32]) -> bf16 (all of bufB; c2-out/Xt_c2 dead)
    f32_to_bf16_kernel<<<5024, 256, 0, stream>>>(bufA, Xb_c3, 1286144);
    {   // c3: bf16 gather, F=32, O=16 -> bufA[0..5.14M)
        dim3 grid(BATCH, (5024 + 255) / 256);
        conv_gemm_bf16_kernel<256, 16><<<grid, 256, 0, stream>>>(
            Xb_c3, S0, dec_w3, dec_b3, bufA, 5024, 5, 16, 384, 1);
    }
    // c3-out (bufA[0..5.14M) fp32) -> bf16 at bufA+5.2M
    f32_to_bf16_kernel<<<2512, 256, 0, stream>>>(bufA, Xb_c4, 643072);
    pad_c4_w_kernel<<<12, 256, 0, stream>>>(dec_w4, dec_b4, WpC4, BpC4);
    {   // c4: bf16 gather, F=16, O=16(pad), identity -> c4pad in bufB
        dim3 grid(BATCH, (5024 + 255) / 256);
        conv_gemm_bf16_kernel<256, 16><<<grid, 256, 0, stream>>>(
            Xb_c4, S0, WpC4, BpC4, bufB, 5024, 4, 16, 192, 0);
    }
    extract_add_kernel<<<(964608 + 255) / 256, 256, 0, stream>>>(bufB, templ, out0, out1, 964608);
}

// Round 9
// 1031.563 us; speedup vs baseline: 4.4455x; 1.0753x over previous
//
#include <hip/hip_runtime.h>
#include <cstddef>

// ---------------------------------------------------------------------------
// SpiralAutoencoder on MI355X — round 9:
//  * c3/c4 -> conv_mfma16: MFMA conv (bf16 G in LDS, W as B-frag from global,
//    register-prefetch dbuf, 1 barrier/slab). Was VALU conv: LDS-throughput
//    bound (32 LDS B / 32 FLOP), c3==c4==132us regardless of K.
//  * c3 writes bf16 directly into c4's gather buffer (drops a convert pass).
// ---------------------------------------------------------------------------

#define BATCH 64
#define SPK 12  // spiral length

typedef __attribute__((ext_vector_type(8))) short bf16x8;
typedef __attribute__((ext_vector_type(4))) short bf16x4;
typedef __attribute__((ext_vector_type(4))) float f32x4;

__device__ __forceinline__ unsigned short f2bf(float x) {
    union { float f; unsigned int u; } v; v.f = x;
    unsigned int r = v.u + 0x7FFF + ((v.u >> 16) & 1);  // RNE
    return (unsigned short)(r >> 16);
}
__device__ __forceinline__ float bf2f(unsigned short u) {
    union { unsigned int i; float f; } v; v.i = ((unsigned int)u) << 16;
    return v.f;
}

__device__ __forceinline__ bf16x8 pack8(const float* v) {
    bf16x8 r;
#pragma unroll
    for (int j = 0; j < 8; ++j) r[j] = (short)f2bf(v[j]);
    return r;
}

// ---------------------------------------------------------------------------
// Flat fp32 -> bf16 convert (8 elems/thread).
// ---------------------------------------------------------------------------
__global__ __launch_bounds__(256) void f32_to_bf16_kernel(
    const float* __restrict__ in, unsigned short* __restrict__ out, int n8)
{
    int i = blockIdx.x * 256 + threadIdx.x;
    if (i < n8) {
        const float* p = in + (size_t)i * 8;
        bf16x8 r;
#pragma unroll
        for (int j = 0; j < 8; ++j) r[j] = (short)f2bf(p[j]);
        *(bf16x8*)(out + (size_t)i * 8) = r;
    }
}

// ---------------------------------------------------------------------------
// conv_mfma16: O=16 spiral conv via MFMA. x bf16, G gathered to LDS (bf16),
// W fp32 [16][KF] consumed as B-frag from global (L1). Grid (batch, mtile256).
// ---------------------------------------------------------------------------
template<int LOGF, int OBF16>
__global__ __launch_bounds__(256) void conv_mfma16_kernel(
    const unsigned short* __restrict__ x, const int* __restrict__ S,
    const float* __restrict__ W, const float* __restrict__ bias,
    void* __restrict__ yv, int Nv, int KF, int elu_flag)
{
    constexpr int PAD = 40;
    __shared__ unsigned short Gs[2][256 * PAD];

    const int b    = blockIdx.x;
    const int n0   = blockIdx.y * 256;
    const int tid  = threadIdx.x;
    const int lane = tid & 63;
    const int wave = tid >> 6;
    const int wm   = wave * 64;
    const int l15  = lane & 15;
    const int quad = lane >> 4;
    const size_t xb = (size_t)b * Nv;
    const int nslab = KF >> 5;

    f32x4 acc[4];
#pragma unroll
    for (int t = 0; t < 4; ++t) acc[t] = (f32x4){0.f, 0.f, 0.f, 0.f};

    auto gath = [&](int k0, bf16x8* g) {
        int n = n0 + tid;
        if (n < Nv) {
#pragma unroll
            for (int j = 0; j < 4; ++j) {
                int kf  = k0 + j * 8;
                int k   = kf >> LOGF;
                int f   = kf & ((1 << LOGF) - 1);
                int src = S[n * SPK + k];
                g[j] = *(const bf16x8*)(x + ((xb + src) << LOGF) + f);
            }
        } else {
#pragma unroll
            for (int j = 0; j < 4; ++j)
#pragma unroll
                for (int e = 0; e < 8; ++e) g[j][e] = 0;
        }
    };
    auto put = [&](int buf, const bf16x8* g) {
#pragma unroll
        for (int j = 0; j < 4; ++j)
            *(bf16x8*)&Gs[buf][tid * PAD + j * 8] = g[j];
    };
    auto wfrag = [&](int k0) {
        const float* wp = W + l15 * KF + k0 + quad * 8;
        float4 wa = *(const float4*)wp;
        float4 wb = *(const float4*)(wp + 4);
        bf16x8 r;
        r[0] = (short)f2bf(wa.x); r[1] = (short)f2bf(wa.y);
        r[2] = (short)f2bf(wa.z); r[3] = (short)f2bf(wa.w);
        r[4] = (short)f2bf(wb.x); r[5] = (short)f2bf(wb.y);
        r[6] = (short)f2bf(wb.z); r[7] = (short)f2bf(wb.w);
        return r;
    };

    bf16x8 gcur[4], gnext[4];
    gath(0, gcur);
    put(0, gcur);
    __syncthreads();

    for (int s = 0; s < nslab; ++s) {
        const int cur = s & 1;
        const bool more = (s + 1) < nslab;
        if (more) gath((s + 1) * 32, gnext);
        bf16x8 wf = wfrag(s * 32);
#pragma unroll
        for (int t = 0; t < 4; ++t) {
            bf16x8 a = *(const bf16x8*)&Gs[cur][(wm + t * 16 + l15) * PAD + quad * 8];
            acc[t] = __builtin_amdgcn_mfma_f32_16x16x32_bf16(a, wf, acc[t], 0, 0, 0);
        }
        if (more) {
            put(cur ^ 1, gnext);
            __syncthreads();
        }
    }

    // epilogue: C/D layout col(o)=lane&15, row=quad*4+reg within 16-row frag
    float bv = bias[l15];
#pragma unroll
    for (int t = 0; t < 4; ++t)
#pragma unroll
        for (int reg = 0; reg < 4; ++reg) {
            int n = n0 + wm + t * 16 + quad * 4 + reg;
            if (n >= Nv) continue;
            float v = acc[t][reg] + bv;
            if (elu_flag && v <= 0.f) v = expm1f(v);
            if (n == Nv - 1) v = 0.f;
            size_t off = ((size_t)b * Nv + n) * 16 + l15;
            if (OBF16) ((unsigned short*)yv)[off] = f2bf(v);
            else       ((float*)yv)[off] = v;
        }
}

// ---------------------------------------------------------------------------
// dsamp_mfma3: 128x128 tile MFMA resample (round-5, proven). D0/U0.
// ---------------------------------------------------------------------------
__global__ __launch_bounds__(256) void dsamp_mfma3_kernel(
    const float* __restrict__ A, const unsigned short* __restrict__ Xt,
    float* __restrict__ Y, int M, int K, int Kp, int logF, int kchunk,
    int atomic_flag)
{
    constexpr int PAD = 40;
    __shared__ unsigned short As[2][128 * PAD];
    __shared__ unsigned short Bs[2][128 * PAD];

    const int fmask = (1 << logF) - 1;
    const int m0   = blockIdx.x * 128;
    const int c0   = blockIdx.y * 128;
    const int kbeg = blockIdx.z * kchunk;
    int kend = kbeg + kchunk; if (kend > Kp) kend = Kp;
    const int nslab = (kend - kbeg + 31) >> 5;

    const int tid  = threadIdx.x;
    const int lane = tid & 63;
    const int wave = tid >> 6;
    const int wm   = (wave >> 1) * 64;
    const int wn   = (wave & 1) * 64;
    const int l15  = lane & 15;
    const int quad = lane >> 4;

    const int ar_row = tid >> 3;
    const int ar_k4  = (tid & 7) * 4;
    const int br_row = tid >> 2;
    const int br_k8  = (tid & 3) * 8;

    f32x4 acc[4][4];
#pragma unroll
    for (int i = 0; i < 4; ++i)
#pragma unroll
        for (int j = 0; j < 4; ++j) acc[i][j] = (f32x4){0.f, 0.f, 0.f, 0.f};

    float4 apre[4];
    bf16x8 bpre[2];

    auto loadAB = [&](int ko) {
#pragma unroll
        for (int i = 0; i < 4; ++i) {
            int m = m0 + ar_row + i * 32;
            int k = ko + ar_k4;
            float4 v = make_float4(0.f, 0.f, 0.f, 0.f);
            if (m < M) {
                const float* ap = A + (size_t)m * K;
                if (k + 3 < K) v = *(const float4*)(ap + k);
                else {
                    v.x = (k     < K) ? ap[k]     : 0.f;
                    v.y = (k + 1 < K) ? ap[k + 1] : 0.f;
                    v.z = (k + 2 < K) ? ap[k + 2] : 0.f;
                    v.w = (k + 3 < K) ? ap[k + 3] : 0.f;
                }
            }
            apre[i] = v;
        }
#pragma unroll
        for (int i = 0; i < 2; ++i)
            bpre[i] = *(const bf16x8*)(Xt + (size_t)(c0 + br_row + i * 64) * Kp + ko + br_k8);
    };
    auto stage = [&](int buf) {
#pragma unroll
        for (int i = 0; i < 4; ++i) {
            bf16x4 t;
            t[0] = (short)f2bf(apre[i].x);
            t[1] = (short)f2bf(apre[i].y);
            t[2] = (short)f2bf(apre[i].z);
            t[3] = (short)f2bf(apre[i].w);
            *(bf16x4*)&As[buf][(ar_row + i * 32) * PAD + ar_k4] = t;
        }
#pragma unroll
        for (int i = 0; i < 2; ++i)
            *(bf16x8*)&Bs[buf][(br_row + i * 64) * PAD + br_k8] = bpre[i];
    };

    loadAB(kbeg);
    stage(0);
    __syncthreads();

    for (int s = 0; s < nslab; ++s) {
        const int cur = s & 1;
        const bool more = (s + 1) < nslab;
        if (more) loadAB(kbeg + (s + 1) * 32);

        bf16x8 af[4], bfr[4];
#pragma unroll
        for (int t = 0; t < 4; ++t) {
            af[t]  = *(const bf16x8*)&As[cur][(wm + t * 16 + l15) * PAD + quad * 8];
            bfr[t] = *(const bf16x8*)&Bs[cur][(wn + t * 16 + l15) * PAD + quad * 8];
        }
#pragma unroll
        for (int tm = 0; tm < 4; ++tm)
#pragma unroll
            for (int tn = 0; tn < 4; ++tn)
                acc[tm][tn] = __builtin_amdgcn_mfma_f32_16x16x32_bf16(af[tm], bfr[tn], acc[tm][tn], 0, 0, 0);

        if (more) { stage(cur ^ 1); __syncthreads(); }
    }

#pragma unroll
    for (int tm = 0; tm < 4; ++tm)
#pragma unroll
        for (int tn = 0; tn < 4; ++tn)
#pragma unroll
            for (int reg = 0; reg < 4; ++reg) {
                int m  = m0 + wm + tm * 16 + quad * 4 + reg;
                int cc = c0 + wn + tn * 16 + l15;
                if (m < M) {
                    int bb = cc >> logF, f = cc & fmask;
                    float* dst = Y + (((size_t)bb * M + m) << logF) + f;
                    if (atomic_flag) atomicAdd(dst, acc[tm][tn][reg]);
                    else *dst = acc[tm][tn][reg];
                }
            }
}

// ---------------------------------------------------------------------------
// dsamp_mfma2 (round-4, proven): D1/U1.
// ---------------------------------------------------------------------------
__global__ __launch_bounds__(256) void dsamp_mfma2_kernel(
    const float* __restrict__ A, const float* __restrict__ X,
    float* __restrict__ Y, int M, int K, int logF, int kchunk, int atomic_flag)
{
    constexpr int PAD = 40;
    __shared__ unsigned short Xs[2][64 * PAD];

    const int fmask = (1 << logF) - 1;
    const int m0   = blockIdx.x * 64;
    const int c0   = blockIdx.y * 64;
    const int kbeg = blockIdx.z * kchunk;
    int kend = kbeg + kchunk; if (kend > K) kend = K;
    const int nslab = (kend - kbeg + 31) >> 5;

    const int tid  = threadIdx.x;
    const int lane = tid & 63;
    const int wave = tid >> 6;
    const int wm   = (wave >> 1) * 32;
    const int wn   = (wave & 1) * 32;
    const int l15  = lane & 15;
    const int quad = lane >> 4;

    const int skk  = tid >> 4;
    const int scg  = (tid & 15) * 4;
    const int cB   = c0 + scg;
    const int xbb  = cB >> logF;
    const int xf   = cB & fmask;
    const size_t xrowbase = (((size_t)xbb * K) << logF) + xf;

    const int mA0 = m0 + wm + l15;
    const int mA1 = mA0 + 16;
    const int kaoff = quad * 8;

    f32x4 acc[2][2];
    acc[0][0] = acc[0][1] = acc[1][0] = acc[1][1] = (f32x4){0.f, 0.f, 0.f, 0.f};

    float4 xn0, xn1;
    float ac0[8], ac1[8], an0[8], an1[8];

    {
        int k = kbeg + skk;
        xn0 = make_float4(0.f, 0.f, 0.f, 0.f);
        if (k < kend) xn0 = *(const float4*)(X + xrowbase + ((size_t)k << logF));
        k = kbeg + 16 + skk;
        xn1 = make_float4(0.f, 0.f, 0.f, 0.f);
        if (k < kend) xn1 = *(const float4*)(X + xrowbase + ((size_t)k << logF));
        int ka = kbeg + kaoff;
#pragma unroll
        for (int j = 0; j < 8; ++j) {
            ac0[j] = (mA0 < M && ka + j < kend) ? A[(size_t)mA0 * K + ka + j] : 0.f;
            ac1[j] = (mA1 < M && ka + j < kend) ? A[(size_t)mA1 * K + ka + j] : 0.f;
        }
        unsigned short* p = &Xs[0][0];
        p[(scg + 0) * PAD + skk] = f2bf(xn0.x);
        p[(scg + 1) * PAD + skk] = f2bf(xn0.y);
        p[(scg + 2) * PAD + skk] = f2bf(xn0.z);
        p[(scg + 3) * PAD + skk] = f2bf(xn0.w);
        int kk1 = 16 + skk;
        p[(scg + 0) * PAD + kk1] = f2bf(xn1.x);
        p[(scg + 1) * PAD + kk1] = f2bf(xn1.y);
        p[(scg + 2) * PAD + kk1] = f2bf(xn1.z);
        p[(scg + 3) * PAD + kk1] = f2bf(xn1.w);
    }
    __syncthreads();

    for (int s = 0; s < nslab; ++s) {
        const int cur = s & 1;
        const bool more = (s + 1 < nslab);
        if (more) {
            int k0 = kbeg + (s + 1) * 32;
            int k = k0 + skk;
            xn0 = make_float4(0.f, 0.f, 0.f, 0.f);
            if (k < kend) xn0 = *(const float4*)(X + xrowbase + ((size_t)k << logF));
            k = k0 + 16 + skk;
            xn1 = make_float4(0.f, 0.f, 0.f, 0.f);
            if (k < kend) xn1 = *(const float4*)(X + xrowbase + ((size_t)k << logF));
            int ka = k0 + kaoff;
#pragma unroll
            for (int j = 0; j < 8; ++j) {
                an0[j] = (mA0 < M && ka + j < kend) ? A[(size_t)mA0 * K + ka + j] : 0.f;
                an1[j] = (mA1 < M && ka + j < kend) ? A[(size_t)mA1 * K + ka + j] : 0.f;
            }
        }
        {
            const unsigned short* p = &Xs[cur][0];
            bf16x8 b0 = *(const bf16x8*)&p[(wn +      l15) * PAD + quad * 8];
            bf16x8 b1 = *(const bf16x8*)&p[(wn + 16 + l15) * PAD + quad * 8];
            bf16x8 a0 = pack8(ac0);
            bf16x8 a1 = pack8(ac1);
            acc[0][0] = __builtin_amdgcn_mfma_f32_16x16x32_bf16(a0, b0, acc[0][0], 0, 0, 0);
            acc[0][1] = __builtin_amdgcn_mfma_f32_16x16x32_bf16(a0, b1, acc[0][1], 0, 0, 0);
            acc[1][0] = __builtin_amdgcn_mfma_f32_16x16x32_bf16(a1, b0, acc[1][0], 0, 0, 0);
            acc[1][1] = __builtin_amdgcn_mfma_f32_16x16x32_bf16(a1, b1, acc[1][1], 0, 0, 0);
        }
        if (more) {
            unsigned short* q = &Xs[cur ^ 1][0];
            q[(scg + 0) * PAD + skk] = f2bf(xn0.x);
            q[(scg + 1) * PAD + skk] = f2bf(xn0.y);
            q[(scg + 2) * PAD + skk] = f2bf(xn0.z);
            q[(scg + 3) * PAD + skk] = f2bf(xn0.w);
            int kk1 = 16 + skk;
            q[(scg + 0) * PAD + kk1] = f2bf(xn1.x);
            q[(scg + 1) * PAD + kk1] = f2bf(xn1.y);
            q[(scg + 2) * PAD + kk1] = f2bf(xn1.z);
            q[(scg + 3) * PAD + kk1] = f2bf(xn1.w);
            __syncthreads();
#pragma unroll
            for (int j = 0; j < 8; ++j) { ac0[j] = an0[j]; ac1[j] = an1[j]; }
        }
    }

#pragma unroll
    for (int tm = 0; tm < 2; ++tm)
#pragma unroll
        for (int tn = 0; tn < 2; ++tn)
#pragma unroll
            for (int reg = 0; reg < 4; ++reg) {
                int m  = m0 + wm + tm * 16 + quad * 4 + reg;
                int cc = c0 + wn + tn * 16 + l15;
                if (m < M) {
                    int bb = cc >> logF, f = cc & fmask;
                    float* dst = Y + (((size_t)bb * M + m) << logF) + f;
                    if (atomic_flag) atomicAdd(dst, acc[tm][tn][reg]);
                    else *dst = acc[tm][tn][reg];
                }
            }
}

// ---------------------------------------------------------------------------
// conv_gemm (fp32 gather). Grid: (batch, mtile). e0/e1/e2/e3/c0/c1/c2.
// ---------------------------------------------------------------------------
template<int MT, int OT>
__global__ __launch_bounds__(256) void conv_gemm_kernel(
    const float* __restrict__ x, const int* __restrict__ S,
    const float* __restrict__ W, const float* __restrict__ bias,
    float* __restrict__ y, int Nv, int logF, int O, int KF, int KFr,
    int elu_flag)
{
    constexpr int CT = OT / 4;
    constexpr int RT = 256 / CT;
    static_assert(RT * 4 == MT, "tile shape");
    __shared__ float Gs[32][MT];
    __shared__ float Ws[32][OT];

    const int b   = blockIdx.x;
    const int n0  = blockIdx.y * MT;
    const int tid = threadIdx.x;
    const int cx  = tid % CT;
    const int ry  = tid / CT;
    const int r0  = ry * 4;
    const int o0  = cx * 4;
    const int fmask = (1 << logF) - 1;
    const size_t xb = (size_t)b * Nv;

    float acc[4][4];
#pragma unroll
    for (int i = 0; i < 4; ++i)
#pragma unroll
        for (int j = 0; j < 4; ++j) acc[i][j] = 0.f;

    for (int k0 = 0; k0 < KF; k0 += 32) {
        constexpr int GSLOTS = MT * 8;
#pragma unroll
        for (int i = 0; i < GSLOTS / 256; ++i) {
            int idx = tid + i * 256;
            int r   = idx & (MT - 1);
            int jg  = idx / MT;
            int j0  = jg * 4;
            int n   = n0 + r;
            int kf  = k0 + j0;
            float4 v = make_float4(0.f, 0.f, 0.f, 0.f);
            if (n < Nv && kf < KFr) {
                int k   = kf >> logF;
                int f   = kf & fmask;
                int src = S[n * SPK + k];
                v = *(const float4*)(x + ((xb + src) << logF) + f);
            }
            Gs[j0 + 0][r] = v.x; Gs[j0 + 1][r] = v.y;
            Gs[j0 + 2][r] = v.z; Gs[j0 + 3][r] = v.w;
        }
        constexpr int WSLOTS = OT * 8;
#pragma unroll
        for (int i = 0; i < (WSLOTS + 255) / 256; ++i) {
            int idx = tid + i * 256;
            if (WSLOTS >= 256 || idx < WSLOTS) {
                int o  = idx & (OT - 1);
                int jg = idx / OT;
                int j0 = jg * 4;
                float4 v = *(const float4*)(W + (size_t)o * KF + k0 + j0);
                Ws[j0 + 0][o] = v.x; Ws[j0 + 1][o] = v.y;
                Ws[j0 + 2][o] = v.z; Ws[j0 + 3][o] = v.w;
            }
        }
        __syncthreads();
#pragma unroll
        for (int kk = 0; kk < 32; ++kk) {
            float4 g = *(const float4*)&Gs[kk][r0];
            float4 w = *(const float4*)&Ws[kk][o0];
            acc[0][0] += g.x * w.x; acc[0][1] += g.x * w.y; acc[0][2] += g.x * w.z; acc[0][3] += g.x * w.w;
            acc[1][0] += g.y * w.x; acc[1][1] += g.y * w.y; acc[1][2] += g.y * w.z; acc[1][3] += g.y * w.w;
            acc[2][0] += g.z * w.x; acc[2][1] += g.z * w.y; acc[2][2] += g.z * w.z; acc[2][3] += g.z * w.w;
            acc[3][0] += g.w * w.x; acc[3][1] += g.w * w.y; acc[3][2] += g.w * w.z; acc[3][3] += g.w * w.w;
        }
        __syncthreads();
    }

    float4 bv = *(const float4*)(bias + o0);
#pragma unroll
    for (int i = 0; i < 4; ++i) {
        int n = n0 + r0 + i;
        if (n >= Nv) continue;
        float v0 = acc[i][0] + bv.x;
        float v1 = acc[i][1] + bv.y;
        float v2 = acc[i][2] + bv.z;
        float v3 = acc[i][3] + bv.w;
        if (elu_flag) {
            v0 = v0 > 0.f ? v0 : expm1f(v0);
            v1 = v1 > 0.f ? v1 : expm1f(v1);
            v2 = v2 > 0.f ? v2 : expm1f(v2);
            v3 = v3 > 0.f ? v3 : expm1f(v3);
        }
        if (n == Nv - 1) { v0 = v1 = v2 = v3 = 0.f; }
        *(float4*)(y + ((size_t)b * Nv + n) * O + o0) = make_float4(v0, v1, v2, v3);
    }
}

// ---------------------------------------------------------------------------
// VALU down/up-sample (tiny levels 2-3 only).
// ---------------------------------------------------------------------------
__global__ __launch_bounds__(256) void dsamp_kernel(
    const float* __restrict__ A, const float* __restrict__ X,
    float* __restrict__ Y, int M, int N, int F)
{
    __shared__ float As[16][68];
    __shared__ float Xs[16][64];

    const int m0  = blockIdx.x * 64;
    const int c0  = blockIdx.y * 64;
    const int tid = threadIdx.x;
    const int tx  = tid & 15;
    const int ty  = tid >> 4;

    float acc[4][4];
#pragma unroll
    for (int i = 0; i < 4; ++i)
#pragma unroll
        for (int j = 0; j < 4; ++j) acc[i][j] = 0.f;

    for (int k0 = 0; k0 < N; k0 += 16) {
#pragma unroll
        for (int p = 0; p < 4; ++p) {
            int r  = (tid >> 4) + p * 16;
            int kk = tid & 15;
            int m  = m0 + r;
            int n  = k0 + kk;
            float v = 0.f;
            if (m < M && n < N) v = A[(size_t)m * N + n];
            As[kk][r] = v;
        }
        {
            int kk = tid >> 4;
            int cc = (tid & 15) * 4;
            int n  = k0 + kk;
            float4 v = make_float4(0.f, 0.f, 0.f, 0.f);
            if (n < N) {
                int c  = c0 + cc;
                int bb = c / F;
                int f  = c - bb * F;
                v = *(const float4*)(X + ((size_t)bb * N + n) * F + f);
            }
            *(float4*)&Xs[kk][cc] = v;
        }
        __syncthreads();
#pragma unroll
        for (int kk = 0; kk < 16; ++kk) {
            float4 av = *(const float4*)&As[kk][ty * 4];
            float4 xv = *(const float4*)&Xs[kk][tx * 4];
            acc[0][0] += av.x * xv.x; acc[0][1] += av.x * xv.y; acc[0][2] += av.x * xv.z; acc[0][3] += av.x * xv.w;
            acc[1][0] += av.y * xv.x; acc[1][1] += av.y * xv.y; acc[1][2] += av.y * xv.z; acc[1][3] += av.y * xv.w;
            acc[2][0] += av.z * xv.x; acc[2][1] += av.z * xv.y; acc[2][2] += av.z * xv.z; acc[2][3] += av.z * xv.w;
            acc[3][0] += av.w * xv.x; acc[3][1] += av.w * xv.y; acc[3][2] += av.w * xv.z; acc[3][3] += av.w * xv.w;
        }
        __syncthreads();
    }

    const int cbase = c0 + tx * 4;
    const int bb = cbase / F;
    const int f  = cbase - bb * F;
#pragma unroll
    for (int i = 0; i < 4; ++i) {
        int m = m0 + ty * 4 + i;
        if (m < M) {
            float4 v = make_float4(acc[i][0], acc[i][1], acc[i][2], acc[i][3]);
            *(float4*)(Y + ((size_t)bb * M + m) * F + f) = v;
        }
    }
}

// ---------------------------------------------------------------------------
// fc_wave: one 64-lane wave per output element (round-6, proven).
// ---------------------------------------------------------------------------
__global__ __launch_bounds__(256) void fc_wave_kernel(
    const float* __restrict__ in, const float* __restrict__ W,
    const float* __restrict__ bias, float* __restrict__ out,
    int In, int O, int dup)
{
    const int gw   = blockIdx.x * 4 + (threadIdx.x >> 6);
    const int lane = threadIdx.x & 63;
    const int b = gw / O;
    const int o = gw - b * O;
    const float* xr = in + (size_t)b * In;
    float acc = 0.f;
    if (dup) {
        const float* wr = W + (size_t)o * (2 * In);
        for (int k = lane; k < In; k += 64)
            acc += xr[k] * (wr[k] + wr[In + k]);
    } else {
        const float* wr = W + (size_t)o * In;
        for (int k = lane; k < In; k += 64)
            acc += xr[k] * wr[k];
    }
#pragma unroll
    for (int off = 32; off > 0; off >>= 1)
        acc += __shfl_down(acc, off, 64);
    if (lane == 0) out[(size_t)b * O + o] = acc + bias[o];
}

// ---------------------------------------------------------------------------
// Transpose-convert: x [b][k][f] fp32 -> xt [c][k] bf16, c = b*F+f, stride Kp.
// ---------------------------------------------------------------------------
__global__ __launch_bounds__(256) void xpose_bf16_kernel(
    const float* __restrict__ x, unsigned short* __restrict__ xt,
    int K, int Kp, int logF)
{
    const int c  = blockIdx.y * 256 + threadIdx.x;
    const int k0 = blockIdx.x * 8;
    const int bb = c >> logF;
    const int f  = c & ((1 << logF) - 1);
    const float* src = x + (((size_t)bb * K) << logF) + f;
    bf16x8 r;
#pragma unroll
    for (int j = 0; j < 8; ++j) {
        int k = k0 + j;
        float v = (k < K) ? src[(size_t)k << logF] : 0.f;
        r[j] = (short)f2bf(v);
    }
    *(bf16x8*)(xt + (size_t)c * Kp + k0) = r;
}

// ---------------------------------------------------------------------------
// Padding / extraction helpers.
// ---------------------------------------------------------------------------
__global__ __launch_bounds__(256) void pad_e0_w_kernel(
    const float* __restrict__ w, float* __restrict__ wp)
{
    int i = blockIdx.x * 256 + threadIdx.x;
    if (i < 1024) {
        int o = i >> 6, kf = i & 63;
        int k = kf >> 2, f = kf & 3;
        wp[i] = (f < 3 && k < 12) ? w[o * 36 + k * 3 + f] : 0.f;
    }
}
__global__ __launch_bounds__(256) void pad_x4_kernel(
    const float* __restrict__ x, float* __restrict__ xp, int n)
{
    int i = blockIdx.x * 256 + threadIdx.x;
    if (i < n) {
        int f = i & 3, nb = i >> 2;
        xp[i] = (f < 3) ? x[nb * 3 + f] : 0.f;
    }
}
__global__ __launch_bounds__(256) void pad_c4_w_kernel(
    const float* __restrict__ w, const float* __restrict__ b,
    float* __restrict__ wp, float* __restrict__ bp)
{
    int i = blockIdx.x * 256 + threadIdx.x;
    if (i < 3072) {
        int o = i / 192;
        wp[i] = (o < 3) ? w[i] : 0.f;
    }
    if (i < 16) bp[i] = (i < 3) ? b[i] : 0.f;
}
__global__ __launch_bounds__(256) void extract_add_kernel(
    const float* __restrict__ cp, const float* __restrict__ t,
    float* __restrict__ o0, float* __restrict__ o1, int n)
{
    int i = blockIdx.x * 256 + threadIdx.x;
    if (i < n) {
        int f = i % 3, nb = i / 3;
        float v = cp[(size_t)nb * 16 + f];
        o0[i] = v;
        o1[i] = v + t[i];
    }
}

// ---------------------------------------------------------------------------

static inline int ilog2(int v) { int l = 0; while ((1 << l) < v) ++l; return l; }

static inline void conv_launch(const float* x, const int* S, const float* W,
                               const float* b, float* y, int Nv, int F, int O,
                               int elu, hipStream_t s)
{
    int KF = SPK * F;
    int logF = ilog2(F);
    if (O == 16) {
        dim3 grid(BATCH, (Nv + 255) / 256);
        conv_gemm_kernel<256, 16><<<grid, 256, 0, s>>>(x, S, W, b, y, Nv, logF, O, KF, KF, elu);
    } else if (O == 32) {
        dim3 grid(BATCH, (Nv + 127) / 128);
        conv_gemm_kernel<128, 32><<<grid, 256, 0, s>>>(x, S, W, b, y, Nv, logF, O, KF, KF, elu);
    } else if (O == 64) {
        dim3 grid(BATCH, (Nv + 63) / 64);
        conv_gemm_kernel<64, 64><<<grid, 256, 0, s>>>(x, S, W, b, y, Nv, logF, O, KF, KF, elu);
    } else {
        dim3 grid(BATCH, (Nv + 31) / 32);
        conv_gemm_kernel<32, 128><<<grid, 256, 0, s>>>(x, S, W, b, y, Nv, logF, O, KF, KF, elu);
    }
}

static inline void dsamp_mfma2_launch(const float* A, const float* X, float* Y,
                                      int M, int K, int F, int ks, hipStream_t s)
{
    int kchunk = (K + ks - 1) / ks;
    kchunk = (kchunk + 31) & ~31;
    int ksz = (K + kchunk - 1) / kchunk;
    dim3 grid((M + 63) / 64, F, ksz);
    dsamp_mfma2_kernel<<<grid, 256, 0, s>>>(A, X, Y, M, K, ilog2(F), kchunk, ksz > 1 ? 1 : 0);
}

static inline void dsamp_mfma3_launch(const float* A, const unsigned short* Xt,
                                      float* Y, int M, int K, int Kp, int F,
                                      int ks, hipStream_t s)
{
    int slabs = Kp >> 5;
    int kchunk = ((slabs + ks - 1) / ks) * 32;
    int ksz = (Kp + kchunk - 1) / kchunk;
    dim3 grid((M + 127) / 128, (BATCH * F) / 128, ksz);
    dsamp_mfma3_kernel<<<grid, 256, 0, s>>>(A, Xt, Y, M, K, Kp, ilog2(F), kchunk,
                                            ksz > 1 ? 1 : 0);
}

static inline void dsamp_launch(const float* A, const float* X, float* Y,
                                int M, int N, int F, hipStream_t s)
{
    dim3 grid((M + 63) / 64, F);
    dsamp_kernel<<<grid, 256, 0, s>>>(A, X, Y, M, N, F);
}

extern "C" void kernel_launch(void* const* d_in, const int* in_sizes, int n_in,
                              void* d_out, int out_size, void* d_ws, size_t ws_size,
                              hipStream_t stream)
{
    const float* x_talking = (const float*)d_in[0];
    const float* templ     = (const float*)d_in[1];
    const float* D0 = (const float*)d_in[2];
    const float* U0 = (const float*)d_in[3];
    const float* D1 = (const float*)d_in[4];
    const float* U1 = (const float*)d_in[5];
    const float* D2 = (const float*)d_in[6];
    const float* U2 = (const float*)d_in[7];
    const float* D3 = (const float*)d_in[8];
    const float* U3 = (const float*)d_in[9];
    const float* enc_w0 = (const float*)d_in[10]; const float* enc_b0 = (const float*)d_in[11];
    const float* enc_w1 = (const float*)d_in[12]; const float* enc_b1 = (const float*)d_in[13];
    const float* enc_w2 = (const float*)d_in[14]; const float* enc_b2 = (const float*)d_in[15];
    const float* enc_w3 = (const float*)d_in[16]; const float* enc_b3 = (const float*)d_in[17];
    const float* fc_enc_w = (const float*)d_in[18]; const float* fc_enc_b = (const float*)d_in[19];
    const float* fc_dec_w = (const float*)d_in[20]; const float* fc_dec_b = (const float*)d_in[21];
    const float* dec_w0 = (const float*)d_in[22]; const float* dec_b0 = (const float*)d_in[23];
    const float* dec_w1 = (const float*)d_in[24]; const float* dec_b1 = (const float*)d_in[25];
    const float* dec_w2 = (const float*)d_in[26]; const float* dec_b2 = (const float*)d_in[27];
    const float* dec_w3 = (const float*)d_in[28]; const float* dec_b3 = (const float*)d_in[29];
    const float* dec_w4 = (const float*)d_in[30]; const float* dec_b4 = (const float*)d_in[31];
    const int* S0 = (const int*)d_in[32];
    const int* S1 = (const int*)d_in[33];
    const int* S2 = (const int*)d_in[34];
    const int* S3 = (const int*)d_in[35];

    float* bufA = (float*)d_ws;            // 10,289,152 floats (41.2 MB)
    float* bufB = bufA + 10289152;         // 5,144,576 floats (20.6 MB)

    float* out0 = (float*)d_out;           // 964,608 floats
    float* out1 = out0 + 964608;

    // Workspace aliases (lifetimes audited):
    unsigned short* Xt_e0 = (unsigned short*)(bufB + 1290240);  // d0-phase B operand
    unsigned short* Xt_c2 = (unsigned short*)(bufB + 2574336);  // u0-phase B operand
    float* xpad   = bufA + 5200000;   // e0 input padded to F=4 (encoder phase)
    float* WpE0   = bufA + 6600000;   // e0 W padded [16][64]   (encoder phase)
    unsigned short* Xb_c3 = (unsigned short*)bufB;              // c3 bf16 input [64,5024,32]
    unsigned short* Xb_c4 = (unsigned short*)(bufA + 5200000);  // c4 bf16 input [64,5024,16] (c3 writes directly)
    float* WpC4   = bufA + 8000000;   // c4 W padded [16][192]
    float* BpC4   = bufA + 8003072;   // c4 bias padded [16]

    size_t arena_bytes = (size_t)(10289152 + 5144576) * sizeof(float);
    if (arena_bytes > ws_size) arena_bytes = ws_size;
    hipMemsetAsync(d_ws, 0, arena_bytes, stream);

    // ---- encoder ----
    pad_e0_w_kernel<<<4, 256, 0, stream>>>(enc_w0, WpE0);
    pad_x4_kernel<<<5024, 256, 0, stream>>>(x_talking, xpad, 1286144);
    {   // e0: F=4(pad), KF=64 (KFr=48), O=16
        dim3 grid(BATCH, (5024 + 255) / 256);
        conv_gemm_kernel<256, 16><<<grid, 256, 0, stream>>>(
            xpad, S0, WpE0, enc_b0, bufA, 5024, 2, 16, 64, 48, 1);
    }
    xpose_bf16_kernel<<<dim3(628, 4), 256, 0, stream>>>(bufA, Xt_e0, 5024, 5024, 4);
    dsamp_mfma3_launch(D0, Xt_e0, bufB, 1257, 5024, 5024, 16, 8, stream);       // d0 [atomic ks=8]
    conv_launch(bufB, S1, enc_w1, enc_b1, bufA, 1257, 16, 32, 1, stream);       // e1
    hipMemsetAsync(bufB, 0, (size_t)645120 * sizeof(float), stream);            // zero d1 target
    dsamp_mfma2_launch(D1, bufA, bufB, 315, 1257, 32, 8, stream);               // d1 [atomic ks=8]
    conv_launch(bufB, S2, enc_w2, enc_b2, bufA, 315, 32, 64, 1, stream);        // e2
    dsamp_launch(D2, bufA, bufB, 80, 315, 64, stream);                          // d2
    conv_launch(bufB, S3, enc_w3, enc_b3, bufA, 80, 64, 128, 1, stream);        // e3
    dsamp_launch(D3, bufA, bufB, 21, 80, 128, stream);                          // d3

    fc_wave_kernel<<<dim3((BATCH * 128) / 4), 256, 0, stream>>>(bufB, fc_enc_w, fc_enc_b, bufA, 2688, 128, 0);
    fc_wave_kernel<<<dim3((BATCH * 2688) / 4), 256, 0, stream>>>(bufA, fc_dec_w, fc_dec_b, bufB, 128, 2688, 1);

    // ---- decoder ----
    dsamp_launch(U3, bufB, bufA, 80, 21, 128, stream);                          // u3
    conv_launch(bufA, S3, dec_w0, dec_b0, bufB, 80, 128, 64, 1, stream);        // c0
    dsamp_launch(U2, bufB, bufA, 315, 80, 64, stream);                          // u2
    conv_launch(bufA, S2, dec_w1, dec_b1, bufB, 315, 64, 32, 1, stream);        // c1
    dsamp_mfma2_launch(U1, bufB, bufA, 1257, 315, 32, 1, stream);               // u1 (plain)
    conv_launch(bufA, S1, dec_w2, dec_b2, bufB, 1257, 32, 32, 1, stream);       // c2
    xpose_bf16_kernel<<<dim3(160, 8), 256, 0, stream>>>(bufB, Xt_c2, 1257, 1280, 5);
    hipMemsetAsync(bufA, 0, (size_t)10289152 * sizeof(float), stream);          // zero u0 target
    dsamp_mfma3_launch(U0, Xt_c2, bufA, 5024, 1257, 1280, 32, 2, stream);       // u0 [atomic ks=2]

    // u0-out (bufA fp32 [64,5024,32]) -> bf16 (all of bufB)
    f32_to_bf16_kernel<<<5024, 256, 0, stream>>>(bufA, Xb_c3, 1286144);
    {   // c3: MFMA conv, F=32, O=16, ELU; writes bf16 directly to Xb_c4
        dim3 grid(BATCH, (5024 + 255) / 256);
        conv_mfma16_kernel<5, 1><<<grid, 256, 0, stream>>>(
            Xb_c3, S0, dec_w3, dec_b3, (void*)Xb_c4, 5024, 384, 1);
    }
    pad_c4_w_kernel<<<12, 256, 0, stream>>>(dec_w4, dec_b4, WpC4, BpC4);
    {   // c4: MFMA conv, F=16, O=16(pad), identity -> c4pad fp32 in bufB
        dim3 grid(BATCH, (5024 + 255) / 256);
        conv_mfma16_kernel<4, 0><<<grid, 256, 0, stream>>>(
            Xb_c4, S0, WpC4, BpC4, (void*)bufB, 5024, 192, 0);
    }
    extract_add_kernel<<<(964608 + 255) / 256, 256, 0, stream>>>(bufB, templ, out0, out1, 964608);
}

// Round 10
// 1003.489 us; speedup vs baseline: 4.5699x; 1.0280x over previous
//
#include <hip/hip_runtime.h>
#include <cstddef>

// ---------------------------------------------------------------------------
// SpiralAutoencoder on MI355X — round 10:
//  * U0 -> ks=1 plain stores (was ks=2 atomic: 2x write traffic + 41MB memset).
//  * e1/c2 -> conv_mfma32 (O=32 twin of proven conv_mfma16), bf16 inputs via
//    flat converts. Kills the last two large VALU (LDS-bound) convs.
// ---------------------------------------------------------------------------

#define BATCH 64
#define SPK 12  // spiral length

typedef __attribute__((ext_vector_type(8))) short bf16x8;
typedef __attribute__((ext_vector_type(4))) short bf16x4;
typedef __attribute__((ext_vector_type(4))) float f32x4;

__device__ __forceinline__ unsigned short f2bf(float x) {
    union { float f; unsigned int u; } v; v.f = x;
    unsigned int r = v.u + 0x7FFF + ((v.u >> 16) & 1);  // RNE
    return (unsigned short)(r >> 16);
}
__device__ __forceinline__ float bf2f(unsigned short u) {
    union { unsigned int i; float f; } v; v.i = ((unsigned int)u) << 16;
    return v.f;
}

__device__ __forceinline__ bf16x8 pack8(const float* v) {
    bf16x8 r;
#pragma unroll
    for (int j = 0; j < 8; ++j) r[j] = (short)f2bf(v[j]);
    return r;
}

// ---------------------------------------------------------------------------
// Flat fp32 -> bf16 convert (8 elems/thread).
// ---------------------------------------------------------------------------
__global__ __launch_bounds__(256) void f32_to_bf16_kernel(
    const float* __restrict__ in, unsigned short* __restrict__ out, int n8)
{
    int i = blockIdx.x * 256 + threadIdx.x;
    if (i < n8) {
        const float* p = in + (size_t)i * 8;
        bf16x8 r;
#pragma unroll
        for (int j = 0; j < 8; ++j) r[j] = (short)f2bf(p[j]);
        *(bf16x8*)(out + (size_t)i * 8) = r;
    }
}

// ---------------------------------------------------------------------------
// conv_mfma16: O=16 spiral conv via MFMA (round-9, proven). c3/c4.
// ---------------------------------------------------------------------------
template<int LOGF, int OBF16>
__global__ __launch_bounds__(256) void conv_mfma16_kernel(
    const unsigned short* __restrict__ x, const int* __restrict__ S,
    const float* __restrict__ W, const float* __restrict__ bias,
    void* __restrict__ yv, int Nv, int KF, int elu_flag)
{
    constexpr int PAD = 40;
    __shared__ unsigned short Gs[2][256 * PAD];

    const int b    = blockIdx.x;
    const int n0   = blockIdx.y * 256;
    const int tid  = threadIdx.x;
    const int lane = tid & 63;
    const int wave = tid >> 6;
    const int wm   = wave * 64;
    const int l15  = lane & 15;
    const int quad = lane >> 4;
    const size_t xb = (size_t)b * Nv;
    const int nslab = KF >> 5;

    f32x4 acc[4];
#pragma unroll
    for (int t = 0; t < 4; ++t) acc[t] = (f32x4){0.f, 0.f, 0.f, 0.f};

    auto gath = [&](int k0, bf16x8* g) {
        int n = n0 + tid;
        if (n < Nv) {
#pragma unroll
            for (int j = 0; j < 4; ++j) {
                int kf  = k0 + j * 8;
                int k   = kf >> LOGF;
                int f   = kf & ((1 << LOGF) - 1);
                int src = S[n * SPK + k];
                g[j] = *(const bf16x8*)(x + ((xb + src) << LOGF) + f);
            }
        } else {
#pragma unroll
            for (int j = 0; j < 4; ++j)
#pragma unroll
                for (int e = 0; e < 8; ++e) g[j][e] = 0;
        }
    };
    auto put = [&](int buf, const bf16x8* g) {
#pragma unroll
        for (int j = 0; j < 4; ++j)
            *(bf16x8*)&Gs[buf][tid * PAD + j * 8] = g[j];
    };
    auto wfrag = [&](int k0) {
        const float* wp = W + l15 * KF + k0 + quad * 8;
        float4 wa = *(const float4*)wp;
        float4 wb = *(const float4*)(wp + 4);
        bf16x8 r;
        r[0] = (short)f2bf(wa.x); r[1] = (short)f2bf(wa.y);
        r[2] = (short)f2bf(wa.z); r[3] = (short)f2bf(wa.w);
        r[4] = (short)f2bf(wb.x); r[5] = (short)f2bf(wb.y);
        r[6] = (short)f2bf(wb.z); r[7] = (short)f2bf(wb.w);
        return r;
    };

    bf16x8 gcur[4], gnext[4];
    gath(0, gcur);
    put(0, gcur);
    __syncthreads();

    for (int s = 0; s < nslab; ++s) {
        const int cur = s & 1;
        const bool more = (s + 1) < nslab;
        if (more) gath((s + 1) * 32, gnext);
        bf16x8 wf = wfrag(s * 32);
#pragma unroll
        for (int t = 0; t < 4; ++t) {
            bf16x8 a = *(const bf16x8*)&Gs[cur][(wm + t * 16 + l15) * PAD + quad * 8];
            acc[t] = __builtin_amdgcn_mfma_f32_16x16x32_bf16(a, wf, acc[t], 0, 0, 0);
        }
        if (more) {
            put(cur ^ 1, gnext);
            __syncthreads();
        }
    }

    float bv = bias[l15];
#pragma unroll
    for (int t = 0; t < 4; ++t)
#pragma unroll
        for (int reg = 0; reg < 4; ++reg) {
            int n = n0 + wm + t * 16 + quad * 4 + reg;
            if (n >= Nv) continue;
            float v = acc[t][reg] + bv;
            if (elu_flag && v <= 0.f) v = expm1f(v);
            if (n == Nv - 1) v = 0.f;
            size_t off = ((size_t)b * Nv + n) * 16 + l15;
            if (OBF16) ((unsigned short*)yv)[off] = f2bf(v);
            else       ((float*)yv)[off] = v;
        }
}

// ---------------------------------------------------------------------------
// conv_mfma32: O=32 spiral conv via MFMA (round-10). e1/c2.
// Same G staging as conv_mfma16; two W B-frags per slab.
// ---------------------------------------------------------------------------
template<int LOGF>
__global__ __launch_bounds__(256) void conv_mfma32_kernel(
    const unsigned short* __restrict__ x, const int* __restrict__ S,
    const float* __restrict__ W, const float* __restrict__ bias,
    float* __restrict__ y, int Nv, int KF, int elu_flag)
{
    constexpr int PAD = 40;
    __shared__ unsigned short Gs[2][256 * PAD];

    const int b    = blockIdx.x;
    const int n0   = blockIdx.y * 256;
    const int tid  = threadIdx.x;
    const int lane = tid & 63;
    const int wave = tid >> 6;
    const int wm   = wave * 64;
    const int l15  = lane & 15;
    const int quad = lane >> 4;
    const size_t xb = (size_t)b * Nv;
    const int nslab = KF >> 5;

    f32x4 acc[4][2];
#pragma unroll
    for (int t = 0; t < 4; ++t)
#pragma unroll
        for (int o = 0; o < 2; ++o) acc[t][o] = (f32x4){0.f, 0.f, 0.f, 0.f};

    auto gath = [&](int k0, bf16x8* g) {
        int n = n0 + tid;
        if (n < Nv) {
#pragma unroll
            for (int j = 0; j < 4; ++j) {
                int kf  = k0 + j * 8;
                int k   = kf >> LOGF;
                int f   = kf & ((1 << LOGF) - 1);
                int src = S[n * SPK + k];
                g[j] = *(const bf16x8*)(x + ((xb + src) << LOGF) + f);
            }
        } else {
#pragma unroll
            for (int j = 0; j < 4; ++j)
#pragma unroll
                for (int e = 0; e < 8; ++e) g[j][e] = 0;
        }
    };
    auto put = [&](int buf, const bf16x8* g) {
#pragma unroll
        for (int j = 0; j < 4; ++j)
            *(bf16x8*)&Gs[buf][tid * PAD + j * 8] = g[j];
    };
    auto wfrag = [&](int k0, int o16) {
        const float* wp = W + (size_t)(o16 * 16 + l15) * KF + k0 + quad * 8;
        float4 wa = *(const float4*)wp;
        float4 wb = *(const float4*)(wp + 4);
        bf16x8 r;
        r[0] = (short)f2bf(wa.x); r[1] = (short)f2bf(wa.y);
        r[2] = (short)f2bf(wa.z); r[3] = (short)f2bf(wa.w);
        r[4] = (short)f2bf(wb.x); r[5] = (short)f2bf(wb.y);
        r[6] = (short)f2bf(wb.z); r[7] = (short)f2bf(wb.w);
        return r;
    };

    bf16x8 gcur[4], gnext[4];
    gath(0, gcur);
    put(0, gcur);
    __syncthreads();

    for (int s = 0; s < nslab; ++s) {
        const int cur = s & 1;
        const bool more = (s + 1) < nslab;
        if (more) gath((s + 1) * 32, gnext);
        bf16x8 wf0 = wfrag(s * 32, 0);
        bf16x8 wf1 = wfrag(s * 32, 1);
#pragma unroll
        for (int t = 0; t < 4; ++t) {
            bf16x8 a = *(const bf16x8*)&Gs[cur][(wm + t * 16 + l15) * PAD + quad * 8];
            acc[t][0] = __builtin_amdgcn_mfma_f32_16x16x32_bf16(a, wf0, acc[t][0], 0, 0, 0);
            acc[t][1] = __builtin_amdgcn_mfma_f32_16x16x32_bf16(a, wf1, acc[t][1], 0, 0, 0);
        }
        if (more) {
            put(cur ^ 1, gnext);
            __syncthreads();
        }
    }

    float bv0 = bias[l15];
    float bv1 = bias[16 + l15];
#pragma unroll
    for (int t = 0; t < 4; ++t)
#pragma unroll
        for (int reg = 0; reg < 4; ++reg) {
            int n = n0 + wm + t * 16 + quad * 4 + reg;
            if (n >= Nv) continue;
            float v0 = acc[t][0][reg] + bv0;
            float v1 = acc[t][1][reg] + bv1;
            if (elu_flag) {
                if (v0 <= 0.f) v0 = expm1f(v0);
                if (v1 <= 0.f) v1 = expm1f(v1);
            }
            if (n == Nv - 1) { v0 = 0.f; v1 = 0.f; }
            size_t off = ((size_t)b * Nv + n) * 32 + l15;
            y[off]      = v0;
            y[off + 16] = v1;
        }
}

// ---------------------------------------------------------------------------
// dsamp_mfma3: 128x128 tile MFMA resample (round-5, proven). D0/U0.
// ---------------------------------------------------------------------------
__global__ __launch_bounds__(256) void dsamp_mfma3_kernel(
    const float* __restrict__ A, const unsigned short* __restrict__ Xt,
    float* __restrict__ Y, int M, int K, int Kp, int logF, int kchunk,
    int atomic_flag)
{
    constexpr int PAD = 40;
    __shared__ unsigned short As[2][128 * PAD];
    __shared__ unsigned short Bs[2][128 * PAD];

    const int fmask = (1 << logF) - 1;
    const int m0   = blockIdx.x * 128;
    const int c0   = blockIdx.y * 128;
    const int kbeg = blockIdx.z * kchunk;
    int kend = kbeg + kchunk; if (kend > Kp) kend = Kp;
    const int nslab = (kend - kbeg + 31) >> 5;

    const int tid  = threadIdx.x;
    const int lane = tid & 63;
    const int wave = tid >> 6;
    const int wm   = (wave >> 1) * 64;
    const int wn   = (wave & 1) * 64;
    const int l15  = lane & 15;
    const int quad = lane >> 4;

    const int ar_row = tid >> 3;
    const int ar_k4  = (tid & 7) * 4;
    const int br_row = tid >> 2;
    const int br_k8  = (tid & 3) * 8;

    f32x4 acc[4][4];
#pragma unroll
    for (int i = 0; i < 4; ++i)
#pragma unroll
        for (int j = 0; j < 4; ++j) acc[i][j] = (f32x4){0.f, 0.f, 0.f, 0.f};

    float4 apre[4];
    bf16x8 bpre[2];

    auto loadAB = [&](int ko) {
#pragma unroll
        for (int i = 0; i < 4; ++i) {
            int m = m0 + ar_row + i * 32;
            int k = ko + ar_k4;
            float4 v = make_float4(0.f, 0.f, 0.f, 0.f);
            if (m < M) {
                const float* ap = A + (size_t)m * K;
                if (k + 3 < K) v = *(const float4*)(ap + k);
                else {
                    v.x = (k     < K) ? ap[k]     : 0.f;
                    v.y = (k + 1 < K) ? ap[k + 1] : 0.f;
                    v.z = (k + 2 < K) ? ap[k + 2] : 0.f;
                    v.w = (k + 3 < K) ? ap[k + 3] : 0.f;
                }
            }
            apre[i] = v;
        }
#pragma unroll
        for (int i = 0; i < 2; ++i)
            bpre[i] = *(const bf16x8*)(Xt + (size_t)(c0 + br_row + i * 64) * Kp + ko + br_k8);
    };
    auto stage = [&](int buf) {
#pragma unroll
        for (int i = 0; i < 4; ++i) {
            bf16x4 t;
            t[0] = (short)f2bf(apre[i].x);
            t[1] = (short)f2bf(apre[i].y);
            t[2] = (short)f2bf(apre[i].z);
            t[3] = (short)f2bf(apre[i].w);
            *(bf16x4*)&As[buf][(ar_row + i * 32) * PAD + ar_k4] = t;
        }
#pragma unroll
        for (int i = 0; i < 2; ++i)
            *(bf16x8*)&Bs[buf][(br_row + i * 64) * PAD + br_k8] = bpre[i];
    };

    loadAB(kbeg);
    stage(0);
    __syncthreads();

    for (int s = 0; s < nslab; ++s) {
        const int cur = s & 1;
        const bool more = (s + 1) < nslab;
        if (more) loadAB(kbeg + (s + 1) * 32);

        bf16x8 af[4], bfr[4];
#pragma unroll
        for (int t = 0; t < 4; ++t) {
            af[t]  = *(const bf16x8*)&As[cur][(wm + t * 16 + l15) * PAD + quad * 8];
            bfr[t] = *(const bf16x8*)&Bs[cur][(wn + t * 16 + l15) * PAD + quad * 8];
        }
#pragma unroll
        for (int tm = 0; tm < 4; ++tm)
#pragma unroll
            for (int tn = 0; tn < 4; ++tn)
                acc[tm][tn] = __builtin_amdgcn_mfma_f32_16x16x32_bf16(af[tm], bfr[tn], acc[tm][tn], 0, 0, 0);

        if (more) { stage(cur ^ 1); __syncthreads(); }
    }

#pragma unroll
    for (int tm = 0; tm < 4; ++tm)
#pragma unroll
        for (int tn = 0; tn < 4; ++tn)
#pragma unroll
            for (int reg = 0; reg < 4; ++reg) {
                int m  = m0 + wm + tm * 16 + quad * 4 + reg;
                int cc = c0 + wn + tn * 16 + l15;
                if (m < M) {
                    int bb = cc >> logF, f = cc & fmask;
                    float* dst = Y + (((size_t)bb * M + m) << logF) + f;
                    if (atomic_flag) atomicAdd(dst, acc[tm][tn][reg]);
                    else *dst = acc[tm][tn][reg];
                }
            }
}

// ---------------------------------------------------------------------------
// dsamp_mfma2 (round-4, proven): D1/U1.
// ---------------------------------------------------------------------------
__global__ __launch_bounds__(256) void dsamp_mfma2_kernel(
    const float* __restrict__ A, const float* __restrict__ X,
    float* __restrict__ Y, int M, int K, int logF, int kchunk, int atomic_flag)
{
    constexpr int PAD = 40;
    __shared__ unsigned short Xs[2][64 * PAD];

    const int fmask = (1 << logF) - 1;
    const int m0   = blockIdx.x * 64;
    const int c0   = blockIdx.y * 64;
    const int kbeg = blockIdx.z * kchunk;
    int kend = kbeg + kchunk; if (kend > K) kend = K;
    const int nslab = (kend - kbeg + 31) >> 5;

    const int tid  = threadIdx.x;
    const int lane = tid & 63;
    const int wave = tid >> 6;
    const int wm   = (wave >> 1) * 32;
    const int wn   = (wave & 1) * 32;
    const int l15  = lane & 15;
    const int quad = lane >> 4;

    const int skk  = tid >> 4;
    const int scg  = (tid & 15) * 4;
    const int cB   = c0 + scg;
    const int xbb  = cB >> logF;
    const int xf   = cB & fmask;
    const size_t xrowbase = (((size_t)xbb * K) << logF) + xf;

    const int mA0 = m0 + wm + l15;
    const int mA1 = mA0 + 16;
    const int kaoff = quad * 8;

    f32x4 acc[2][2];
    acc[0][0] = acc[0][1] = acc[1][0] = acc[1][1] = (f32x4){0.f, 0.f, 0.f, 0.f};

    float4 xn0, xn1;
    float ac0[8], ac1[8], an0[8], an1[8];

    {
        int k = kbeg + skk;
        xn0 = make_float4(0.f, 0.f, 0.f, 0.f);
        if (k < kend) xn0 = *(const float4*)(X + xrowbase + ((size_t)k << logF));
        k = kbeg + 16 + skk;
        xn1 = make_float4(0.f, 0.f, 0.f, 0.f);
        if (k < kend) xn1 = *(const float4*)(X + xrowbase + ((size_t)k << logF));
        int ka = kbeg + kaoff;
#pragma unroll
        for (int j = 0; j < 8; ++j) {
            ac0[j] = (mA0 < M && ka + j < kend) ? A[(size_t)mA0 * K + ka + j] : 0.f;
            ac1[j] = (mA1 < M && ka + j < kend) ? A[(size_t)mA1 * K + ka + j] : 0.f;
        }
        unsigned short* p = &Xs[0][0];
        p[(scg + 0) * PAD + skk] = f2bf(xn0.x);
        p[(scg + 1) * PAD + skk] = f2bf(xn0.y);
        p[(scg + 2) * PAD + skk] = f2bf(xn0.z);
        p[(scg + 3) * PAD + skk] = f2bf(xn0.w);
        int kk1 = 16 + skk;
        p[(scg + 0) * PAD + kk1] = f2bf(xn1.x);
        p[(scg + 1) * PAD + kk1] = f2bf(xn1.y);
        p[(scg + 2) * PAD + kk1] = f2bf(xn1.z);
        p[(scg + 3) * PAD + kk1] = f2bf(xn1.w);
    }
    __syncthreads();

    for (int s = 0; s < nslab; ++s) {
        const int cur = s & 1;
        const bool more = (s + 1 < nslab);
        if (more) {
            int k0 = kbeg + (s + 1) * 32;
            int k = k0 + skk;
            xn0 = make_float4(0.f, 0.f, 0.f, 0.f);
            if (k < kend) xn0 = *(const float4*)(X + xrowbase + ((size_t)k << logF));
            k = k0 + 16 + skk;
            xn1 = make_float4(0.f, 0.f, 0.f, 0.f);
            if (k < kend) xn1 = *(const float4*)(X + xrowbase + ((size_t)k << logF));
            int ka = k0 + kaoff;
#pragma unroll
            for (int j = 0; j < 8; ++j) {
                an0[j] = (mA0 < M && ka + j < kend) ? A[(size_t)mA0 * K + ka + j] : 0.f;
                an1[j] = (mA1 < M && ka + j < kend) ? A[(size_t)mA1 * K + ka + j] : 0.f;
            }
        }
        {
            const unsigned short* p = &Xs[cur][0];
            bf16x8 b0 = *(const bf16x8*)&p[(wn +      l15) * PAD + quad * 8];
            bf16x8 b1 = *(const bf16x8*)&p[(wn + 16 + l15) * PAD + quad * 8];
            bf16x8 a0 = pack8(ac0);
            bf16x8 a1 = pack8(ac1);
            acc[0][0] = __builtin_amdgcn_mfma_f32_16x16x32_bf16(a0, b0, acc[0][0], 0, 0, 0);
            acc[0][1] = __builtin_amdgcn_mfma_f32_16x16x32_bf16(a0, b1, acc[0][1], 0, 0, 0);
            acc[1][0] = __builtin_amdgcn_mfma_f32_16x16x32_bf16(a1, b0, acc[1][0], 0, 0, 0);
            acc[1][1] = __builtin_amdgcn_mfma_f32_16x16x32_bf16(a1, b1, acc[1][1], 0, 0, 0);
        }
        if (more) {
            unsigned short* q = &Xs[cur ^ 1][0];
            q[(scg + 0) * PAD + skk] = f2bf(xn0.x);
            q[(scg + 1) * PAD + skk] = f2bf(xn0.y);
            q[(scg + 2) * PAD + skk] = f2bf(xn0.z);
            q[(scg + 3) * PAD + skk] = f2bf(xn0.w);
            int kk1 = 16 + skk;
            q[(scg + 0) * PAD + kk1] = f2bf(xn1.x);
            q[(scg + 1) * PAD + kk1] = f2bf(xn1.y);
            q[(scg + 2) * PAD + kk1] = f2bf(xn1.z);
            q[(scg + 3) * PAD + kk1] = f2bf(xn1.w);
            __syncthreads();
#pragma unroll
            for (int j = 0; j < 8; ++j) { ac0[j] = an0[j]; ac1[j] = an1[j]; }
        }
    }

#pragma unroll
    for (int tm = 0; tm < 2; ++tm)
#pragma unroll
        for (int tn = 0; tn < 2; ++tn)
#pragma unroll
            for (int reg = 0; reg < 4; ++reg) {
                int m  = m0 + wm + tm * 16 + quad * 4 + reg;
                int cc = c0 + wn + tn * 16 + l15;
                if (m < M) {
                    int bb = cc >> logF, f = cc & fmask;
                    float* dst = Y + (((size_t)bb * M + m) << logF) + f;
                    if (atomic_flag) atomicAdd(dst, acc[tm][tn][reg]);
                    else *dst = acc[tm][tn][reg];
                }
            }
}

// ---------------------------------------------------------------------------
// conv_gemm (fp32 gather). e0/e2/e3/c0/c1. Grid: (batch, mtile).
// ---------------------------------------------------------------------------
template<int MT, int OT>
__global__ __launch_bounds__(256) void conv_gemm_kernel(
    const float* __restrict__ x, const int* __restrict__ S,
    const float* __restrict__ W, const float* __restrict__ bias,
    float* __restrict__ y, int Nv, int logF, int O, int KF, int KFr,
    int elu_flag)
{
    constexpr int CT = OT / 4;
    constexpr int RT = 256 / CT;
    static_assert(RT * 4 == MT, "tile shape");
    __shared__ float Gs[32][MT];
    __shared__ float Ws[32][OT];

    const int b   = blockIdx.x;
    const int n0  = blockIdx.y * MT;
    const int tid = threadIdx.x;
    const int cx  = tid % CT;
    const int ry  = tid / CT;
    const int r0  = ry * 4;
    const int o0  = cx * 4;
    const int fmask = (1 << logF) - 1;
    const size_t xb = (size_t)b * Nv;

    float acc[4][4];
#pragma unroll
    for (int i = 0; i < 4; ++i)
#pragma unroll
        for (int j = 0; j < 4; ++j) acc[i][j] = 0.f;

    for (int k0 = 0; k0 < KF; k0 += 32) {
        constexpr int GSLOTS = MT * 8;
#pragma unroll
        for (int i = 0; i < GSLOTS / 256; ++i) {
            int idx = tid + i * 256;
            int r   = idx & (MT - 1);
            int jg  = idx / MT;
            int j0  = jg * 4;
            int n   = n0 + r;
            int kf  = k0 + j0;
            float4 v = make_float4(0.f, 0.f, 0.f, 0.f);
            if (n < Nv && kf < KFr) {
                int k   = kf >> logF;
                int f   = kf & fmask;
                int src = S[n * SPK + k];
                v = *(const float4*)(x + ((xb + src) << logF) + f);
            }
            Gs[j0 + 0][r] = v.x; Gs[j0 + 1][r] = v.y;
            Gs[j0 + 2][r] = v.z; Gs[j0 + 3][r] = v.w;
        }
        constexpr int WSLOTS = OT * 8;
#pragma unroll
        for (int i = 0; i < (WSLOTS + 255) / 256; ++i) {
            int idx = tid + i * 256;
            if (WSLOTS >= 256 || idx < WSLOTS) {
                int o  = idx & (OT - 1);
                int jg = idx / OT;
                int j0 = jg * 4;
                float4 v = *(const float4*)(W + (size_t)o * KF + k0 + j0);
                Ws[j0 + 0][o] = v.x; Ws[j0 + 1][o] = v.y;
                Ws[j0 + 2][o] = v.z; Ws[j0 + 3][o] = v.w;
            }
        }
        __syncthreads();
#pragma unroll
        for (int kk = 0; kk < 32; ++kk) {
            float4 g = *(const float4*)&Gs[kk][r0];
            float4 w = *(const float4*)&Ws[kk][o0];
            acc[0][0] += g.x * w.x; acc[0][1] += g.x * w.y; acc[0][2] += g.x * w.z; acc[0][3] += g.x * w.w;
            acc[1][0] += g.y * w.x; acc[1][1] += g.y * w.y; acc[1][2] += g.y * w.z; acc[1][3] += g.y * w.w;
            acc[2][0] += g.z * w.x; acc[2][1] += g.z * w.y; acc[2][2] += g.z * w.z; acc[2][3] += g.z * w.w;
            acc[3][0] += g.w * w.x; acc[3][1] += g.w * w.y; acc[3][2] += g.w * w.z; acc[3][3] += g.w * w.w;
        }
        __syncthreads();
    }

    float4 bv = *(const float4*)(bias + o0);
#pragma unroll
    for (int i = 0; i < 4; ++i) {
        int n = n0 + r0 + i;
        if (n >= Nv) continue;
        float v0 = acc[i][0] + bv.x;
        float v1 = acc[i][1] + bv.y;
        float v2 = acc[i][2] + bv.z;
        float v3 = acc[i][3] + bv.w;
        if (elu_flag) {
            v0 = v0 > 0.f ? v0 : expm1f(v0);
            v1 = v1 > 0.f ? v1 : expm1f(v1);
            v2 = v2 > 0.f ? v2 : expm1f(v2);
            v3 = v3 > 0.f ? v3 : expm1f(v3);
        }
        if (n == Nv - 1) { v0 = v1 = v2 = v3 = 0.f; }
        *(float4*)(y + ((size_t)b * Nv + n) * O + o0) = make_float4(v0, v1, v2, v3);
    }
}

// ---------------------------------------------------------------------------
// VALU down/up-sample (tiny levels 2-3 only).
// ---------------------------------------------------------------------------
__global__ __launch_bounds__(256) void dsamp_kernel(
    const float* __restrict__ A, const float* __restrict__ X,
    float* __restrict__ Y, int M, int N, int F)
{
    __shared__ float As[16][68];
    __shared__ float Xs[16][64];

    const int m0  = blockIdx.x * 64;
    const int c0  = blockIdx.y * 64;
    const int tid = threadIdx.x;
    const int tx  = tid & 15;
    const int ty  = tid >> 4;

    float acc[4][4];
#pragma unroll
    for (int i = 0; i < 4; ++i)
#pragma unroll
        for (int j = 0; j < 4; ++j) acc[i][j] = 0.f;

    for (int k0 = 0; k0 < N; k0 += 16) {
#pragma unroll
        for (int p = 0; p < 4; ++p) {
            int r  = (tid >> 4) + p * 16;
            int kk = tid & 15;
            int m  = m0 + r;
            int n  = k0 + kk;
            float v = 0.f;
            if (m < M && n < N) v = A[(size_t)m * N + n];
            As[kk][r] = v;
        }
        {
            int kk = tid >> 4;
            int cc = (tid & 15) * 4;
            int n  = k0 + kk;
            float4 v = make_float4(0.f, 0.f, 0.f, 0.f);
            if (n < N) {
                int c  = c0 + cc;
                int bb = c / F;
                int f  = c - bb * F;
                v = *(const float4*)(X + ((size_t)bb * N + n) * F + f);
            }
            *(float4*)&Xs[kk][cc] = v;
        }
        __syncthreads();
#pragma unroll
        for (int kk = 0; kk < 16; ++kk) {
            float4 av = *(const float4*)&As[kk][ty * 4];
            float4 xv = *(const float4*)&Xs[kk][tx * 4];
            acc[0][0] += av.x * xv.x; acc[0][1] += av.x * xv.y; acc[0][2] += av.x * xv.z; acc[0][3] += av.x * xv.w;
            acc[1][0] += av.y * xv.x; acc[1][1] += av.y * xv.y; acc[1][2] += av.y * xv.z; acc[1][3] += av.y * xv.w;
            acc[2][0] += av.z * xv.x; acc[2][1] += av.z * xv.y; acc[2][2] += av.z * xv.z; acc[2][3] += av.z * xv.w;
            acc[3][0] += av.w * xv.x; acc[3][1] += av.w * xv.y; acc[3][2] += av.w * xv.z; acc[3][3] += av.w * xv.w;
        }
        __syncthreads();
    }

    const int cbase = c0 + tx * 4;
    const int bb = cbase / F;
    const int f  = cbase - bb * F;
#pragma unroll
    for (int i = 0; i < 4; ++i) {
        int m = m0 + ty * 4 + i;
        if (m < M) {
            float4 v = make_float4(acc[i][0], acc[i][1], acc[i][2], acc[i][3]);
            *(float4*)(Y + ((size_t)bb * M + m) * F + f) = v;
        }
    }
}

// ---------------------------------------------------------------------------
// fc_wave: one 64-lane wave per output element (round-6, proven).
// ---------------------------------------------------------------------------
__global__ __launch_bounds__(256) void fc_wave_kernel(
    const float* __restrict__ in, const float* __restrict__ W,
    const float* __restrict__ bias, float* __restrict__ out,
    int In, int O, int dup)
{
    const int gw   = blockIdx.x * 4 + (threadIdx.x >> 6);
    const int lane = threadIdx.x & 63;
    const int b = gw / O;
    const int o = gw - b * O;
    const float* xr = in + (size_t)b * In;
    float acc = 0.f;
    if (dup) {
        const float* wr = W + (size_t)o * (2 * In);
        for (int k = lane; k < In; k += 64)
            acc += xr[k] * (wr[k] + wr[In + k]);
    } else {
        const float* wr = W + (size_t)o * In;
        for (int k = lane; k < In; k += 64)
            acc += xr[k] * wr[k];
    }
#pragma unroll
    for (int off = 32; off > 0; off >>= 1)
        acc += __shfl_down(acc, off, 64);
    if (lane == 0) out[(size_t)b * O + o] = acc + bias[o];
}

// ---------------------------------------------------------------------------
// Transpose-convert: x [b][k][f] fp32 -> xt [c][k] bf16, c = b*F+f, stride Kp.
// ---------------------------------------------------------------------------
__global__ __launch_bounds__(256) void xpose_bf16_kernel(
    const float* __restrict__ x, unsigned short* __restrict__ xt,
    int K, int Kp, int logF)
{
    const int c  = blockIdx.y * 256 + threadIdx.x;
    const int k0 = blockIdx.x * 8;
    const int bb = c >> logF;
    const int f  = c & ((1 << logF) - 1);
    const float* src = x + (((size_t)bb * K) << logF) + f;
    bf16x8 r;
#pragma unroll
    for (int j = 0; j < 8; ++j) {
        int k = k0 + j;
        float v = (k < K) ? src[(size_t)k << logF] : 0.f;
        r[j] = (short)f2bf(v);
    }
    *(bf16x8*)(xt + (size_t)c * Kp + k0) = r;
}

// ---------------------------------------------------------------------------
// Padding / extraction helpers.
// ---------------------------------------------------------------------------
__global__ __launch_bounds__(256) void pad_e0_w_kernel(
    const float* __restrict__ w, float* __restrict__ wp)
{
    int i = blockIdx.x * 256 + threadIdx.x;
    if (i < 1024) {
        int o = i >> 6, kf = i & 63;
        int k = kf >> 2, f = kf & 3;
        wp[i] = (f < 3 && k < 12) ? w[o * 36 + k * 3 + f] : 0.f;
    }
}
__global__ __launch_bounds__(256) void pad_x4_kernel(
    const float* __restrict__ x, float* __restrict__ xp, int n)
{
    int i = blockIdx.x * 256 + threadIdx.x;
    if (i < n) {
        int f = i & 3, nb = i >> 2;
        xp[i] = (f < 3) ? x[nb * 3 + f] : 0.f;
    }
}
__global__ __launch_bounds__(256) void pad_c4_w_kernel(
    const float* __restrict__ w, const float* __restrict__ b,
    float* __restrict__ wp, float* __restrict__ bp)
{
    int i = blockIdx.x * 256 + threadIdx.x;
    if (i < 3072) {
        int o = i / 192;
        wp[i] = (o < 3) ? w[i] : 0.f;
    }
    if (i < 16) bp[i] = (i < 3) ? b[i] : 0.f;
}
__global__ __launch_bounds__(256) void extract_add_kernel(
    const float* __restrict__ cp, const float* __restrict__ t,
    float* __restrict__ o0, float* __restrict__ o1, int n)
{
    int i = blockIdx.x * 256 + threadIdx.x;
    if (i < n) {
        int f = i % 3, nb = i / 3;
        float v = cp[(size_t)nb * 16 + f];
        o0[i] = v;
        o1[i] = v + t[i];
    }
}

// ---------------------------------------------------------------------------

static inline int ilog2(int v) { int l = 0; while ((1 << l) < v) ++l; return l; }

static inline void conv_launch(const float* x, const int* S, const float* W,
                               const float* b, float* y, int Nv, int F, int O,
                               int elu, hipStream_t s)
{
    int KF = SPK * F;
    int logF = ilog2(F);
    if (O == 16) {
        dim3 grid(BATCH, (Nv + 255) / 256);
        conv_gemm_kernel<256, 16><<<grid, 256, 0, s>>>(x, S, W, b, y, Nv, logF, O, KF, KF, elu);
    } else if (O == 32) {
        dim3 grid(BATCH, (Nv + 127) / 128);
        conv_gemm_kernel<128, 32><<<grid, 256, 0, s>>>(x, S, W, b, y, Nv, logF, O, KF, KF, elu);
    } else if (O == 64) {
        dim3 grid(BATCH, (Nv + 63) / 64);
        conv_gemm_kernel<64, 64><<<grid, 256, 0, s>>>(x, S, W, b, y, Nv, logF, O, KF, KF, elu);
    } else {
        dim3 grid(BATCH, (Nv + 31) / 32);
        conv_gemm_kernel<32, 128><<<grid, 256, 0, s>>>(x, S, W, b, y, Nv, logF, O, KF, KF, elu);
    }
}

static inline void dsamp_mfma2_launch(const float* A, const float* X, float* Y,
                                      int M, int K, int F, int ks, hipStream_t s)
{
    int kchunk = (K + ks - 1) / ks;
    kchunk = (kchunk + 31) & ~31;
    int ksz = (K + kchunk - 1) / kchunk;
    dim3 grid((M + 63) / 64, F, ksz);
    dsamp_mfma2_kernel<<<grid, 256, 0, s>>>(A, X, Y, M, K, ilog2(F), kchunk, ksz > 1 ? 1 : 0);
}

static inline void dsamp_mfma3_launch(const float* A, const unsigned short* Xt,
                                      float* Y, int M, int K, int Kp, int F,
                                      int ks, hipStream_t s)
{
    int slabs = Kp >> 5;
    int kchunk = ((slabs + ks - 1) / ks) * 32;
    int ksz = (Kp + kchunk - 1) / kchunk;
    dim3 grid((M + 127) / 128, (BATCH * F) / 128, ksz);
    dsamp_mfma3_kernel<<<grid, 256, 0, s>>>(A, Xt, Y, M, K, Kp, ilog2(F), kchunk,
                                            ksz > 1 ? 1 : 0);
}

static inline void dsamp_launch(const float* A, const float* X, float* Y,
                                int M, int N, int F, hipStream_t s)
{
    dim3 grid((M + 63) / 64, F);
    dsamp_kernel<<<grid, 256, 0, s>>>(A, X, Y, M, N, F);
}

extern "C" void kernel_launch(void* const* d_in, const int* in_sizes, int n_in,
                              void* d_out, int out_size, void* d_ws, size_t ws_size,
                              hipStream_t stream)
{
    const float* x_talking = (const float*)d_in[0];
    const float* templ     = (const float*)d_in[1];
    const float* D0 = (const float*)d_in[2];
    const float* U0 = (const float*)d_in[3];
    const float* D1 = (const float*)d_in[4];
    const float* U1 = (const float*)d_in[5];
    const float* D2 = (const float*)d_in[6];
    const float* U2 = (const float*)d_in[7];
    const float* D3 = (const float*)d_in[8];
    const float* U3 = (const float*)d_in[9];
    const float* enc_w0 = (const float*)d_in[10]; const float* enc_b0 = (const float*)d_in[11];
    const float* enc_w1 = (const float*)d_in[12]; const float* enc_b1 = (const float*)d_in[13];
    const float* enc_w2 = (const float*)d_in[14]; const float* enc_b2 = (const float*)d_in[15];
    const float* enc_w3 = (const float*)d_in[16]; const float* enc_b3 = (const float*)d_in[17];
    const float* fc_enc_w = (const float*)d_in[18]; const float* fc_enc_b = (const float*)d_in[19];
    const float* fc_dec_w = (const float*)d_in[20]; const float* fc_dec_b = (const float*)d_in[21];
    const float* dec_w0 = (const float*)d_in[22]; const float* dec_b0 = (const float*)d_in[23];
    const float* dec_w1 = (const float*)d_in[24]; const float* dec_b1 = (const float*)d_in[25];
    const float* dec_w2 = (const float*)d_in[26]; const float* dec_b2 = (const float*)d_in[27];
    const float* dec_w3 = (const float*)d_in[28]; const float* dec_b3 = (const float*)d_in[29];
    const float* dec_w4 = (const float*)d_in[30]; const float* dec_b4 = (const float*)d_in[31];
    const int* S0 = (const int*)d_in[32];
    const int* S1 = (const int*)d_in[33];
    const int* S2 = (const int*)d_in[34];
    const int* S3 = (const int*)d_in[35];

    float* bufA = (float*)d_ws;            // 10,289,152 floats (41.2 MB)
    float* bufB = bufA + 10289152;         // 5,144,576 floats (20.6 MB)

    float* out0 = (float*)d_out;           // 964,608 floats
    float* out1 = out0 + 964608;

    // Workspace aliases (lifetimes audited):
    unsigned short* Xt_e0 = (unsigned short*)(bufB + 1290240);  // d0-phase B operand
    unsigned short* Xt_c2 = (unsigned short*)(bufB + 2574336);  // u0-phase B operand
    float* xpad   = bufA + 5200000;   // e0 input padded to F=4 (dead after e0)
    float* WpE0   = bufA + 6600000;   // e0 W padded [16][64]
    unsigned short* Xb_e1   = (unsigned short*)(bufA + 5200000); // e1 bf16 in [64,1257,16] (xpad dead)
    unsigned short* Xb_c2in = (unsigned short*)(bufA + 2600000); // c2 bf16 in [64,1257,32] (past u1-out)
    unsigned short* Xb_c3 = (unsigned short*)bufB;               // c3 bf16 input [64,5024,32]
    unsigned short* Xb_c4 = (unsigned short*)(bufA + 5200000);   // c4 bf16 input (c3 writes directly)
    float* WpC4   = bufA + 8000000;   // c4 W padded [16][192]
    float* BpC4   = bufA + 8003072;   // c4 bias padded [16]

    size_t arena_bytes = (size_t)(10289152 + 5144576) * sizeof(float);
    if (arena_bytes > ws_size) arena_bytes = ws_size;
    hipMemsetAsync(d_ws, 0, arena_bytes, stream);

    // ---- encoder ----
    pad_e0_w_kernel<<<4, 256, 0, stream>>>(enc_w0, WpE0);
    pad_x4_kernel<<<5024, 256, 0, stream>>>(x_talking, xpad, 1286144);
    {   // e0: F=4(pad), KF=64 (KFr=48), O=16
        dim3 grid(BATCH, (5024 + 255) / 256);
        conv_gemm_kernel<256, 16><<<grid, 256, 0, stream>>>(
            xpad, S0, WpE0, enc_b0, bufA, 5024, 2, 16, 64, 48, 1);
    }
    xpose_bf16_kernel<<<dim3(628, 4), 256, 0, stream>>>(bufA, Xt_e0, 5024, 5024, 4);
    dsamp_mfma3_launch(D0, Xt_e0, bufB, 1257, 5024, 5024, 16, 8, stream);       // d0 [atomic ks=8]
    // d0-out (bufB fp32 [64,1257,16]) -> bf16 at Xb_e1
    f32_to_bf16_kernel<<<629, 256, 0, stream>>>(bufB, Xb_e1, 160896);
    {   // e1: MFMA conv, F=16, O=32, ELU -> bufA [64,1257,32]
        dim3 grid(BATCH, (1257 + 255) / 256);
        conv_mfma32_kernel<4><<<grid, 256, 0, stream>>>(
            Xb_e1, S1, enc_w1, enc_b1, bufA, 1257, 192, 1);
    }
    hipMemsetAsync(bufB, 0, (size_t)645120 * sizeof(float), stream);            // zero d1 target
    dsamp_mfma2_launch(D1, bufA, bufB, 315, 1257, 32, 8, stream);               // d1 [atomic ks=8]
    conv_launch(bufB, S2, enc_w2, enc_b2, bufA, 315, 32, 64, 1, stream);        // e2
    dsamp_launch(D2, bufA, bufB, 80, 315, 64, stream);                          // d2
    conv_launch(bufB, S3, enc_w3, enc_b3, bufA, 80, 64, 128, 1, stream);        // e3
    dsamp_launch(D3, bufA, bufB, 21, 80, 128, stream);                          // d3

    fc_wave_kernel<<<dim3((BATCH * 128) / 4), 256, 0, stream>>>(bufB, fc_enc_w, fc_enc_b, bufA, 2688, 128, 0);
    fc_wave_kernel<<<dim3((BATCH * 2688) / 4), 256, 0, stream>>>(bufA, fc_dec_w, fc_dec_b, bufB, 128, 2688, 1);

    // ---- decoder ----
    dsamp_launch(U3, bufB, bufA, 80, 21, 128, stream);                          // u3
    conv_launch(bufA, S3, dec_w0, dec_b0, bufB, 80, 128, 64, 1, stream);        // c0
    dsamp_launch(U2, bufB, bufA, 315, 80, 64, stream);                          // u2
    conv_launch(bufA, S2, dec_w1, dec_b1, bufB, 315, 64, 32, 1, stream);        // c1
    dsamp_mfma2_launch(U1, bufB, bufA, 1257, 315, 32, 1, stream);               // u1 -> bufA [64,1257,32]
    // u1-out -> bf16 at Xb_c2in
    f32_to_bf16_kernel<<<1257, 256, 0, stream>>>(bufA, Xb_c2in, 321792);
    {   // c2: MFMA conv, F=32, O=32, ELU -> bufB [64,1257,32]
        dim3 grid(BATCH, (1257 + 255) / 256);
        conv_mfma32_kernel<5><<<grid, 256, 0, stream>>>(
            Xb_c2in, S1, dec_w2, dec_b2, bufB, 1257, 384, 1);
    }
    xpose_bf16_kernel<<<dim3(160, 8), 256, 0, stream>>>(bufB, Xt_c2, 1257, 1280, 5);
    dsamp_mfma3_launch(U0, Xt_c2, bufA, 5024, 1257, 1280, 32, 1, stream);       // u0 [ks=1, plain stores]

    // u0-out (bufA fp32 [64,5024,32]) -> bf16 (all of bufB)
    f32_to_bf16_kernel<<<5024, 256, 0, stream>>>(bufA, Xb_c3, 1286144);
    {   // c3: MFMA conv, F=32, O=16, ELU; writes bf16 directly to Xb_c4
        dim3 grid(BATCH, (5024 + 255) / 256);
        conv_mfma16_kernel<5, 1><<<grid, 256, 0, stream>>>(
            Xb_c3, S0, dec_w3, dec_b3, (void*)Xb_c4, 5024, 384, 1);
    }
    pad_c4_w_kernel<<<12, 256, 0, stream>>>(dec_w4, dec_b4, WpC4, BpC4);
    {   // c4: MFMA conv, F=16, O=16(pad), identity -> c4pad fp32 in bufB
        dim3 grid(BATCH, (5024 + 255) / 256);
        conv_mfma16_kernel<4, 0><<<grid, 256, 0, stream>>>(
            Xb_c4, S0, WpC4, BpC4, (void*)bufB, 5024, 192, 0);
    }
    extract_add_kernel<<<(964608 + 255) / 256, 256, 0, stream>>>(bufB, templ, out0, out1, 964608);
}